// Round 9
// baseline (1771.756 us; speedup 1.0000x reference)
//
#include <hip/hip_runtime.h>
#include <hip/hip_cooperative_groups.h>
#include <cstdint>

namespace cg = cooperative_groups;

#define BX   32
#define NN   1000
#define FF   16
#define TT   48          // HIST + FC
#define HIST 24
#define FC   24
#define HID  64
#define DEG  16
#define BN   (BX*NN)     // 32000 nodes

typedef __attribute__((ext_vector_type(8)))  short s8v;   // bf16x8 MFMA frag (4 VGPR)
typedef __attribute__((ext_vector_type(16))) float f16v;  // 32x32 accumulator

__device__ __forceinline__ float sigf(float x)  { return 1.0f/(1.0f+__expf(-x)); }
__device__ __forceinline__ float tanhf_(float x){ return 2.0f/(1.0f+__expf(-2.0f*x)) - 1.0f; }
__device__ __forceinline__ unsigned short f2bf(float x){
    unsigned int u = __float_as_uint(x);
    return (unsigned short)((u + 0x7FFFu + ((u>>16)&1u)) >> 16);   // RNE
}
__device__ __forceinline__ float bf2f(unsigned short b){
    return __uint_as_float(((unsigned int)b)<<16);
}

// ---------------- one-time: bf16 weight images in LDS-exact layout ----------------
// encB: [B1 64x72 | Bih 192x104 | Bhh 192x72]   decB: [Bihd 192x72 | Bhhd 192x72]
__global__ void prep_weights(
    const float* __restrict__ W_rel, const float* __restrict__ W_root,
    const float* __restrict__ eWih, const float* __restrict__ eWhh,
    const float* __restrict__ dWih, const float* __restrict__ dWhh,
    unsigned short* __restrict__ encB, unsigned short* __restrict__ decB)
{
    const int i = blockIdx.x*256 + threadIdx.x;   // grid covers 192*104 = 19968
    if (i < 64*72){                                // B1[n][k]: k<18 W_rel, 32..49 W_root
        int n = i/72, k = i%72;
        float v = 0.f;
        if (k < 18) v = W_rel[k*64 + n];
        else if (k >= 32 && k < 50) v = W_root[(k-32)*64 + n];
        encB[i] = f2bf(v);
    }
    if (i < 192*104){                              // Bih[n][k]: k<18 xg-part, 32..95 conv-part
        int n = i/104, k = i%104;
        float v = 0.f;
        if (k < 18) v = eWih[n*82 + k];
        else if (k >= 32 && k < 96) v = eWih[n*82 + 18 + (k-32)];
        encB[4608 + i] = f2bf(v);
    }
    if (i < 192*72){                               // Bhh / dec images
        int n = i/72, k = i%72;
        encB[24576 + i] = f2bf((k < 64) ? eWhh[n*64 + k] : 0.f);
        decB[i]         = f2bf((k < 64) ? dWih[n*64 + k] : 0.f);
        decB[13824 + i] = f2bf((k < 64) ? dWhh[n*64 + k] : 0.f);
    }
}

// ---------------- pre-pass: static edge aggregation (R7-proven) ----------------
__global__ __launch_bounds__(1024, 4) void agg_pre(
    const float* __restrict__ X, const float* __restrict__ y,
    const int*   __restrict__ esrc, const float* __restrict__ ew,
    float* __restrict__ aggs)
{
    extern __shared__ float sm[];
    float* Xs = sm;            // [1000][16]
    float* ys = sm + NN*FF;    // [1000]

    const int b = blockIdx.x;
    const int t = blockIdx.y;
    const float* Xt = X + (size_t)(b*TT + t)*NN*FF;
    const float* yt = y + (size_t)(b*TT + t)*NN;

    for (int i = threadIdx.x; i < NN*FF/4; i += 1024)
        ((float4*)Xs)[i] = ((const float4*)Xt)[i];
    for (int i = threadIdx.x; i < NN; i += 1024)
        ys[i] = yt[i];
    __syncthreads();

    const int nl = threadIdx.x;
    if (nl < NN){
        const int node = b*NN + nl;
        float agg[17];
        #pragma unroll
        for (int i=0;i<17;i++) agg[i]=0.f;
        const int4*   sv = (const int4*)  (esrc + node*DEG);
        const float4* wv = (const float4*)(ew   + node*DEG);
        #pragma unroll
        for (int q=0;q<4;q++){
            int4 s4 = sv[q]; float4 w4 = wv[q];
            const int   ss[4] = {s4.x, s4.y, s4.z, s4.w};
            const float ww[4] = {w4.x, w4.y, w4.z, w4.w};
            #pragma unroll
            for (int i=0;i<4;i++){
                const int sl = ss[i] - b*NN;
                const float wgt = ww[i];
                agg[0] += wgt * ys[sl];
                const float4* sr = (const float4*)&Xs[sl*FF];
                #pragma unroll
                for (int q2=0;q2<4;q2++){
                    float4 v = sr[q2];
                    agg[1+4*q2] += wgt*v.x; agg[2+4*q2] += wgt*v.y;
                    agg[3+4*q2] += wgt*v.z; agg[4+4*q2] += wgt*v.w;
                }
            }
        }
        #pragma unroll
        for (int k=0;k<17;k++) aggs[((size_t)t*17 + k)*BN + node] = agg[k];
    }
}

// ---------------- fused persistent kernel: all 24 enc + 24 dec steps ----------------
// 250 blocks x 512 threads (1 block/CU), grid.sync() between steps.
// LDS (bf16 units): W@0 (enc 38400 / dec overlay 27648)
//                   A_s@38400 (128x136)  enc=[agg|0|xg|0|conv]; dec A_x overlay (pitch 72)
//                   A_h@55808 (128x136)  = [h_hi64|h_lo64] -- PERSISTS across all steps
#define OFFB1  0
#define OFFBIH 4608
#define OFFBHH 24576
#define DOFFBIH 0
#define DOFFBHH 13824
#define OFFAS  38400
#define OFFAH  55808
#define FU_SMEM 146432
#define PAS  136
#define PBIH 104
#define PB72 72

__global__ __launch_bounds__(512, 1) void fused_steps(
    const float* __restrict__ X, const float* __restrict__ y,
    const int* __restrict__ esrc, const float* __restrict__ ew,
    const float* __restrict__ aggs,
    const unsigned short* __restrict__ encB, const unsigned short* __restrict__ decB,
    const float* __restrict__ b_rel,
    const float* __restrict__ ebih, const float* __restrict__ ebhh,
    const float* __restrict__ eWout, const float* __restrict__ ebout,
    const float* __restrict__ dbih, const float* __restrict__ dbhh,
    const float* __restrict__ dWin, const float* __restrict__ dbin,
    const float* __restrict__ dWout, const float* __restrict__ dbout,
    float* __restrict__ xnA, float* __restrict__ xnB, float* __restrict__ out)
{
    extern __shared__ char smraw[];
    __shared__ float xs[512];
    unsigned short* sm16 = (unsigned short*)smraw;
    cg::grid_group grid = cg::this_grid();

    const int tid  = threadIdx.x;
    const int lane = tid & 63;
    const int w    = __builtin_amdgcn_readfirstlane(tid >> 6);
    const int mt = w >> 1, jt = w & 1;
    const int blk = blockIdx.x;

    // ---- one-time init: enc weights -> LDS, zero A_h (h=0), zero A_s gap cols ----
    {
        const uint4* src = (const uint4*)encB;
        uint4* dst = (uint4*)smraw;
        for (int i = tid; i < 4800; i += 512) dst[i] = src[i];
        unsigned int* ah32 = (unsigned int*)(sm16 + OFFAH);
        for (int i = tid; i < 8704; i += 512) ah32[i] = 0u;
        unsigned int* as32 = (unsigned int*)(sm16 + OFFAS);
        for (int i = tid; i < 128*14; i += 512){
            int node = i & 127, q = i >> 7;
            int col = (q < 7) ? (18 + 2*q) : (50 + 2*(q-7));
            as32[(node*PAS + col) >> 1] = 0u;
        }
    }

    for (int t = 0; t < TT; ++t){
        const bool enc = (t < HIST);
        const float* xn_r = (t & 1) ? xnB : xnA;
        float*       xn_w = (t & 1) ? xnA : xnB;

        if (enc){
            // ---- P0c: static agg channels -> A_s cols 1..17 ----
            for (int i = tid; i < 128*17; i += 512){
                int node = i & 127, k = i >> 7;
                float v = aggs[((size_t)t*17 + k)*BN + blk*128 + node];
                sm16[OFFAS + node*PAS + 1 + k] = f2bf(v);
            }
            // ---- P0d: xn-gather (col0) + xg (cols 32..49) ----
            if (tid < 128){
                const int node = tid, node_g = blk*128 + node;
                const int b = node_g / NN, nloc = node_g - b*NN;
                const float* Xt = X + (size_t)(b*TT + t)*NN*FF;
                const float* yt = y + (size_t)(b*TT + t)*NN;
                unsigned short* as = sm16 + OFFAS + node*PAS;
                float a0 = 0.f, xnv = 0.f;
                if (t > 0){
                    const int4*   sv = (const int4*)  (esrc + node_g*DEG);
                    const float4* wv = (const float4*)(ew   + node_g*DEG);
                    #pragma unroll
                    for (int q=0;q<4;q++){
                        int4 s4 = sv[q]; float4 w4 = wv[q];
                        a0 += w4.x*xn_r[s4.x] + w4.y*xn_r[s4.y]
                            + w4.z*xn_r[s4.z] + w4.w*xn_r[s4.w];
                    }
                    xnv = xn_r[node_g];
                }
                as[0]  = f2bf(a0);
                as[32] = f2bf(xnv);
                as[33] = f2bf(yt[nloc]);
                const float4* xr = (const float4*)(Xt + nloc*FF);
                #pragma unroll
                for (int q=0;q<4;q++){
                    float4 v = xr[q];
                    as[34+4*q] = f2bf(v.x); as[35+4*q] = f2bf(v.y);
                    as[36+4*q] = f2bf(v.z); as[37+4*q] = f2bf(v.w);
                }
            }
            __syncthreads();

            // ---- P1: GraphConv GEMM -> sigmoid -> A_s cols 64..127 ----
            {
                f16v acc = {};
                const int rA = mt*32 + (lane & 31);
                const int rB = jt*32 + (lane & 31);
                const int ke = (lane >> 5)*8;
                #pragma unroll
                for (int ks=0; ks<4; ks++){
                    s8v a = *(const s8v*)(sm16 + OFFAS + rA*PAS  + ks*16 + ke);
                    s8v b = *(const s8v*)(sm16 + OFFB1 + rB*PB72 + ks*16 + ke);
                    acc = __builtin_amdgcn_mfma_f32_32x32x16_bf16(a, b, acc, 0, 0, 0);
                }
                const int j = jt*32 + (lane & 31);
                const float brl = b_rel[j];
                #pragma unroll
                for (int reg=0; reg<16; reg++){
                    int row = (reg&3) + 8*(reg>>2) + 4*(lane>>5);
                    sm16[OFFAS + (mt*32 + row)*PAS + 64 + j] = f2bf(sigf(acc[reg] + brl));
                }
            }
            __syncthreads();

            // ---- P2: GRU GEMMs ----
            f16v accx[3] = {{},{},{}};
            f16v acch[3] = {{},{},{}};
            {
                const int rA = mt*32 + (lane & 31);
                const int ln = lane & 31;
                const int ke = (lane >> 5)*8;
                #pragma unroll
                for (int ks=0; ks<6; ks++){               // x-GEMM: A_s window [32,128)
                    s8v a = *(const s8v*)(sm16 + OFFAS + rA*PAS + 32 + ks*16 + ke);
                    #pragma unroll
                    for (int nt=0; nt<3; nt++){
                        int NT = jt + nt*2;
                        s8v b = *(const s8v*)(sm16 + OFFBIH + (NT*32 + ln)*PBIH + ks*16 + ke);
                        accx[nt] = __builtin_amdgcn_mfma_f32_32x32x16_bf16(a, b, accx[nt], 0,0,0);
                    }
                }
                #pragma unroll
                for (int ks=0; ks<4; ks++){               // h-GEMM: hi + lo passes
                    s8v ah = *(const s8v*)(sm16 + OFFAH + rA*PAS      + ks*16 + ke);
                    s8v al = *(const s8v*)(sm16 + OFFAH + rA*PAS + 64 + ks*16 + ke);
                    #pragma unroll
                    for (int nt=0; nt<3; nt++){
                        int NT = jt + nt*2;
                        s8v b = *(const s8v*)(sm16 + OFFBHH + (NT*32 + ln)*PB72 + ks*16 + ke);
                        acch[nt] = __builtin_amdgcn_mfma_f32_32x32x16_bf16(ah, b, acch[nt], 0,0,0);
                        acch[nt] = __builtin_amdgcn_mfma_f32_32x32x16_bf16(al, b, acch[nt], 0,0,0);
                    }
                }
            }
            __syncthreads();                              // all A_h reads done

            // ---- P3: epilogue; h' written back to A_h (hi/lo) in place ----
            {
                const int j = jt*32 + (lane & 31);
                const float br  = ebih[j]     + ebhh[j];
                const float bz  = ebih[64+j]  + ebhh[64+j];
                const float bin_ = ebih[128+j];
                const float bhn  = ebhh[128+j];
                #pragma unroll
                for (int reg=0; reg<16; reg++){
                    int row = (reg&3) + 8*(reg>>2) + 4*(lane>>5);
                    int node_l = mt*32 + row;
                    unsigned short* hh = sm16 + OFFAH + node_l*PAS + j;
                    float hold = bf2f(hh[0]) + bf2f(hh[64]);
                    float r  = sigf(accx[0][reg] + acch[0][reg] + br);
                    float z  = sigf(accx[1][reg] + acch[1][reg] + bz);
                    float nn = tanhf_(accx[2][reg] + bin_ + r*(acch[2][reg] + bhn));
                    float hp = (1.f - z)*nn + z*hold;
                    unsigned short nh = f2bf(hp);
                    hh[0]  = nh;
                    hh[64] = f2bf(hp - bf2f(nh));
                }
            }
            __syncthreads();

            // ---- P4: xn = h' @ Wout + bout ----
            {
                const int node_l = tid >> 2, q = tid & 3;
                float s = 0.f;
                #pragma unroll
                for (int qq=0; qq<2; qq++){
                    s8v hi = *(const s8v*)(sm16 + OFFAH + node_l*PAS      + q*16 + qq*8);
                    s8v lo = *(const s8v*)(sm16 + OFFAH + node_l*PAS + 64 + q*16 + qq*8);
                    #pragma unroll
                    for (int i=0;i<8;i++){
                        float hv = bf2f((unsigned short)hi[i]) + bf2f((unsigned short)lo[i]);
                        s += hv * eWout[q*16 + qq*8 + i];
                    }
                }
                xs[tid] = s;
            }
            __syncthreads();
            if (tid < 128)
                xn_w[blk*128 + tid] = xs[4*tid] + xs[4*tid+1] + xs[4*tid+2] + xs[4*tid+3] + ebout[0];
        } else {
            // ---- decoder ----
            if (t == HIST){                               // overlay dec weights once
                const uint4* src = (const uint4*)decB;
                uint4* dst = (uint4*)smraw;
                for (int i = tid; i < 3456; i += 512) dst[i] = src[i];
            }
            // P0b: xin = [xn|X13..15] @ Win + bin -> A_x (pitch 72)
            {
                const int node = tid >> 2, c0 = (tid & 3)*16;
                const int node_g = blk*128 + node;
                const int b = node_g / NN, nloc = node_g - b*NN;
                const float* Xt = X + (size_t)(b*TT + t)*NN*FF;
                float x0 = xn_r[node_g];
                float x1 = Xt[nloc*FF + 13];
                float x2 = Xt[nloc*FF + 14];
                float x3 = Xt[nloc*FF + 15];
                unsigned int* ax32 = (unsigned int*)(sm16 + OFFAS);
                #pragma unroll
                for (int p=0; p<8; p++){
                    int c = c0 + 2*p;
                    float va = dbin[c]   + x0*dWin[c]     + x1*dWin[64+c]   + x2*dWin[128+c]   + x3*dWin[192+c];
                    float vb = dbin[c+1] + x0*dWin[c+1]   + x1*dWin[64+c+1] + x2*dWin[128+c+1] + x3*dWin[192+c+1];
                    ax32[(node*PB72 + c) >> 1] = (unsigned int)f2bf(va) | ((unsigned int)f2bf(vb) << 16);
                }
            }
            __syncthreads();

            f16v accx[3] = {{},{},{}};
            f16v acch[3] = {{},{},{}};
            {
                const int rA = mt*32 + (lane & 31);
                const int ln = lane & 31;
                const int ke = (lane >> 5)*8;
                #pragma unroll
                for (int ks=0; ks<4; ks++){
                    s8v a = *(const s8v*)(sm16 + OFFAS + rA*PB72 + ks*16 + ke);
                    #pragma unroll
                    for (int nt=0; nt<3; nt++){
                        int NT = jt + nt*2;
                        s8v b = *(const s8v*)(sm16 + DOFFBIH + (NT*32 + ln)*PB72 + ks*16 + ke);
                        accx[nt] = __builtin_amdgcn_mfma_f32_32x32x16_bf16(a, b, accx[nt], 0,0,0);
                    }
                }
                #pragma unroll
                for (int ks=0; ks<4; ks++){
                    s8v ah = *(const s8v*)(sm16 + OFFAH + rA*PAS      + ks*16 + ke);
                    s8v al = *(const s8v*)(sm16 + OFFAH + rA*PAS + 64 + ks*16 + ke);
                    #pragma unroll
                    for (int nt=0; nt<3; nt++){
                        int NT = jt + nt*2;
                        s8v b = *(const s8v*)(sm16 + DOFFBHH + (NT*32 + ln)*PB72 + ks*16 + ke);
                        acch[nt] = __builtin_amdgcn_mfma_f32_32x32x16_bf16(ah, b, acch[nt], 0,0,0);
                        acch[nt] = __builtin_amdgcn_mfma_f32_32x32x16_bf16(al, b, acch[nt], 0,0,0);
                    }
                }
            }
            __syncthreads();

            {
                const int j = jt*32 + (lane & 31);
                const float br  = dbih[j]     + dbhh[j];
                const float bz  = dbih[64+j]  + dbhh[64+j];
                const float bin_ = dbih[128+j];
                const float bhn  = dbhh[128+j];
                #pragma unroll
                for (int reg=0; reg<16; reg++){
                    int row = (reg&3) + 8*(reg>>2) + 4*(lane>>5);
                    int node_l = mt*32 + row;
                    unsigned short* hh = sm16 + OFFAH + node_l*PAS + j;
                    float hold = bf2f(hh[0]) + bf2f(hh[64]);
                    float r  = sigf(accx[0][reg] + acch[0][reg] + br);
                    float z  = sigf(accx[1][reg] + acch[1][reg] + bz);
                    float nn = tanhf_(accx[2][reg] + bin_ + r*(acch[2][reg] + bhn));
                    float hp = (1.f - z)*nn + z*hold;
                    unsigned short nh = f2bf(hp);
                    hh[0]  = nh;
                    hh[64] = f2bf(hp - bf2f(nh));
                }
            }
            __syncthreads();

            {
                const int node_l = tid >> 2, q = tid & 3;
                float s = 0.f;
                #pragma unroll
                for (int qq=0; qq<2; qq++){
                    s8v hi = *(const s8v*)(sm16 + OFFAH + node_l*PAS      + q*16 + qq*8);
                    s8v lo = *(const s8v*)(sm16 + OFFAH + node_l*PAS + 64 + q*16 + qq*8);
                    #pragma unroll
                    for (int i=0;i<8;i++){
                        float hv = bf2f((unsigned short)hi[i]) + bf2f((unsigned short)lo[i]);
                        s += hv * dWout[q*16 + qq*8 + i];
                    }
                }
                xs[tid] = s;
            }
            __syncthreads();
            if (tid < 128){
                float v = xs[4*tid] + xs[4*tid+1] + xs[4*tid+2] + xs[4*tid+3] + dbout[0];
                const int node_g = blk*128 + tid;
                const int b = node_g / NN, nloc = node_g - b*NN;
                xn_w[node_g] = v;
                out[(size_t)(b*FC + (t - HIST))*NN + nloc] = v;
            }
        }
        grid.sync();
    }
}

extern "C" void kernel_launch(void* const* d_in, const int* in_sizes, int n_in,
                              void* d_out, int out_size, void* d_ws, size_t ws_size,
                              hipStream_t stream)
{
    const float* X     = (const float*)d_in[0];
    const float* y     = (const float*)d_in[1];
    const int*   ei    = (const int*)  d_in[2];
    const float* ew    = (const float*)d_in[3];
    const float* W_rel = (const float*)d_in[4];
    const float* b_rel = (const float*)d_in[5];
    const float* W_root= (const float*)d_in[6];
    const float* eWih  = (const float*)d_in[7];
    const float* eWhh  = (const float*)d_in[8];
    const float* ebih  = (const float*)d_in[9];
    const float* ebhh  = (const float*)d_in[10];
    const float* eWout = (const float*)d_in[11];
    const float* ebout = (const float*)d_in[12];
    const float* dWin  = (const float*)d_in[13];
    const float* dbin  = (const float*)d_in[14];
    const float* dWih  = (const float*)d_in[15];
    const float* dWhh  = (const float*)d_in[16];
    const float* dbih  = (const float*)d_in[17];
    const float* dbhh  = (const float*)d_in[18];
    const float* dWout = (const float*)d_in[19];
    const float* dbout = (const float*)d_in[20];
    float* out = (float*)d_out;

    // ws: aggs 52.2MB | xn ping-pong 2x128KB | encB 76.8KB | decB 55.3KB
    float* aggs = (float*)d_ws;
    float* x0 = aggs + (size_t)24*17*BN;
    float* x1 = x0 + BN;
    unsigned short* encB = (unsigned short*)(x1 + BN);
    unsigned short* decB = encB + 38400;

    const int* esrc = ei;

    const int smA = (NN*FF + NN)*sizeof(float);
    hipFuncSetAttribute((const void*)agg_pre,
                        hipFuncAttributeMaxDynamicSharedMemorySize, smA);
    hipFuncSetAttribute((const void*)fused_steps,
                        hipFuncAttributeMaxDynamicSharedMemorySize, FU_SMEM);

    prep_weights<<<78, 256, 0, stream>>>(W_rel, W_root, eWih, eWhh, dWih, dWhh, encB, decB);
    agg_pre<<<dim3(BX,24), 1024, smA, stream>>>(X, y, esrc, ew, aggs);

    void* args[] = {
        (void*)&X, (void*)&y, (void*)&esrc, (void*)&ew, (void*)&aggs,
        (void*)&encB, (void*)&decB,
        (void*)&b_rel, (void*)&ebih, (void*)&ebhh, (void*)&eWout, (void*)&ebout,
        (void*)&dbih, (void*)&dbhh, (void*)&dWin, (void*)&dbin, (void*)&dWout, (void*)&dbout,
        (void*)&x0, (void*)&x1, (void*)&out
    };
    hipLaunchCooperativeKernel((const void*)fused_steps, dim3(250), dim3(512),
                               args, FU_SMEM, stream);
}

// Round 10
// 794.459 us; speedup vs baseline: 2.2301x; 2.2301x over previous
//
#include <hip/hip_runtime.h>
#include <cstdint>

#define BX   32
#define NN   1000
#define FF   16
#define TT   48          // HIST + FC
#define HIST 24
#define FC   24
#define HID  64
#define DEG  16
#define BN   (BX*NN)     // 32000 nodes

typedef __attribute__((ext_vector_type(8)))  short s8v;   // bf16x8 MFMA frag (4 VGPR)
typedef __attribute__((ext_vector_type(16))) float f16v;  // 32x32 accumulator

__device__ __forceinline__ float sigf(float x)  { return 1.0f/(1.0f+__expf(-x)); }
__device__ __forceinline__ float tanhf_(float x){ return 2.0f/(1.0f+__expf(-2.0f*x)) - 1.0f; }
__device__ __forceinline__ unsigned short f2bf(float x){
    unsigned int u = __float_as_uint(x);
    return (unsigned short)((u + 0x7FFFu + ((u>>16)&1u)) >> 16);   // RNE
}
__device__ __forceinline__ float bf2f(unsigned short b){
    return __uint_as_float(((unsigned int)b)<<16);
}

// xn moves through agent-scope atomics (coherent at LLC, bypasses per-XCD L2)
// so the inter-step barrier needs NO cache maintenance.
__device__ __forceinline__ void  xn_st(float* p, float v){
    __hip_atomic_store(p, v, __ATOMIC_RELAXED, __HIP_MEMORY_SCOPE_AGENT);
}
__device__ __forceinline__ float xn_ld(const float* p){
    return __hip_atomic_load(p, __ATOMIC_RELAXED, __HIP_MEMORY_SCOPE_AGENT);
}

// flush-free grid barrier: monotonic counter in global, relaxed atomics only.
// __syncthreads() drains vmcnt for all waves (HIP emits s_waitcnt vmcnt(0)
// before s_barrier), so this block's xn stores are LLC-visible before the add.
__device__ __forceinline__ void grid_barrier(unsigned int* bar, unsigned int target){
    __syncthreads();
    if (threadIdx.x == 0){
        asm volatile("s_waitcnt vmcnt(0)" ::: "memory");
        __hip_atomic_fetch_add(bar, 1u, __ATOMIC_RELAXED, __HIP_MEMORY_SCOPE_AGENT);
        while (__hip_atomic_load(bar, __ATOMIC_RELAXED, __HIP_MEMORY_SCOPE_AGENT) < target)
            __builtin_amdgcn_s_sleep(1);
    }
    __syncthreads();
}

// ---------------- one-time: bf16 weight images in LDS-exact layout ----------------
// encB: [B1 64x72 | Bih 192x104 | Bhh 192x72]   decB: [Bihd 192x72 | Bhhd 192x72]
__global__ void prep_weights(
    const float* __restrict__ W_rel, const float* __restrict__ W_root,
    const float* __restrict__ eWih, const float* __restrict__ eWhh,
    const float* __restrict__ dWih, const float* __restrict__ dWhh,
    unsigned short* __restrict__ encB, unsigned short* __restrict__ decB)
{
    const int i = blockIdx.x*256 + threadIdx.x;   // grid covers 192*104 = 19968
    if (i < 64*72){                                // B1[n][k]: k<18 W_rel, 32..49 W_root
        int n = i/72, k = i%72;
        float v = 0.f;
        if (k < 18) v = W_rel[k*64 + n];
        else if (k >= 32 && k < 50) v = W_root[(k-32)*64 + n];
        encB[i] = f2bf(v);
    }
    if (i < 192*104){                              // Bih[n][k]: k<18 xg-part, 32..95 conv-part
        int n = i/104, k = i%104;
        float v = 0.f;
        if (k < 18) v = eWih[n*82 + k];
        else if (k >= 32 && k < 96) v = eWih[n*82 + 18 + (k-32)];
        encB[4608 + i] = f2bf(v);
    }
    if (i < 192*72){                               // Bhh / dec images
        int n = i/72, k = i%72;
        encB[24576 + i] = f2bf((k < 64) ? eWhh[n*64 + k] : 0.f);
        decB[i]         = f2bf((k < 64) ? dWih[n*64 + k] : 0.f);
        decB[13824 + i] = f2bf((k < 64) ? dWhh[n*64 + k] : 0.f);
    }
}

// ---------------- pre-pass: static edge aggregation (R7-proven) ----------------
__global__ __launch_bounds__(1024, 4) void agg_pre(
    const float* __restrict__ X, const float* __restrict__ y,
    const int*   __restrict__ esrc, const float* __restrict__ ew,
    float* __restrict__ aggs)
{
    extern __shared__ float sm[];
    float* Xs = sm;            // [1000][16]
    float* ys = sm + NN*FF;    // [1000]

    const int b = blockIdx.x;
    const int t = blockIdx.y;
    const float* Xt = X + (size_t)(b*TT + t)*NN*FF;
    const float* yt = y + (size_t)(b*TT + t)*NN;

    for (int i = threadIdx.x; i < NN*FF/4; i += 1024)
        ((float4*)Xs)[i] = ((const float4*)Xt)[i];
    for (int i = threadIdx.x; i < NN; i += 1024)
        ys[i] = yt[i];
    __syncthreads();

    const int nl = threadIdx.x;
    if (nl < NN){
        const int node = b*NN + nl;
        float agg[17];
        #pragma unroll
        for (int i=0;i<17;i++) agg[i]=0.f;
        const int4*   sv = (const int4*)  (esrc + node*DEG);
        const float4* wv = (const float4*)(ew   + node*DEG);
        #pragma unroll
        for (int q=0;q<4;q++){
            int4 s4 = sv[q]; float4 w4 = wv[q];
            const int   ss[4] = {s4.x, s4.y, s4.z, s4.w};
            const float ww[4] = {w4.x, w4.y, w4.z, w4.w};
            #pragma unroll
            for (int i=0;i<4;i++){
                const int sl = ss[i] - b*NN;
                const float wgt = ww[i];
                agg[0] += wgt * ys[sl];
                const float4* sr = (const float4*)&Xs[sl*FF];
                #pragma unroll
                for (int q2=0;q2<4;q2++){
                    float4 v = sr[q2];
                    agg[1+4*q2] += wgt*v.x; agg[2+4*q2] += wgt*v.y;
                    agg[3+4*q2] += wgt*v.z; agg[4+4*q2] += wgt*v.w;
                }
            }
        }
        #pragma unroll
        for (int k=0;k<17;k++) aggs[((size_t)t*17 + k)*BN + node] = agg[k];
    }
}

// ---------------- fused persistent kernel: all 24 enc + 24 dec steps ----------------
// 250 blocks x 512 threads (1 block/CU), custom flush-free barrier between steps.
#define OFFB1  0
#define OFFBIH 4608
#define OFFBHH 24576
#define DOFFBIH 0
#define DOFFBHH 13824
#define OFFAS  38400
#define OFFAH  55808
#define FU_SMEM 146432
#define PAS  136
#define PBIH 104
#define PB72 72

__global__ __launch_bounds__(512, 1) void fused_steps(
    const float* __restrict__ X, const float* __restrict__ y,
    const int* __restrict__ esrc, const float* __restrict__ ew,
    const float* __restrict__ aggs,
    const unsigned short* __restrict__ encB, const unsigned short* __restrict__ decB,
    const float* __restrict__ b_rel,
    const float* __restrict__ ebih, const float* __restrict__ ebhh,
    const float* __restrict__ eWout, const float* __restrict__ ebout,
    const float* __restrict__ dbih, const float* __restrict__ dbhh,
    const float* __restrict__ dWin, const float* __restrict__ dbin,
    const float* __restrict__ dWout, const float* __restrict__ dbout,
    float* __restrict__ xnA, float* __restrict__ xnB,
    unsigned int* __restrict__ bar, float* __restrict__ out)
{
    extern __shared__ char smraw[];
    __shared__ float xs[512];
    unsigned short* sm16 = (unsigned short*)smraw;

    const int tid  = threadIdx.x;
    const int lane = tid & 63;
    const int w    = __builtin_amdgcn_readfirstlane(tid >> 6);
    const int mt = w >> 1, jt = w & 1;
    const int blk = blockIdx.x;
    const unsigned int NB = gridDim.x;

    // ---- one-time init: enc weights -> LDS, zero A_h (h=0), zero A_s gap cols ----
    {
        const uint4* src = (const uint4*)encB;
        uint4* dst = (uint4*)smraw;
        for (int i = tid; i < 4800; i += 512) dst[i] = src[i];
        unsigned int* ah32 = (unsigned int*)(sm16 + OFFAH);
        for (int i = tid; i < 8704; i += 512) ah32[i] = 0u;
        unsigned int* as32 = (unsigned int*)(sm16 + OFFAS);
        for (int i = tid; i < 128*14; i += 512){
            int node = i & 127, q = i >> 7;
            int col = (q < 7) ? (18 + 2*q) : (50 + 2*(q-7));
            as32[(node*PAS + col) >> 1] = 0u;
        }
    }

    for (int t = 0; t < TT; ++t){
        const bool enc = (t < HIST);
        const float* xn_r = (t & 1) ? xnB : xnA;
        float*       xn_w = (t & 1) ? xnA : xnB;

        if (enc){
            // ---- P0c: static agg channels -> A_s cols 1..17 ----
            for (int i = tid; i < 128*17; i += 512){
                int node = i & 127, k = i >> 7;
                float v = aggs[((size_t)t*17 + k)*BN + blk*128 + node];
                sm16[OFFAS + node*PAS + 1 + k] = f2bf(v);
            }
            // ---- P0d: xn-gather (col0) + xg (cols 32..49) ----
            if (tid < 128){
                const int node = tid, node_g = blk*128 + node;
                const int b = node_g / NN, nloc = node_g - b*NN;
                const float* Xt = X + (size_t)(b*TT + t)*NN*FF;
                const float* yt = y + (size_t)(b*TT + t)*NN;
                unsigned short* as = sm16 + OFFAS + node*PAS;
                float a0 = 0.f, xnv = 0.f;
                if (t > 0){
                    const int4*   sv = (const int4*)  (esrc + node_g*DEG);
                    const float4* wv = (const float4*)(ew   + node_g*DEG);
                    #pragma unroll
                    for (int q=0;q<4;q++){
                        int4 s4 = sv[q]; float4 w4 = wv[q];
                        a0 += w4.x*xn_ld(xn_r + s4.x) + w4.y*xn_ld(xn_r + s4.y)
                            + w4.z*xn_ld(xn_r + s4.z) + w4.w*xn_ld(xn_r + s4.w);
                    }
                    xnv = xn_ld(xn_r + node_g);
                }
                as[0]  = f2bf(a0);
                as[32] = f2bf(xnv);
                as[33] = f2bf(yt[nloc]);
                const float4* xr = (const float4*)(Xt + nloc*FF);
                #pragma unroll
                for (int q=0;q<4;q++){
                    float4 v = xr[q];
                    as[34+4*q] = f2bf(v.x); as[35+4*q] = f2bf(v.y);
                    as[36+4*q] = f2bf(v.z); as[37+4*q] = f2bf(v.w);
                }
            }
            __syncthreads();

            // ---- P1: GraphConv GEMM -> sigmoid -> A_s cols 64..127 ----
            {
                f16v acc = {};
                const int rA = mt*32 + (lane & 31);
                const int rB = jt*32 + (lane & 31);
                const int ke = (lane >> 5)*8;
                #pragma unroll
                for (int ks=0; ks<4; ks++){
                    s8v a = *(const s8v*)(sm16 + OFFAS + rA*PAS  + ks*16 + ke);
                    s8v b = *(const s8v*)(sm16 + OFFB1 + rB*PB72 + ks*16 + ke);
                    acc = __builtin_amdgcn_mfma_f32_32x32x16_bf16(a, b, acc, 0, 0, 0);
                }
                const int j = jt*32 + (lane & 31);
                const float brl = b_rel[j];
                #pragma unroll
                for (int reg=0; reg<16; reg++){
                    int row = (reg&3) + 8*(reg>>2) + 4*(lane>>5);
                    sm16[OFFAS + (mt*32 + row)*PAS + 64 + j] = f2bf(sigf(acc[reg] + brl));
                }
            }
            __syncthreads();

            // ---- P2: GRU GEMMs ----
            f16v accx[3] = {{},{},{}};
            f16v acch[3] = {{},{},{}};
            {
                const int rA = mt*32 + (lane & 31);
                const int ln = lane & 31;
                const int ke = (lane >> 5)*8;
                #pragma unroll
                for (int ks=0; ks<6; ks++){               // x-GEMM: A_s window [32,128)
                    s8v a = *(const s8v*)(sm16 + OFFAS + rA*PAS + 32 + ks*16 + ke);
                    #pragma unroll
                    for (int nt=0; nt<3; nt++){
                        int NT = jt + nt*2;
                        s8v b = *(const s8v*)(sm16 + OFFBIH + (NT*32 + ln)*PBIH + ks*16 + ke);
                        accx[nt] = __builtin_amdgcn_mfma_f32_32x32x16_bf16(a, b, accx[nt], 0,0,0);
                    }
                }
                #pragma unroll
                for (int ks=0; ks<4; ks++){               // h-GEMM: hi + lo passes
                    s8v ah = *(const s8v*)(sm16 + OFFAH + rA*PAS      + ks*16 + ke);
                    s8v al = *(const s8v*)(sm16 + OFFAH + rA*PAS + 64 + ks*16 + ke);
                    #pragma unroll
                    for (int nt=0; nt<3; nt++){
                        int NT = jt + nt*2;
                        s8v b = *(const s8v*)(sm16 + OFFBHH + (NT*32 + ln)*PB72 + ks*16 + ke);
                        acch[nt] = __builtin_amdgcn_mfma_f32_32x32x16_bf16(ah, b, acch[nt], 0,0,0);
                        acch[nt] = __builtin_amdgcn_mfma_f32_32x32x16_bf16(al, b, acch[nt], 0,0,0);
                    }
                }
            }
            __syncthreads();                              // all A_h reads done

            // ---- P3: epilogue; h' written back to A_h (hi/lo) in place ----
            {
                const int j = jt*32 + (lane & 31);
                const float br  = ebih[j]     + ebhh[j];
                const float bz  = ebih[64+j]  + ebhh[64+j];
                const float bin_ = ebih[128+j];
                const float bhn  = ebhh[128+j];
                #pragma unroll
                for (int reg=0; reg<16; reg++){
                    int row = (reg&3) + 8*(reg>>2) + 4*(lane>>5);
                    int node_l = mt*32 + row;
                    unsigned short* hh = sm16 + OFFAH + node_l*PAS + j;
                    float hold = bf2f(hh[0]) + bf2f(hh[64]);
                    float r  = sigf(accx[0][reg] + acch[0][reg] + br);
                    float z  = sigf(accx[1][reg] + acch[1][reg] + bz);
                    float nn = tanhf_(accx[2][reg] + bin_ + r*(acch[2][reg] + bhn));
                    float hp = (1.f - z)*nn + z*hold;
                    unsigned short nh = f2bf(hp);
                    hh[0]  = nh;
                    hh[64] = f2bf(hp - bf2f(nh));
                }
            }
            __syncthreads();

            // ---- P4: xn = h' @ Wout + bout ----
            {
                const int node_l = tid >> 2, q = tid & 3;
                float s = 0.f;
                #pragma unroll
                for (int qq=0; qq<2; qq++){
                    s8v hi = *(const s8v*)(sm16 + OFFAH + node_l*PAS      + q*16 + qq*8);
                    s8v lo = *(const s8v*)(sm16 + OFFAH + node_l*PAS + 64 + q*16 + qq*8);
                    #pragma unroll
                    for (int i=0;i<8;i++){
                        float hv = bf2f((unsigned short)hi[i]) + bf2f((unsigned short)lo[i]);
                        s += hv * eWout[q*16 + qq*8 + i];
                    }
                }
                xs[tid] = s;
            }
            __syncthreads();
            if (tid < 128)
                xn_st(xn_w + blk*128 + tid,
                      xs[4*tid] + xs[4*tid+1] + xs[4*tid+2] + xs[4*tid+3] + ebout[0]);
        } else {
            // ---- decoder ----
            if (t == HIST){                               // overlay dec weights once
                const uint4* src = (const uint4*)decB;
                uint4* dst = (uint4*)smraw;
                for (int i = tid; i < 3456; i += 512) dst[i] = src[i];
            }
            // P0b: xin = [xn|X13..15] @ Win + bin -> A_x (pitch 72)
            {
                const int node = tid >> 2, c0 = (tid & 3)*16;
                const int node_g = blk*128 + node;
                const int b = node_g / NN, nloc = node_g - b*NN;
                const float* Xt = X + (size_t)(b*TT + t)*NN*FF;
                float x0 = xn_ld(xn_r + node_g);
                float x1 = Xt[nloc*FF + 13];
                float x2 = Xt[nloc*FF + 14];
                float x3 = Xt[nloc*FF + 15];
                unsigned int* ax32 = (unsigned int*)(sm16 + OFFAS);
                #pragma unroll
                for (int p=0; p<8; p++){
                    int c = c0 + 2*p;
                    float va = dbin[c]   + x0*dWin[c]     + x1*dWin[64+c]   + x2*dWin[128+c]   + x3*dWin[192+c];
                    float vb = dbin[c+1] + x0*dWin[c+1]   + x1*dWin[64+c+1] + x2*dWin[128+c+1] + x3*dWin[192+c+1];
                    ax32[(node*PB72 + c) >> 1] = (unsigned int)f2bf(va) | ((unsigned int)f2bf(vb) << 16);
                }
            }
            __syncthreads();

            f16v accx[3] = {{},{},{}};
            f16v acch[3] = {{},{},{}};
            {
                const int rA = mt*32 + (lane & 31);
                const int ln = lane & 31;
                const int ke = (lane >> 5)*8;
                #pragma unroll
                for (int ks=0; ks<4; ks++){
                    s8v a = *(const s8v*)(sm16 + OFFAS + rA*PB72 + ks*16 + ke);
                    #pragma unroll
                    for (int nt=0; nt<3; nt++){
                        int NT = jt + nt*2;
                        s8v b = *(const s8v*)(sm16 + DOFFBIH + (NT*32 + ln)*PB72 + ks*16 + ke);
                        accx[nt] = __builtin_amdgcn_mfma_f32_32x32x16_bf16(a, b, accx[nt], 0,0,0);
                    }
                }
                #pragma unroll
                for (int ks=0; ks<4; ks++){
                    s8v ah = *(const s8v*)(sm16 + OFFAH + rA*PAS      + ks*16 + ke);
                    s8v al = *(const s8v*)(sm16 + OFFAH + rA*PAS + 64 + ks*16 + ke);
                    #pragma unroll
                    for (int nt=0; nt<3; nt++){
                        int NT = jt + nt*2;
                        s8v b = *(const s8v*)(sm16 + DOFFBHH + (NT*32 + ln)*PB72 + ks*16 + ke);
                        acch[nt] = __builtin_amdgcn_mfma_f32_32x32x16_bf16(ah, b, acch[nt], 0,0,0);
                        acch[nt] = __builtin_amdgcn_mfma_f32_32x32x16_bf16(al, b, acch[nt], 0,0,0);
                    }
                }
            }
            __syncthreads();

            {
                const int j = jt*32 + (lane & 31);
                const float br  = dbih[j]     + dbhh[j];
                const float bz  = dbih[64+j]  + dbhh[64+j];
                const float bin_ = dbih[128+j];
                const float bhn  = dbhh[128+j];
                #pragma unroll
                for (int reg=0; reg<16; reg++){
                    int row = (reg&3) + 8*(reg>>2) + 4*(lane>>5);
                    int node_l = mt*32 + row;
                    unsigned short* hh = sm16 + OFFAH + node_l*PAS + j;
                    float hold = bf2f(hh[0]) + bf2f(hh[64]);
                    float r  = sigf(accx[0][reg] + acch[0][reg] + br);
                    float z  = sigf(accx[1][reg] + acch[1][reg] + bz);
                    float nn = tanhf_(accx[2][reg] + bin_ + r*(acch[2][reg] + bhn));
                    float hp = (1.f - z)*nn + z*hold;
                    unsigned short nh = f2bf(hp);
                    hh[0]  = nh;
                    hh[64] = f2bf(hp - bf2f(nh));
                }
            }
            __syncthreads();

            {
                const int node_l = tid >> 2, q = tid & 3;
                float s = 0.f;
                #pragma unroll
                for (int qq=0; qq<2; qq++){
                    s8v hi = *(const s8v*)(sm16 + OFFAH + node_l*PAS      + q*16 + qq*8);
                    s8v lo = *(const s8v*)(sm16 + OFFAH + node_l*PAS + 64 + q*16 + qq*8);
                    #pragma unroll
                    for (int i=0;i<8;i++){
                        float hv = bf2f((unsigned short)hi[i]) + bf2f((unsigned short)lo[i]);
                        s += hv * dWout[q*16 + qq*8 + i];
                    }
                }
                xs[tid] = s;
            }
            __syncthreads();
            if (tid < 128){
                float v = xs[4*tid] + xs[4*tid+1] + xs[4*tid+2] + xs[4*tid+3] + dbout[0];
                const int node_g = blk*128 + tid;
                const int b = node_g / NN, nloc = node_g - b*NN;
                xn_st(xn_w + node_g, v);
                out[(size_t)(b*FC + (t - HIST))*NN + nloc] = v;
            }
        }
        if (t < TT-1) grid_barrier(bar, NB*(unsigned)(t+1));
    }
}

extern "C" void kernel_launch(void* const* d_in, const int* in_sizes, int n_in,
                              void* d_out, int out_size, void* d_ws, size_t ws_size,
                              hipStream_t stream)
{
    const float* X     = (const float*)d_in[0];
    const float* y     = (const float*)d_in[1];
    const int*   ei    = (const int*)  d_in[2];
    const float* ew    = (const float*)d_in[3];
    const float* W_rel = (const float*)d_in[4];
    const float* b_rel = (const float*)d_in[5];
    const float* W_root= (const float*)d_in[6];
    const float* eWih  = (const float*)d_in[7];
    const float* eWhh  = (const float*)d_in[8];
    const float* ebih  = (const float*)d_in[9];
    const float* ebhh  = (const float*)d_in[10];
    const float* eWout = (const float*)d_in[11];
    const float* ebout = (const float*)d_in[12];
    const float* dWin  = (const float*)d_in[13];
    const float* dbin  = (const float*)d_in[14];
    const float* dWih  = (const float*)d_in[15];
    const float* dWhh  = (const float*)d_in[16];
    const float* dbih  = (const float*)d_in[17];
    const float* dbhh  = (const float*)d_in[18];
    const float* dWout = (const float*)d_in[19];
    const float* dbout = (const float*)d_in[20];
    float* out = (float*)d_out;

    // ws: aggs 52.2MB | xn ping-pong 2x128KB | encB 76.8KB | decB 55.3KB | barrier 4B
    float* aggs = (float*)d_ws;
    float* x0 = aggs + (size_t)24*17*BN;
    float* x1 = x0 + BN;
    unsigned short* encB = (unsigned short*)(x1 + BN);
    unsigned short* decB = encB + 38400;
    unsigned int* bar = (unsigned int*)(decB + 27648);

    const int* esrc = ei;

    const int smA = (NN*FF + NN)*sizeof(float);
    hipFuncSetAttribute((const void*)agg_pre,
                        hipFuncAttributeMaxDynamicSharedMemorySize, smA);
    hipFuncSetAttribute((const void*)fused_steps,
                        hipFuncAttributeMaxDynamicSharedMemorySize, FU_SMEM);

    hipMemsetAsync(bar, 0, sizeof(unsigned int), stream);
    prep_weights<<<78, 256, 0, stream>>>(W_rel, W_root, eWih, eWhh, dWih, dWhh, encB, decB);
    agg_pre<<<dim3(BX,24), 1024, smA, stream>>>(X, y, esrc, ew, aggs);

    void* args[] = {
        (void*)&X, (void*)&y, (void*)&esrc, (void*)&ew, (void*)&aggs,
        (void*)&encB, (void*)&decB,
        (void*)&b_rel, (void*)&ebih, (void*)&ebhh, (void*)&eWout, (void*)&ebout,
        (void*)&dbih, (void*)&dbhh, (void*)&dWin, (void*)&dbin, (void*)&dWout, (void*)&dbout,
        (void*)&x0, (void*)&x1, (void*)&bar, (void*)&out
    };
    hipLaunchCooperativeKernel((const void*)fused_steps, dim3(250), dim3(512),
                               args, FU_SMEM, stream);
}

// Round 11
// 543.443 us; speedup vs baseline: 3.2602x; 1.4619x over previous
//
#include <hip/hip_runtime.h>
#include <cstdint>

#define BX   32
#define NN   1000
#define FF   16
#define TT   48          // HIST + FC
#define HIST 24
#define FC   24
#define HID  64
#define DEG  16
#define BN   (BX*NN)     // 32000 nodes

typedef __attribute__((ext_vector_type(8)))  short s8v;   // bf16x8 MFMA frag (4 VGPR)
typedef __attribute__((ext_vector_type(16))) float f16v;  // 32x32 accumulator

__device__ __forceinline__ float sigf(float x)  { return 1.0f/(1.0f+__expf(-x)); }
__device__ __forceinline__ float tanhf_(float x){ return 2.0f/(1.0f+__expf(-2.0f*x)) - 1.0f; }
__device__ __forceinline__ unsigned short f2bf(float x){
    unsigned int u = __float_as_uint(x);
    return (unsigned short)((u + 0x7FFFu + ((u>>16)&1u)) >> 16);   // RNE
}
__device__ __forceinline__ float bf2f(unsigned short b){
    return __uint_as_float(((unsigned int)b)<<16);
}

// xn moves through agent-scope atomics (coherent at LLC, bypasses per-XCD L2).
__device__ __forceinline__ void  xn_st(float* p, float v){
    __hip_atomic_store(p, v, __ATOMIC_RELAXED, __HIP_MEMORY_SCOPE_AGENT);
}
__device__ __forceinline__ float xn_ld(const float* p){
    return __hip_atomic_load(p, __ATOMIC_RELAXED, __HIP_MEMORY_SCOPE_AGENT);
}

// flush-free PER-BATCH barrier (8 blocks), monotonic counter, relaxed atomics.
__device__ __forceinline__ void batch_barrier(unsigned int* bar, unsigned int target){
    __syncthreads();
    if (threadIdx.x == 0){
        asm volatile("s_waitcnt vmcnt(0)" ::: "memory");
        __hip_atomic_fetch_add(bar, 1u, __ATOMIC_RELAXED, __HIP_MEMORY_SCOPE_AGENT);
        while (__hip_atomic_load(bar, __ATOMIC_RELAXED, __HIP_MEMORY_SCOPE_AGENT) < target)
            __builtin_amdgcn_s_sleep(1);
    }
    __syncthreads();
}

// ---------------- one-time: bf16 weight images in LDS-exact layout ----------------
// encB: [B1 64x72 | Bih 192x104 | Bhh 192x72]   decB: [Bihd 192x72 | Bhhd 192x72]
__global__ void prep_weights(
    const float* __restrict__ W_rel, const float* __restrict__ W_root,
    const float* __restrict__ eWih, const float* __restrict__ eWhh,
    const float* __restrict__ dWih, const float* __restrict__ dWhh,
    unsigned short* __restrict__ encB, unsigned short* __restrict__ decB)
{
    const int i = blockIdx.x*256 + threadIdx.x;   // grid covers 192*104 = 19968
    if (i < 64*72){                                // B1[n][k]: k<18 W_rel, 32..49 W_root
        int n = i/72, k = i%72;
        float v = 0.f;
        if (k < 18) v = W_rel[k*64 + n];
        else if (k >= 32 && k < 50) v = W_root[(k-32)*64 + n];
        encB[i] = f2bf(v);
    }
    if (i < 192*104){                              // Bih[n][k]: k<18 xg-part, 32..95 conv-part
        int n = i/104, k = i%104;
        float v = 0.f;
        if (k < 18) v = eWih[n*82 + k];
        else if (k >= 32 && k < 96) v = eWih[n*82 + 18 + (k-32)];
        encB[4608 + i] = f2bf(v);
    }
    if (i < 192*72){                               // Bhh / dec images
        int n = i/72, k = i%72;
        encB[24576 + i] = f2bf((k < 64) ? eWhh[n*64 + k] : 0.f);
        decB[i]         = f2bf((k < 64) ? dWih[n*64 + k] : 0.f);
        decB[13824 + i] = f2bf((k < 64) ? dWhh[n*64 + k] : 0.f);
    }
}

// ---------------- pre-pass: static edge aggregation -> bf16 ----------------
__global__ __launch_bounds__(1024, 4) void agg_pre(
    const float* __restrict__ X, const float* __restrict__ y,
    const int*   __restrict__ esrc, const float* __restrict__ ew,
    unsigned short* __restrict__ aggsbf)
{
    extern __shared__ float sm[];
    float* Xs = sm;            // [1000][16]
    float* ys = sm + NN*FF;    // [1000]

    const int b = blockIdx.x;
    const int t = blockIdx.y;
    const float* Xt = X + (size_t)(b*TT + t)*NN*FF;
    const float* yt = y + (size_t)(b*TT + t)*NN;

    for (int i = threadIdx.x; i < NN*FF/4; i += 1024)
        ((float4*)Xs)[i] = ((const float4*)Xt)[i];
    for (int i = threadIdx.x; i < NN; i += 1024)
        ys[i] = yt[i];
    __syncthreads();

    const int nl = threadIdx.x;
    if (nl < NN){
        const int node = b*NN + nl;
        float agg[17];
        #pragma unroll
        for (int i=0;i<17;i++) agg[i]=0.f;
        const int4*   sv = (const int4*)  (esrc + node*DEG);
        const float4* wv = (const float4*)(ew   + node*DEG);
        #pragma unroll
        for (int q=0;q<4;q++){
            int4 s4 = sv[q]; float4 w4 = wv[q];
            const int   ss[4] = {s4.x, s4.y, s4.z, s4.w};
            const float ww[4] = {w4.x, w4.y, w4.z, w4.w};
            #pragma unroll
            for (int i=0;i<4;i++){
                const int sl = ss[i] - b*NN;
                const float wgt = ww[i];
                agg[0] += wgt * ys[sl];
                const float4* sr = (const float4*)&Xs[sl*FF];
                #pragma unroll
                for (int q2=0;q2<4;q2++){
                    float4 v = sr[q2];
                    agg[1+4*q2] += wgt*v.x; agg[2+4*q2] += wgt*v.y;
                    agg[3+4*q2] += wgt*v.z; agg[4+4*q2] += wgt*v.w;
                }
            }
        }
        #pragma unroll
        for (int k=0;k<17;k++) aggsbf[((size_t)t*17 + k)*BN + node] = f2bf(agg[k]);
    }
}

// ---------------- fused persistent kernel ----------------
// 256 blocks = 32 batches x 8 sub-blocks; per-batch barrier (enc only);
// decoder is fully block-local (xn in LDS, zero grid sync).
#define OFFB1  0
#define OFFBIH 4608
#define OFFBHH 24576
#define DOFFBIH 0
#define DOFFBHH 13824
#define OFFAS  38400
#define OFFAH  55808
#define FU_SMEM 146432
#define PAS  136
#define PBIH 104
#define PB72 72

__global__ __launch_bounds__(512, 1) void fused_steps(
    const float* __restrict__ X, const float* __restrict__ y,
    const int* __restrict__ esrc, const float* __restrict__ ew,
    const unsigned short* __restrict__ aggsbf,
    const unsigned short* __restrict__ encB, const unsigned short* __restrict__ decB,
    const float* __restrict__ b_rel,
    const float* __restrict__ ebih, const float* __restrict__ ebhh,
    const float* __restrict__ eWout, const float* __restrict__ ebout,
    const float* __restrict__ dbih, const float* __restrict__ dbhh,
    const float* __restrict__ dWin, const float* __restrict__ dbin,
    const float* __restrict__ dWout, const float* __restrict__ dbout,
    float* __restrict__ xnA, float* __restrict__ xnB,
    unsigned int* __restrict__ bar, float* __restrict__ out)
{
    extern __shared__ char smraw[];
    __shared__ float xs[512];
    __shared__ float xnL[128];
    unsigned short* sm16 = (unsigned short*)smraw;

    const int tid  = threadIdx.x;
    const int lane = tid & 63;
    const int w    = __builtin_amdgcn_readfirstlane(tid >> 6);
    const int mt = w >> 1, jt = w & 1;
    const int batch = blockIdx.x >> 3;           // 0..31
    const int sub   = blockIdx.x & 7;            // 0..7  (nodes sub*128 .. )
    unsigned int* mybar = bar + batch*32;        // 128B-separated counters

    // ---- one-time init: enc weights -> LDS, zero A_h (h=0), zero A_s gap cols ----
    {
        const uint4* src = (const uint4*)encB;
        uint4* dst = (uint4*)smraw;
        for (int i = tid; i < 4800; i += 512) dst[i] = src[i];
        unsigned int* ah32 = (unsigned int*)(sm16 + OFFAH);
        for (int i = tid; i < 8704; i += 512) ah32[i] = 0u;
        unsigned int* as32 = (unsigned int*)(sm16 + OFFAS);
        for (int i = tid; i < 128*14; i += 512){
            int node = i & 127, q = i >> 7;
            int col = (q < 7) ? (18 + 2*q) : (50 + 2*(q-7));
            as32[(node*PAS + col) >> 1] = 0u;
        }
    }

    for (int t = 0; t < TT; ++t){
        const bool enc = (t < HIST);
        const float* xn_r = (t & 1) ? xnB : xnA;
        float*       xn_w = (t & 1) ? xnA : xnB;

        if (enc){
            // ---- P0c: static agg channels (bf16) -> A_s cols 1..17 ----
            for (int i = tid; i < 128*17; i += 512){
                int node = i & 127, k = i >> 7;
                int nl2 = sub*128 + node;
                int nc  = (nl2 < NN) ? nl2 : NN-1;
                sm16[OFFAS + node*PAS + 1 + k] =
                    aggsbf[((size_t)t*17 + k)*BN + batch*NN + nc];
            }
            // ---- P0d: xn-gather (col0) + xg (cols 32..49) ----
            if (tid < 128){
                const int node = tid;
                const int nl2 = sub*128 + node;
                const int nc  = (nl2 < NN) ? nl2 : NN-1;
                const int node_g = batch*NN + nc;
                const float* Xt = X + (size_t)(batch*TT + t)*NN*FF;
                const float* yt = y + (size_t)(batch*TT + t)*NN;
                unsigned short* as = sm16 + OFFAS + node*PAS;
                float a0 = 0.f, xnv = 0.f;
                if (t > 0){
                    const int4*   sv = (const int4*)  (esrc + node_g*DEG);
                    const float4* wv = (const float4*)(ew   + node_g*DEG);
                    #pragma unroll
                    for (int q=0;q<4;q++){
                        int4 s4 = sv[q]; float4 w4 = wv[q];
                        a0 += w4.x*xn_ld(xn_r + s4.x) + w4.y*xn_ld(xn_r + s4.y)
                            + w4.z*xn_ld(xn_r + s4.z) + w4.w*xn_ld(xn_r + s4.w);
                    }
                    xnv = xn_ld(xn_r + node_g);
                }
                as[0]  = f2bf(a0);
                as[32] = f2bf(xnv);
                as[33] = f2bf(yt[nc]);
                const float4* xr = (const float4*)(Xt + nc*FF);
                #pragma unroll
                for (int q=0;q<4;q++){
                    float4 v = xr[q];
                    as[34+4*q] = f2bf(v.x); as[35+4*q] = f2bf(v.y);
                    as[36+4*q] = f2bf(v.z); as[37+4*q] = f2bf(v.w);
                }
            }
            __syncthreads();

            // ---- P1: GraphConv GEMM -> sigmoid -> A_s cols 64..127 ----
            {
                f16v acc = {};
                const int rA = mt*32 + (lane & 31);
                const int rB = jt*32 + (lane & 31);
                const int ke = (lane >> 5)*8;
                #pragma unroll
                for (int ks=0; ks<4; ks++){
                    s8v a = *(const s8v*)(sm16 + OFFAS + rA*PAS  + ks*16 + ke);
                    s8v b = *(const s8v*)(sm16 + OFFB1 + rB*PB72 + ks*16 + ke);
                    acc = __builtin_amdgcn_mfma_f32_32x32x16_bf16(a, b, acc, 0, 0, 0);
                }
                const int j = jt*32 + (lane & 31);
                const float brl = b_rel[j];
                #pragma unroll
                for (int reg=0; reg<16; reg++){
                    int row = (reg&3) + 8*(reg>>2) + 4*(lane>>5);
                    sm16[OFFAS + (mt*32 + row)*PAS + 64 + j] = f2bf(sigf(acc[reg] + brl));
                }
            }
            __syncthreads();

            // ---- P2: GRU GEMMs ----
            f16v accx[3] = {{},{},{}};
            f16v acch[3] = {{},{},{}};
            {
                const int rA = mt*32 + (lane & 31);
                const int ln = lane & 31;
                const int ke = (lane >> 5)*8;
                #pragma unroll
                for (int ks=0; ks<6; ks++){               // x-GEMM: A_s window [32,128)
                    s8v a = *(const s8v*)(sm16 + OFFAS + rA*PAS + 32 + ks*16 + ke);
                    #pragma unroll
                    for (int nt=0; nt<3; nt++){
                        int NT = jt + nt*2;
                        s8v b = *(const s8v*)(sm16 + OFFBIH + (NT*32 + ln)*PBIH + ks*16 + ke);
                        accx[nt] = __builtin_amdgcn_mfma_f32_32x32x16_bf16(a, b, accx[nt], 0,0,0);
                    }
                }
                #pragma unroll
                for (int ks=0; ks<4; ks++){               // h-GEMM: hi + lo passes
                    s8v ah = *(const s8v*)(sm16 + OFFAH + rA*PAS      + ks*16 + ke);
                    s8v al = *(const s8v*)(sm16 + OFFAH + rA*PAS + 64 + ks*16 + ke);
                    #pragma unroll
                    for (int nt=0; nt<3; nt++){
                        int NT = jt + nt*2;
                        s8v b = *(const s8v*)(sm16 + OFFBHH + (NT*32 + ln)*PB72 + ks*16 + ke);
                        acch[nt] = __builtin_amdgcn_mfma_f32_32x32x16_bf16(ah, b, acch[nt], 0,0,0);
                        acch[nt] = __builtin_amdgcn_mfma_f32_32x32x16_bf16(al, b, acch[nt], 0,0,0);
                    }
                }
            }
            __syncthreads();                              // all A_h reads done

            // ---- P3: epilogue; h' written back to A_h (hi/lo) in place ----
            {
                const int j = jt*32 + (lane & 31);
                const float br  = ebih[j]     + ebhh[j];
                const float bz  = ebih[64+j]  + ebhh[64+j];
                const float bin_ = ebih[128+j];
                const float bhn  = ebhh[128+j];
                #pragma unroll
                for (int reg=0; reg<16; reg++){
                    int row = (reg&3) + 8*(reg>>2) + 4*(lane>>5);
                    int node_l = mt*32 + row;
                    unsigned short* hh = sm16 + OFFAH + node_l*PAS + j;
                    float hold = bf2f(hh[0]) + bf2f(hh[64]);
                    float r  = sigf(accx[0][reg] + acch[0][reg] + br);
                    float z  = sigf(accx[1][reg] + acch[1][reg] + bz);
                    float nn = tanhf_(accx[2][reg] + bin_ + r*(acch[2][reg] + bhn));
                    float hp = (1.f - z)*nn + z*hold;
                    unsigned short nh = f2bf(hp);
                    hh[0]  = nh;
                    hh[64] = f2bf(hp - bf2f(nh));
                }
            }
            __syncthreads();

            // ---- P4: xn = h' @ Wout + bout ----
            {
                const int node_l = tid >> 2, q = tid & 3;
                float s = 0.f;
                #pragma unroll
                for (int qq=0; qq<2; qq++){
                    s8v hi = *(const s8v*)(sm16 + OFFAH + node_l*PAS      + q*16 + qq*8);
                    s8v lo = *(const s8v*)(sm16 + OFFAH + node_l*PAS + 64 + q*16 + qq*8);
                    #pragma unroll
                    for (int i=0;i<8;i++){
                        float hv = bf2f((unsigned short)hi[i]) + bf2f((unsigned short)lo[i]);
                        s += hv * eWout[q*16 + qq*8 + i];
                    }
                }
                xs[tid] = s;
            }
            __syncthreads();
            if (tid < 128 && sub*128 + tid < NN)
                xn_st(xn_w + batch*NN + sub*128 + tid,
                      xs[4*tid] + xs[4*tid+1] + xs[4*tid+2] + xs[4*tid+3] + ebout[0]);
        } else {
            // ---- decoder (block-local; no grid sync) ----
            if (t == HIST){                               // overlay dec weights once
                const uint4* src = (const uint4*)decB;
                uint4* dst = (uint4*)smraw;
                for (int i = tid; i < 3456; i += 512) dst[i] = src[i];
            }
            // P0b: xin = [xn|X13..15] @ Win + bin -> A_x (pitch 72)
            {
                const int node = tid >> 2, c0 = (tid & 3)*16;
                const int nl2 = sub*128 + node;
                const int nc  = (nl2 < NN) ? nl2 : NN-1;
                const float* Xt = X + (size_t)(batch*TT + t)*NN*FF;
                float x0 = (t == HIST) ? xn_ld(xn_r + batch*NN + nc) : xnL[node];
                float x1 = Xt[nc*FF + 13];
                float x2 = Xt[nc*FF + 14];
                float x3 = Xt[nc*FF + 15];
                unsigned int* ax32 = (unsigned int*)(sm16 + OFFAS);
                #pragma unroll
                for (int p=0; p<8; p++){
                    int c = c0 + 2*p;
                    float va = dbin[c]   + x0*dWin[c]     + x1*dWin[64+c]   + x2*dWin[128+c]   + x3*dWin[192+c];
                    float vb = dbin[c+1] + x0*dWin[c+1]   + x1*dWin[64+c+1] + x2*dWin[128+c+1] + x3*dWin[192+c+1];
                    ax32[(node*PB72 + c) >> 1] = (unsigned int)f2bf(va) | ((unsigned int)f2bf(vb) << 16);
                }
            }
            __syncthreads();

            f16v accx[3] = {{},{},{}};
            f16v acch[3] = {{},{},{}};
            {
                const int rA = mt*32 + (lane & 31);
                const int ln = lane & 31;
                const int ke = (lane >> 5)*8;
                #pragma unroll
                for (int ks=0; ks<4; ks++){
                    s8v a = *(const s8v*)(sm16 + OFFAS + rA*PB72 + ks*16 + ke);
                    #pragma unroll
                    for (int nt=0; nt<3; nt++){
                        int NT = jt + nt*2;
                        s8v b = *(const s8v*)(sm16 + DOFFBIH + (NT*32 + ln)*PB72 + ks*16 + ke);
                        accx[nt] = __builtin_amdgcn_mfma_f32_32x32x16_bf16(a, b, accx[nt], 0,0,0);
                    }
                }
                #pragma unroll
                for (int ks=0; ks<4; ks++){
                    s8v ah = *(const s8v*)(sm16 + OFFAH + rA*PAS      + ks*16 + ke);
                    s8v al = *(const s8v*)(sm16 + OFFAH + rA*PAS + 64 + ks*16 + ke);
                    #pragma unroll
                    for (int nt=0; nt<3; nt++){
                        int NT = jt + nt*2;
                        s8v b = *(const s8v*)(sm16 + DOFFBHH + (NT*32 + ln)*PB72 + ks*16 + ke);
                        acch[nt] = __builtin_amdgcn_mfma_f32_32x32x16_bf16(ah, b, acch[nt], 0,0,0);
                        acch[nt] = __builtin_amdgcn_mfma_f32_32x32x16_bf16(al, b, acch[nt], 0,0,0);
                    }
                }
            }
            __syncthreads();

            {
                const int j = jt*32 + (lane & 31);
                const float br  = dbih[j]     + dbhh[j];
                const float bz  = dbih[64+j]  + dbhh[64+j];
                const float bin_ = dbih[128+j];
                const float bhn  = dbhh[128+j];
                #pragma unroll
                for (int reg=0; reg<16; reg++){
                    int row = (reg&3) + 8*(reg>>2) + 4*(lane>>5);
                    int node_l = mt*32 + row;
                    unsigned short* hh = sm16 + OFFAH + node_l*PAS + j;
                    float hold = bf2f(hh[0]) + bf2f(hh[64]);
                    float r  = sigf(accx[0][reg] + acch[0][reg] + br);
                    float z  = sigf(accx[1][reg] + acch[1][reg] + bz);
                    float nn = tanhf_(accx[2][reg] + bin_ + r*(acch[2][reg] + bhn));
                    float hp = (1.f - z)*nn + z*hold;
                    unsigned short nh = f2bf(hp);
                    hh[0]  = nh;
                    hh[64] = f2bf(hp - bf2f(nh));
                }
            }
            __syncthreads();

            {
                const int node_l = tid >> 2, q = tid & 3;
                float s = 0.f;
                #pragma unroll
                for (int qq=0; qq<2; qq++){
                    s8v hi = *(const s8v*)(sm16 + OFFAH + node_l*PAS      + q*16 + qq*8);
                    s8v lo = *(const s8v*)(sm16 + OFFAH + node_l*PAS + 64 + q*16 + qq*8);
                    #pragma unroll
                    for (int i=0;i<8;i++){
                        float hv = bf2f((unsigned short)hi[i]) + bf2f((unsigned short)lo[i]);
                        s += hv * dWout[q*16 + qq*8 + i];
                    }
                }
                xs[tid] = s;
            }
            __syncthreads();
            if (tid < 128){
                float v = xs[4*tid] + xs[4*tid+1] + xs[4*tid+2] + xs[4*tid+3] + dbout[0];
                xnL[tid] = v;
                const int nl2 = sub*128 + tid;
                if (nl2 < NN)
                    out[(size_t)(batch*FC + (t - HIST))*NN + nl2] = v;
            }
        }
        // sync: per-batch barrier between encoder steps; local sync otherwise
        if (t < HIST-1) batch_barrier(mybar, 8u*(unsigned)(t+1));
        else            __syncthreads();
    }
}

extern "C" void kernel_launch(void* const* d_in, const int* in_sizes, int n_in,
                              void* d_out, int out_size, void* d_ws, size_t ws_size,
                              hipStream_t stream)
{
    const float* X     = (const float*)d_in[0];
    const float* y     = (const float*)d_in[1];
    const int*   ei    = (const int*)  d_in[2];
    const float* ew    = (const float*)d_in[3];
    const float* W_rel = (const float*)d_in[4];
    const float* b_rel = (const float*)d_in[5];
    const float* W_root= (const float*)d_in[6];
    const float* eWih  = (const float*)d_in[7];
    const float* eWhh  = (const float*)d_in[8];
    const float* ebih  = (const float*)d_in[9];
    const float* ebhh  = (const float*)d_in[10];
    const float* eWout = (const float*)d_in[11];
    const float* ebout = (const float*)d_in[12];
    const float* dWin  = (const float*)d_in[13];
    const float* dbin  = (const float*)d_in[14];
    const float* dWih  = (const float*)d_in[15];
    const float* dWhh  = (const float*)d_in[16];
    const float* dbih  = (const float*)d_in[17];
    const float* dbhh  = (const float*)d_in[18];
    const float* dWout = (const float*)d_in[19];
    const float* dbout = (const float*)d_in[20];
    float* out = (float*)d_out;

    // ws: aggsbf 26.1MB | xn ping-pong 2x128KB | encB 76.8KB | decB 55.3KB | bar 4KB
    unsigned short* aggsbf = (unsigned short*)d_ws;
    float* x0 = (float*)(aggsbf + (size_t)24*17*BN);
    float* x1 = x0 + BN;
    unsigned short* encB = (unsigned short*)(x1 + BN);
    unsigned short* decB = encB + 38400;
    unsigned int* bar = (unsigned int*)(decB + 27648);

    const int* esrc = ei;

    const int smA = (NN*FF + NN)*sizeof(float);
    hipFuncSetAttribute((const void*)agg_pre,
                        hipFuncAttributeMaxDynamicSharedMemorySize, smA);
    hipFuncSetAttribute((const void*)fused_steps,
                        hipFuncAttributeMaxDynamicSharedMemorySize, FU_SMEM);

    hipMemsetAsync(bar, 0, 32*32*sizeof(unsigned int), stream);
    prep_weights<<<78, 256, 0, stream>>>(W_rel, W_root, eWih, eWhh, dWih, dWhh, encB, decB);
    agg_pre<<<dim3(BX,24), 1024, smA, stream>>>(X, y, esrc, ew, aggsbf);

    void* args[] = {
        (void*)&X, (void*)&y, (void*)&esrc, (void*)&ew, (void*)&aggsbf,
        (void*)&encB, (void*)&decB,
        (void*)&b_rel, (void*)&ebih, (void*)&ebhh, (void*)&eWout, (void*)&ebout,
        (void*)&dbih, (void*)&dbhh, (void*)&dWin, (void*)&dbin, (void*)&dWout, (void*)&dbout,
        (void*)&x0, (void*)&x1, (void*)&bar, (void*)&out
    };
    hipLaunchCooperativeKernel((const void*)fused_steps, dim3(256), dim3(512),
                               args, FU_SMEM, stream);
}

// Round 13
// 530.330 us; speedup vs baseline: 3.3409x; 1.0247x over previous
//
#include <hip/hip_runtime.h>
#include <cstdint>

#define BX   32
#define NN   1000
#define FF   16
#define TT   48          // HIST + FC
#define HIST 24
#define FC   24
#define HID  64
#define DEG  16
#define BN   (BX*NN)     // 32000 nodes
#define IMGP 40          // static-image pitch (shorts/node)

typedef __attribute__((ext_vector_type(8)))  short s8v;   // bf16x8 MFMA frag
typedef __attribute__((ext_vector_type(16))) float f16v;  // 32x32 accumulator

__device__ __forceinline__ float sigf(float x)  { return 1.0f/(1.0f+__expf(-x)); }
__device__ __forceinline__ float tanhf_(float x){ return 2.0f/(1.0f+__expf(-2.0f*x)) - 1.0f; }
__device__ __forceinline__ unsigned short f2bf(float x){
    unsigned int u = __float_as_uint(x);
    return (unsigned short)((u + 0x7FFFu + ((u>>16)&1u)) >> 16);   // RNE
}
__device__ __forceinline__ float bf2f(unsigned short b){
    return __uint_as_float(((unsigned int)b)<<16);
}
// packed f32x2 -> bf16x2 (lo = a, hi = b), hardware RNE
__device__ __forceinline__ unsigned int cvtpk(float a, float b){
    unsigned int r;
    asm("v_cvt_pk_bf16_f32 %0, %1, %2" : "=v"(r) : "v"(a), "v"(b));
    return r;
}

// xn moves through agent-scope atomics (coherent at LLC, bypasses per-XCD L2).
__device__ __forceinline__ void  xn_st(float* p, float v){
    __hip_atomic_store(p, v, __ATOMIC_RELAXED, __HIP_MEMORY_SCOPE_AGENT);
}
__device__ __forceinline__ float xn_ld(const float* p){
    return __hip_atomic_load(p, __ATOMIC_RELAXED, __HIP_MEMORY_SCOPE_AGENT);
}

// flush-free PER-BATCH barrier (8 blocks), monotonic counter, relaxed atomics.
__device__ __forceinline__ void batch_barrier(unsigned int* bar, unsigned int target){
    __syncthreads();
    if (threadIdx.x == 0){
        asm volatile("s_waitcnt vmcnt(0)" ::: "memory");
        __hip_atomic_fetch_add(bar, 1u, __ATOMIC_RELAXED, __HIP_MEMORY_SCOPE_AGENT);
        while (__hip_atomic_load(bar, __ATOMIC_RELAXED, __HIP_MEMORY_SCOPE_AGENT) < target)
            __builtin_amdgcn_s_sleep(1);
    }
    __syncthreads();
}

// A_s column map (enc): 0..16 agg(y_agg,X_agg0..15) | 17 y | 18..33 X | 34 xn_agg
//                       | 35 xn_self | 36..63 zero | 64..127 conv
// ---------------- one-time: bf16 weight images in LDS-exact layout ----------------
// encB: [B1 64x56 | Bih 192x104 | Bhh 192x72]   decB: [Bihd 192x72 | Bhhd 192x72]
__global__ void prep_weights(
    const float* __restrict__ W_rel, const float* __restrict__ W_root,
    const float* __restrict__ eWih, const float* __restrict__ eWhh,
    const float* __restrict__ dWih, const float* __restrict__ dWhh,
    unsigned short* __restrict__ encB, unsigned short* __restrict__ decB)
{
    const int i = blockIdx.x*256 + threadIdx.x;   // grid covers 192*104 = 19968
    if (i < 64*56){                                // B1[n][k], K-window cols 0..47
        int n = i/56, k = i%56;
        float v = 0.f;
        if (k < 17)                 v = W_rel[(k+1)*64 + n];    // agg ch 1..17
        else if (k == 17)           v = W_root[64 + n];         // y_self
        else if (k >= 18 && k < 34) v = W_root[(k-16)*64 + n];  // X_self 0..15
        else if (k == 34)           v = W_rel[n];               // xn_agg
        else if (k == 35)           v = W_root[n];              // xn_self
        encB[i] = f2bf(v);
    }
    if (i < 192*104){                              // Bih[n][c], 6 ks-blocks of x-GEMM
        int n = i/104, c = i%104;
        float v = 0.f;
        if (c >= 1 && c <= 17)       v = eWih[n*82 + c];        // y,X0..13 | X14,X15
        else if (c == 19)            v = eWih[n*82 + 0];        // xn_self
        else if (c >= 32 && c < 96)  v = eWih[n*82 + 18 + (c-32)]; // conv
        encB[3584 + i] = f2bf(v);
    }
    if (i < 192*72){                               // Bhh / dec images
        int n = i/72, k = i%72;
        encB[23552 + i] = f2bf((k < 64) ? eWhh[n*64 + k] : 0.f);
        decB[i]         = f2bf((k < 64) ? dWih[n*64 + k] : 0.f);
        decB[13824 + i] = f2bf((k < 64) ? dWhh[n*64 + k] : 0.f);
    }
}

// ---------------- pre-pass: static image [t][gblk 256][node 128][IMGP] bf16 ------
// cols 0..16 = agg(y_agg, X_agg*16); 17 = y_self; 18..33 = X_self; rest unused.
__global__ __launch_bounds__(1024, 4) void agg_pre(
    const float* __restrict__ X, const float* __restrict__ y,
    const int*   __restrict__ esrc, const float* __restrict__ ew,
    unsigned short* __restrict__ img)
{
    extern __shared__ float sm[];
    float* Xs = sm;            // [1000][16]
    float* ys = sm + NN*FF;    // [1000]

    const int b = blockIdx.x;
    const int t = blockIdx.y;
    const float* Xt = X + (size_t)(b*TT + t)*NN*FF;
    const float* yt = y + (size_t)(b*TT + t)*NN;

    for (int i = threadIdx.x; i < NN*FF/4; i += 1024)
        ((float4*)Xs)[i] = ((const float4*)Xt)[i];
    for (int i = threadIdx.x; i < NN; i += 1024)
        ys[i] = yt[i];
    __syncthreads();

    const int nl = threadIdx.x;                    // 0..1023 (>=1000 -> clamp dup)
    const int nc = (nl < NN) ? nl : NN-1;
    const int node = b*NN + nc;
    float a[18];
    #pragma unroll
    for (int i=0;i<17;i++) a[i]=0.f;
    const int4*   sv = (const int4*)  (esrc + node*DEG);
    const float4* wv = (const float4*)(ew   + node*DEG);
    #pragma unroll
    for (int q=0;q<4;q++){
        int4 s4 = sv[q]; float4 w4 = wv[q];
        const int   ss[4] = {s4.x, s4.y, s4.z, s4.w};
        const float ww[4] = {w4.x, w4.y, w4.z, w4.w};
        #pragma unroll
        for (int i=0;i<4;i++){
            const int sl = ss[i] - b*NN;
            const float wgt = ww[i];
            a[0] += wgt * ys[sl];
            const float4* sr = (const float4*)&Xs[sl*FF];
            #pragma unroll
            for (int q2=0;q2<4;q2++){
                float4 v = sr[q2];
                a[1+4*q2] += wgt*v.x; a[2+4*q2] += wgt*v.y;
                a[3+4*q2] += wgt*v.z; a[4+4*q2] += wgt*v.w;
            }
        }
    }
    a[17] = ys[nc];
    const int gblk = b*8 + (nl >> 7);
    unsigned int* w32 = (unsigned int*)(img +
        (((size_t)t*256 + gblk)*128 + (nl & 127))*IMGP);
    #pragma unroll
    for (int p=0;p<9;p++)  w32[p]   = cvtpk(a[2*p], a[2*p+1]);       // cols 0..17
    #pragma unroll
    for (int p=0;p<8;p++)  w32[9+p] = cvtpk(Xs[nc*FF+2*p], Xs[nc*FF+2*p+1]); // 18..33
}

// ---------------- fused persistent kernel ----------------
#define OFFB1  0
#define OFFBIH 3584
#define OFFBHH 23552
#define DOFFBIH 0
#define DOFFBHH 13824
#define OFFAS  37376
#define OFFAH  54784
#define FU_SMEM 144384
#define PAS  136
#define PB1  56
#define PBIH 104
#define PB72 72

__global__ __launch_bounds__(512, 1) void fused_steps(
    const float* __restrict__ X,
    const int* __restrict__ esrc, const float* __restrict__ ew,
    const unsigned short* __restrict__ img,
    const unsigned short* __restrict__ encB, const unsigned short* __restrict__ decB,
    const float* __restrict__ b_rel,
    const float* __restrict__ ebih, const float* __restrict__ ebhh,
    const float* __restrict__ eWout, const float* __restrict__ ebout,
    const float* __restrict__ dbih, const float* __restrict__ dbhh,
    const float* __restrict__ dWin, const float* __restrict__ dbin,
    const float* __restrict__ dWout, const float* __restrict__ dbout,
    float* __restrict__ xnA, float* __restrict__ xnB,
    unsigned int* __restrict__ bar, float* __restrict__ out)
{
    extern __shared__ char smraw[];
    __shared__ float xs[512];
    __shared__ float xnL[128];
    unsigned short* sm16 = (unsigned short*)smraw;

    const int tid  = threadIdx.x;
    const int lane = tid & 63;
    const int w    = __builtin_amdgcn_readfirstlane(tid >> 6);
    const int mt = w >> 1, jt = w & 1;
    const int batch = blockIdx.x >> 3;
    const int sub   = blockIdx.x & 7;
    unsigned int* mybar = bar + batch*32;

    // ---- one-time init: enc weights -> LDS, zero A_s + A_h ----
    {
        const uint4* src = (const uint4*)encB;
        uint4* dst = (uint4*)smraw;
        for (int i = tid; i < 4672; i += 512) dst[i] = src[i];
        unsigned int* z32 = (unsigned int*)(sm16 + OFFAS);
        for (int i = tid; i < 17408; i += 512) z32[i] = 0u;   // A_s + A_h (both 8704 u32)
    }

    for (int t = 0; t < TT; ++t){
        const bool enc = (t < HIST);
        const float* xn_r = (t & 1) ? xnB : xnA;
        float*       xn_w = (t & 1) ? xnA : xnB;

        if (enc){
            // ---- P0c: static image -> A_s cols 0..33 (aligned vector copies) ----
            {
                const unsigned short* imgrow = img +
                    (((size_t)t*256 + blockIdx.x)*128)*IMGP;
                for (int i = tid; i < 640; i += 512){
                    int node = i/5, part = i - node*5;
                    if (part < 4){
                        uint4 v = *(const uint4*)(imgrow + node*IMGP + part*8);
                        *(uint4*)(sm16 + OFFAS + node*PAS + part*8) = v;
                    } else {
                        unsigned int v = *(const unsigned int*)(imgrow + node*IMGP + 32);
                        *(unsigned int*)(sm16 + OFFAS + node*PAS + 32) = v;
                    }
                }
            }
            // ---- P0d: xn-gather -> cols 34(xn_agg), 35(xn_self) ----
            if (tid < 128){
                const int nl2 = sub*128 + tid;
                const int nc  = (nl2 < NN) ? nl2 : NN-1;
                const int node_g = batch*NN + nc;
                float a0 = 0.f, xnv = 0.f;
                if (t > 0){
                    const int4*   sv = (const int4*)  (esrc + node_g*DEG);
                    const float4* wv = (const float4*)(ew   + node_g*DEG);
                    #pragma unroll
                    for (int q=0;q<4;q++){
                        int4 s4 = sv[q]; float4 w4 = wv[q];
                        a0 += w4.x*xn_ld(xn_r + s4.x) + w4.y*xn_ld(xn_r + s4.y)
                            + w4.z*xn_ld(xn_r + s4.z) + w4.w*xn_ld(xn_r + s4.w);
                    }
                    xnv = xn_ld(xn_r + node_g);
                }
                *(unsigned int*)(sm16 + OFFAS + tid*PAS + 34) = cvtpk(a0, xnv);
            }
            __syncthreads();

            // ---- P1: GraphConv GEMM (K=48) -> sigmoid -> A_s cols 64..127 ----
            {
                f16v acc = {};
                const int rA = mt*32 + (lane & 31);
                const int rB = jt*32 + (lane & 31);
                const int ke = (lane >> 5)*8;
                #pragma unroll
                for (int ks=0; ks<3; ks++){
                    s8v a = *(const s8v*)(sm16 + OFFAS + rA*PAS + ks*16 + ke);
                    s8v b = *(const s8v*)(sm16 + OFFB1 + rB*PB1 + ks*16 + ke);
                    acc = __builtin_amdgcn_mfma_f32_32x32x16_bf16(a, b, acc, 0, 0, 0);
                }
                const int j = jt*32 + (lane & 31);
                const float brl = b_rel[j];
                #pragma unroll
                for (int p=0; p<8; p++){
                    float s0 = sigf(acc[2*p]   + brl);
                    float s1 = sigf(acc[2*p+1] + brl);
                    unsigned int pk = cvtpk(s0, s1);
                    int row = ((2*p)&3) + 8*(p>>1) + 4*(lane>>5);   // rows r, r+1
                    sm16[OFFAS + (mt*32 + row  )*PAS + 64 + j] = (unsigned short)pk;
                    sm16[OFFAS + (mt*32 + row+1)*PAS + 64 + j] = (unsigned short)(pk>>16);
                }
            }
            __syncthreads();

            // ---- P2: GRU GEMMs ----
            f16v accx[3] = {{},{},{}};
            f16v acch[3] = {{},{},{}};
            {
                const int rA = mt*32 + (lane & 31);
                const int ln = lane & 31;
                const int ke = (lane >> 5)*8;
                #pragma unroll
                for (int s=0; s<6; s++){              // x-GEMM: cols {16,32,64,80,96,112}
                    const int acol = (s < 2) ? (16 + 16*s) : (32 + 16*s);
                    s8v a = *(const s8v*)(sm16 + OFFAS + rA*PAS + acol + ke);
                    #pragma unroll
                    for (int nt=0; nt<3; nt++){
                        int NT = jt + nt*2;
                        s8v b = *(const s8v*)(sm16 + OFFBIH + (NT*32 + ln)*PBIH + s*16 + ke);
                        accx[nt] = __builtin_amdgcn_mfma_f32_32x32x16_bf16(a, b, accx[nt], 0,0,0);
                    }
                }
                #pragma unroll
                for (int ks=0; ks<4; ks++){           // h-GEMM: hi + lo passes
                    s8v ah = *(const s8v*)(sm16 + OFFAH + rA*PAS      + ks*16 + ke);
                    s8v al = *(const s8v*)(sm16 + OFFAH + rA*PAS + 64 + ks*16 + ke);
                    #pragma unroll
                    for (int nt=0; nt<3; nt++){
                        int NT = jt + nt*2;
                        s8v b = *(const s8v*)(sm16 + OFFBHH + (NT*32 + ln)*PB72 + ks*16 + ke);
                        acch[nt] = __builtin_amdgcn_mfma_f32_32x32x16_bf16(ah, b, acch[nt], 0,0,0);
                        acch[nt] = __builtin_amdgcn_mfma_f32_32x32x16_bf16(al, b, acch[nt], 0,0,0);
                    }
                }
            }
            __syncthreads();

            // ---- P3: epilogue; h' back to A_h hi/lo (cvt_pk pairs) ----
            {
                const int j = jt*32 + (lane & 31);
                const float br  = ebih[j]     + ebhh[j];
                const float bz  = ebih[64+j]  + ebhh[64+j];
                const float bin_ = ebih[128+j];
                const float bhn  = ebhh[128+j];
                #pragma unroll
                for (int p=0; p<8; p++){
                    const int r0 = 2*p, r1 = 2*p+1;
                    int row = ((r0)&3) + 8*(p>>1) + 4*(lane>>5);
                    unsigned short* hh0 = sm16 + OFFAH + (mt*32 + row  )*PAS + j;
                    unsigned short* hh1 = sm16 + OFFAH + (mt*32 + row+1)*PAS + j;
                    float hold0 = bf2f(hh0[0]) + bf2f(hh0[64]);
                    float hold1 = bf2f(hh1[0]) + bf2f(hh1[64]);
                    float rr0 = sigf(accx[0][r0] + acch[0][r0] + br);
                    float rr1 = sigf(accx[0][r1] + acch[0][r1] + br);
                    float zz0 = sigf(accx[1][r0] + acch[1][r0] + bz);
                    float zz1 = sigf(accx[1][r1] + acch[1][r1] + bz);
                    float nn0 = tanhf_(accx[2][r0] + bin_ + rr0*(acch[2][r0] + bhn));
                    float nn1 = tanhf_(accx[2][r1] + bin_ + rr1*(acch[2][r1] + bhn));
                    float hp0 = (1.f - zz0)*nn0 + zz0*hold0;
                    float hp1 = (1.f - zz1)*nn1 + zz1*hold1;
                    unsigned int nh = cvtpk(hp0, hp1);
                    float hi0 = __uint_as_float(nh << 16);
                    float hi1 = __uint_as_float(nh & 0xffff0000u);
                    unsigned int lo = cvtpk(hp0 - hi0, hp1 - hi1);
                    hh0[0]  = (unsigned short)nh;   hh1[0]  = (unsigned short)(nh>>16);
                    hh0[64] = (unsigned short)lo;   hh1[64] = (unsigned short)(lo>>16);
                }
            }
            __syncthreads();

            // ---- P4: xn = h' @ Wout + bout ----
            {
                const int node_l = tid >> 2, q = tid & 3;
                float s = 0.f;
                #pragma unroll
                for (int qq=0; qq<2; qq++){
                    s8v hi = *(const s8v*)(sm16 + OFFAH + node_l*PAS      + q*16 + qq*8);
                    s8v lo = *(const s8v*)(sm16 + OFFAH + node_l*PAS + 64 + q*16 + qq*8);
                    #pragma unroll
                    for (int i=0;i<8;i++){
                        float hv = bf2f((unsigned short)hi[i]) + bf2f((unsigned short)lo[i]);
                        s += hv * eWout[q*16 + qq*8 + i];
                    }
                }
                xs[tid] = s;
            }
            __syncthreads();
            if (tid < 128 && sub*128 + tid < NN)
                xn_st(xn_w + batch*NN + sub*128 + tid,
                      xs[4*tid] + xs[4*tid+1] + xs[4*tid+2] + xs[4*tid+3] + ebout[0]);
        } else {
            // ---- decoder (block-local; no grid sync) ----
            if (t == HIST){                               // overlay dec weights once
                const uint4* src = (const uint4*)decB;
                uint4* dst = (uint4*)smraw;
                for (int i = tid; i < 3456; i += 512) dst[i] = src[i];
            }
            // P0b: xin = [xn|X13..15] @ Win + bin -> A_x (pitch 72)
            {
                const int node = tid >> 2, c0 = (tid & 3)*16;
                const int nl2 = sub*128 + node;
                const int nc  = (nl2 < NN) ? nl2 : NN-1;
                const float* Xt = X + (size_t)(batch*TT + t)*NN*FF;
                float x0 = (t == HIST) ? xn_ld(xn_r + batch*NN + nc) : xnL[node];
                float x1 = Xt[nc*FF + 13];
                float x2 = Xt[nc*FF + 14];
                float x3 = Xt[nc*FF + 15];
                unsigned int* ax32 = (unsigned int*)(sm16 + OFFAS);
                #pragma unroll
                for (int p=0; p<8; p++){
                    int c = c0 + 2*p;
                    float va = dbin[c]   + x0*dWin[c]     + x1*dWin[64+c]   + x2*dWin[128+c]   + x3*dWin[192+c];
                    float vb = dbin[c+1] + x0*dWin[c+1]   + x1*dWin[64+c+1] + x2*dWin[128+c+1] + x3*dWin[192+c+1];
                    ax32[(node*PB72 + c) >> 1] = cvtpk(va, vb);
                }
            }
            __syncthreads();

            f16v accx[3] = {{},{},{}};
            f16v acch[3] = {{},{},{}};
            {
                const int rA = mt*32 + (lane & 31);
                const int ln = lane & 31;
                const int ke = (lane >> 5)*8;
                #pragma unroll
                for (int ks=0; ks<4; ks++){
                    s8v a = *(const s8v*)(sm16 + OFFAS + rA*PB72 + ks*16 + ke);
                    #pragma unroll
                    for (int nt=0; nt<3; nt++){
                        int NT = jt + nt*2;
                        s8v b = *(const s8v*)(sm16 + DOFFBIH + (NT*32 + ln)*PB72 + ks*16 + ke);
                        accx[nt] = __builtin_amdgcn_mfma_f32_32x32x16_bf16(a, b, accx[nt], 0,0,0);
                    }
                }
                #pragma unroll
                for (int ks=0; ks<4; ks++){
                    s8v ah = *(const s8v*)(sm16 + OFFAH + rA*PAS      + ks*16 + ke);
                    s8v al = *(const s8v*)(sm16 + OFFAH + rA*PAS + 64 + ks*16 + ke);
                    #pragma unroll
                    for (int nt=0; nt<3; nt++){
                        int NT = jt + nt*2;
                        s8v b = *(const s8v*)(sm16 + DOFFBHH + (NT*32 + ln)*PB72 + ks*16 + ke);
                        acch[nt] = __builtin_amdgcn_mfma_f32_32x32x16_bf16(ah, b, acch[nt], 0,0,0);
                        acch[nt] = __builtin_amdgcn_mfma_f32_32x32x16_bf16(al, b, acch[nt], 0,0,0);
                    }
                }
            }
            __syncthreads();

            {
                const int j = jt*32 + (lane & 31);
                const float br  = dbih[j]     + dbhh[j];
                const float bz  = dbih[64+j]  + dbhh[64+j];
                const float bin_ = dbih[128+j];
                const float bhn  = dbhh[128+j];
                #pragma unroll
                for (int p=0; p<8; p++){
                    const int r0 = 2*p, r1 = 2*p+1;
                    int row = ((r0)&3) + 8*(p>>1) + 4*(lane>>5);
                    unsigned short* hh0 = sm16 + OFFAH + (mt*32 + row  )*PAS + j;
                    unsigned short* hh1 = sm16 + OFFAH + (mt*32 + row+1)*PAS + j;
                    float hold0 = bf2f(hh0[0]) + bf2f(hh0[64]);
                    float hold1 = bf2f(hh1[0]) + bf2f(hh1[64]);
                    float rr0 = sigf(accx[0][r0] + acch[0][r0] + br);
                    float rr1 = sigf(accx[0][r1] + acch[0][r1] + br);
                    float zz0 = sigf(accx[1][r0] + acch[1][r0] + bz);
                    float zz1 = sigf(accx[1][r1] + acch[1][r1] + bz);
                    float nn0 = tanhf_(accx[2][r0] + bin_ + rr0*(acch[2][r0] + bhn));
                    float nn1 = tanhf_(accx[2][r1] + bin_ + rr1*(acch[2][r1] + bhn));
                    float hp0 = (1.f - zz0)*nn0 + zz0*hold0;
                    float hp1 = (1.f - zz1)*nn1 + zz1*hold1;
                    unsigned int nh = cvtpk(hp0, hp1);
                    float hi0 = __uint_as_float(nh << 16);
                    float hi1 = __uint_as_float(nh & 0xffff0000u);
                    unsigned int lo = cvtpk(hp0 - hi0, hp1 - hi1);
                    hh0[0]  = (unsigned short)nh;   hh1[0]  = (unsigned short)(nh>>16);
                    hh0[64] = (unsigned short)lo;   hh1[64] = (unsigned short)(lo>>16);
                }
            }
            __syncthreads();

            {
                const int node_l = tid >> 2, q = tid & 3;
                float s = 0.f;
                #pragma unroll
                for (int qq=0; qq<2; qq++){
                    s8v hi = *(const s8v*)(sm16 + OFFAH + node_l*PAS      + q*16 + qq*8);
                    s8v lo = *(const s8v*)(sm16 + OFFAH + node_l*PAS + 64 + q*16 + qq*8);
                    #pragma unroll
                    for (int i=0;i<8;i++){
                        float hv = bf2f((unsigned short)hi[i]) + bf2f((unsigned short)lo[i]);
                        s += hv * dWout[q*16 + qq*8 + i];
                    }
                }
                xs[tid] = s;
            }
            __syncthreads();
            if (tid < 128){
                float v = xs[4*tid] + xs[4*tid+1] + xs[4*tid+2] + xs[4*tid+3] + dbout[0];
                xnL[tid] = v;
                const int nl2 = sub*128 + tid;
                if (nl2 < NN)
                    out[(size_t)(batch*FC + (t - HIST))*NN + nl2] = v;
            }
        }
        // sync: per-batch barrier between encoder steps; local sync otherwise
        if (t < HIST-1) batch_barrier(mybar, 8u*(unsigned)(t+1));
        else            __syncthreads();
    }
}

extern "C" void kernel_launch(void* const* d_in, const int* in_sizes, int n_in,
                              void* d_out, int out_size, void* d_ws, size_t ws_size,
                              hipStream_t stream)
{
    const float* X     = (const float*)d_in[0];
    const float* y     = (const float*)d_in[1];
    const int*   ei    = (const int*)  d_in[2];
    const float* ew    = (const float*)d_in[3];
    const float* W_rel = (const float*)d_in[4];
    const float* b_rel = (const float*)d_in[5];
    const float* W_root= (const float*)d_in[6];
    const float* eWih  = (const float*)d_in[7];
    const float* eWhh  = (const float*)d_in[8];
    const float* ebih  = (const float*)d_in[9];
    const float* ebhh  = (const float*)d_in[10];
    const float* eWout = (const float*)d_in[11];
    const float* ebout = (const float*)d_in[12];
    const float* dWin  = (const float*)d_in[13];
    const float* dbin  = (const float*)d_in[14];
    const float* dWih  = (const float*)d_in[15];
    const float* dWhh  = (const float*)d_in[16];
    const float* dbih  = (const float*)d_in[17];
    const float* dbhh  = (const float*)d_in[18];
    const float* dWout = (const float*)d_in[19];
    const float* dbout = (const float*)d_in[20];
    float* out = (float*)d_out;

    // ws: img 62.9MB | xn ping-pong 2x128KB | encB 74.8KB | decB 55.3KB | bar 4KB
    unsigned short* img = (unsigned short*)d_ws;
    float* x0 = (float*)(img + (size_t)24*256*128*IMGP);
    float* x1 = x0 + BN;
    unsigned short* encB = (unsigned short*)(x1 + BN);
    unsigned short* decB = encB + 37376;
    unsigned int* bar = (unsigned int*)(decB + 27648);

    const int* esrc = ei;

    const int smA = (NN*FF + NN)*sizeof(float);
    hipFuncSetAttribute((const void*)agg_pre,
                        hipFuncAttributeMaxDynamicSharedMemorySize, smA);
    hipFuncSetAttribute((const void*)fused_steps,
                        hipFuncAttributeMaxDynamicSharedMemorySize, FU_SMEM);

    hipMemsetAsync(bar, 0, 32*32*sizeof(unsigned int), stream);
    prep_weights<<<78, 256, 0, stream>>>(W_rel, W_root, eWih, eWhh, dWih, dWhh, encB, decB);
    agg_pre<<<dim3(BX,24), 1024, smA, stream>>>(X, y, esrc, ew, img);

    void* args[] = {
        (void*)&X, (void*)&esrc, (void*)&ew, (void*)&img,
        (void*)&encB, (void*)&decB,
        (void*)&b_rel, (void*)&ebih, (void*)&ebhh, (void*)&eWout, (void*)&ebout,
        (void*)&dbih, (void*)&dbhh, (void*)&dWin, (void*)&dbin, (void*)&dWout, (void*)&dbout,
        (void*)&x0, (void*)&x1, (void*)&bar, (void*)&out
    };
    hipLaunchCooperativeKernel((const void*)fused_steps, dim3(256), dim3(512),
                               args, FU_SMEM, stream);
}

// Round 15
// 504.857 us; speedup vs baseline: 3.5094x; 1.0505x over previous
//
#include <hip/hip_runtime.h>
#include <cstdint>

#define BX   32
#define NN   1000
#define FF   16
#define TT   48          // HIST + FC
#define HIST 24
#define FC   24
#define HID  64
#define DEG  16
#define BN   (BX*NN)     // 32000 nodes
#define IMGP 40          // static-image pitch (shorts/node)

typedef __attribute__((ext_vector_type(8)))  short s8v;   // bf16x8 MFMA frag
typedef __attribute__((ext_vector_type(16))) float f16v;  // 32x32 accumulator

__device__ __forceinline__ float sigf(float x)  { return 1.0f/(1.0f+__expf(-x)); }
__device__ __forceinline__ float tanhf_(float x){ return 2.0f/(1.0f+__expf(-2.0f*x)) - 1.0f; }
__device__ __forceinline__ unsigned short f2bf(float x){
    unsigned int u = __float_as_uint(x);
    return (unsigned short)((u + 0x7FFFu + ((u>>16)&1u)) >> 16);   // RNE
}
__device__ __forceinline__ float bf2f(unsigned short b){
    return __uint_as_float(((unsigned int)b)<<16);
}
// packed f32x2 -> bf16x2 (lo = a, hi = b), hardware RNE
__device__ __forceinline__ unsigned int cvtpk(float a, float b){
    unsigned int r;
    asm("v_cvt_pk_bf16_f32 %0, %1, %2" : "=v"(r) : "v"(a), "v"(b));
    return r;
}

// xn moves through agent-scope atomics (coherent at LLC, bypasses per-XCD L2).
__device__ __forceinline__ void  xn_st(float* p, float v){
    __hip_atomic_store(p, v, __ATOMIC_RELAXED, __HIP_MEMORY_SCOPE_AGENT);
}
__device__ __forceinline__ float xn_ld(const float* p){
    return __hip_atomic_load(p, __ATOMIC_RELAXED, __HIP_MEMORY_SCOPE_AGENT);
}

// flush-free PER-BATCH barrier (8 blocks), monotonic counter, relaxed atomics.
__device__ __forceinline__ void batch_barrier(unsigned int* bar, unsigned int target){
    __syncthreads();
    if (threadIdx.x == 0){
        asm volatile("s_waitcnt vmcnt(0)" ::: "memory");
        __hip_atomic_fetch_add(bar, 1u, __ATOMIC_RELAXED, __HIP_MEMORY_SCOPE_AGENT);
        while (__hip_atomic_load(bar, __ATOMIC_RELAXED, __HIP_MEMORY_SCOPE_AGENT) < target)
            __builtin_amdgcn_s_sleep(1);
    }
    __syncthreads();
}

// A_s column map (enc): 0..16 agg | 17 y | 18..33 X | 34 xn_agg | 35 xn_self
//                       | 36..63 zero | 64..127 conv
// encB: [B1 64x56 | Bih 192x96 | Bhh 192x72]   decB: [Bihd 192x72 | Bhhd 192x72]
__global__ void prep_weights(
    const float* __restrict__ W_rel, const float* __restrict__ W_root,
    const float* __restrict__ eWih, const float* __restrict__ eWhh,
    const float* __restrict__ dWih, const float* __restrict__ dWhh,
    unsigned short* __restrict__ encB, unsigned short* __restrict__ decB)
{
    const int i = blockIdx.x*256 + threadIdx.x;   // grid covers 192*96 = 18432
    if (i < 64*56){                                // B1[n][k]
        int n = i/56, k = i%56;
        float v = 0.f;
        if (k < 17)                 v = W_rel[(k+1)*64 + n];    // agg ch 1..17
        else if (k == 17)           v = W_root[64 + n];         // y_self
        else if (k >= 18 && k < 34) v = W_root[(k-16)*64 + n];  // X_self 0..15
        else if (k == 34)           v = W_rel[n];               // xn_agg
        else if (k == 35)           v = W_root[n];              // xn_self
        encB[i] = f2bf(v);
    }
    if (i < 192*96){                               // Bih[n][c] (pitch 96)
        int n = i/96, c = i%96;
        float v = 0.f;
        if (c >= 1 && c <= 17)       v = eWih[n*82 + c];        // y,X0..15
        else if (c == 19)            v = eWih[n*82 + 0];        // xn_self
        else if (c >= 32 && c < 96)  v = eWih[n*82 + 18 + (c-32)]; // conv
        encB[3584 + i] = f2bf(v);
    }
    if (i < 192*72){                               // Bhh / dec images
        int n = i/72, k = i%72;
        encB[22016 + i] = f2bf((k < 64) ? eWhh[n*64 + k] : 0.f);
        decB[i]         = f2bf((k < 64) ? dWih[n*64 + k] : 0.f);
        decB[13824 + i] = f2bf((k < 64) ? dWhh[n*64 + k] : 0.f);
    }
}

// ---------------- pre-pass: static image [t][gblk 256][node 128][IMGP] bf16 ------
__global__ __launch_bounds__(1024, 4) void agg_pre(
    const float* __restrict__ X, const float* __restrict__ y,
    const int*   __restrict__ esrc, const float* __restrict__ ew,
    unsigned short* __restrict__ img)
{
    extern __shared__ float sm[];
    float* Xs = sm;            // [1000][16]
    float* ys = sm + NN*FF;    // [1000]

    const int b = blockIdx.x;
    const int t = blockIdx.y;
    const float* Xt = X + (size_t)(b*TT + t)*NN*FF;
    const float* yt = y + (size_t)(b*TT + t)*NN;

    for (int i = threadIdx.x; i < NN*FF/4; i += 1024)
        ((float4*)Xs)[i] = ((const float4*)Xt)[i];
    for (int i = threadIdx.x; i < NN; i += 1024)
        ys[i] = yt[i];
    __syncthreads();

    const int nl = threadIdx.x;                    // 0..1023 (>=1000 -> clamp dup)
    const int nc = (nl < NN) ? nl : NN-1;
    const int node = b*NN + nc;
    float a[18];
    #pragma unroll
    for (int i=0;i<17;i++) a[i]=0.f;
    const int4*   sv = (const int4*)  (esrc + node*DEG);
    const float4* wv = (const float4*)(ew   + node*DEG);
    #pragma unroll
    for (int q=0;q<4;q++){
        int4 s4 = sv[q]; float4 w4 = wv[q];
        const int   ss[4] = {s4.x, s4.y, s4.z, s4.w};
        const float ww[4] = {w4.x, w4.y, w4.z, w4.w};
        #pragma unroll
        for (int i=0;i<4;i++){
            const int sl = ss[i] - b*NN;
            const float wgt = ww[i];
            a[0] += wgt * ys[sl];
            const float4* sr = (const float4*)&Xs[sl*FF];
            #pragma unroll
            for (int q2=0;q2<4;q2++){
                float4 v = sr[q2];
                a[1+4*q2] += wgt*v.x; a[2+4*q2] += wgt*v.y;
                a[3+4*q2] += wgt*v.z; a[4+4*q2] += wgt*v.w;
            }
        }
    }
    a[17] = ys[nc];
    const int gblk = b*8 + (nl >> 7);
    unsigned int* w32 = (unsigned int*)(img +
        (((size_t)t*256 + gblk)*128 + (nl & 127))*IMGP);
    #pragma unroll
    for (int p=0;p<9;p++)  w32[p]   = cvtpk(a[2*p], a[2*p+1]);       // cols 0..17
    #pragma unroll
    for (int p=0;p<8;p++)  w32[9+p] = cvtpk(Xs[nc*FF+2*p], Xs[nc*FF+2*p+1]); // 18..33
}

// ---------------- fused persistent kernel ----------------
// LDS (bytes): enc weights @0..71680 | A_s @71680 (128x136 bf16) |
//              A_hbf @106496 (128x72 bf16, hi-only h) | h_f32 @124928 (128x68 f32)
#define OFFB1   0
#define OFFBIH  3584
#define OFFBHH  22016
#define DOFFBIH 0
#define DOFFBHH 13824
#define OFFAS   35840     // shorts
#define OFFAHB  53248     // shorts
#define OFFHF   124928    // bytes
#define FU_SMEM 159744
#define PAS  136
#define PB1  56
#define PBIH 96
#define PB72 72
#define PHF  68

__global__ __launch_bounds__(512, 1) void fused_steps(
    const float* __restrict__ X,
    const int* __restrict__ esrc, const float* __restrict__ ew,
    const unsigned short* __restrict__ img,
    const unsigned short* __restrict__ encB, const unsigned short* __restrict__ decB,
    const float* __restrict__ b_rel,
    const float* __restrict__ ebih, const float* __restrict__ ebhh,
    const float* __restrict__ eWout, const float* __restrict__ ebout,
    const float* __restrict__ dbih, const float* __restrict__ dbhh,
    const float* __restrict__ dWin, const float* __restrict__ dbin,
    const float* __restrict__ dWout, const float* __restrict__ dbout,
    float* __restrict__ xnA, float* __restrict__ xnB,
    unsigned int* __restrict__ bar, float* __restrict__ out)
{
    extern __shared__ char smraw[];
    __shared__ float xnL[128];
    unsigned short* sm16 = (unsigned short*)smraw;
    float* hf = (float*)(smraw + OFFHF);

    const int tid  = threadIdx.x;
    const int lane = tid & 63;
    const int w    = __builtin_amdgcn_readfirstlane(tid >> 6);
    const int mt = w >> 1, jt = w & 1;
    const int batch = blockIdx.x >> 3;
    const int sub   = blockIdx.x & 7;
    unsigned int* mybar = bar + batch*32;

    // ---- one-time init: enc weights -> LDS, zero A_s + A_hbf + h_f32 ----
    {
        const uint4* src = (const uint4*)encB;
        uint4* dst = (uint4*)smraw;
        for (int i = tid; i < 4480; i += 512) dst[i] = src[i];
        unsigned int* z32 = (unsigned int*)(smraw + 71680);
        for (int i = tid; i < 22016; i += 512) z32[i] = 0u;
    }

    for (int t = 0; t < TT; ++t){
        const bool enc = (t < HIST);
        const float* xn_r = (t & 1) ? xnB : xnA;
        float*       xn_w = (t & 1) ? xnA : xnB;

        if (enc){
            // ---- P0c: static image -> A_s cols 0..33 (aligned vector copies) ----
            {
                const unsigned short* imgrow = img +
                    (((size_t)t*256 + blockIdx.x)*128)*IMGP;
                for (int i = tid; i < 640; i += 512){
                    int node = i/5, part = i - node*5;
                    if (part < 4){
                        uint4 v = *(const uint4*)(imgrow + node*IMGP + part*8);
                        *(uint4*)(sm16 + OFFAS + node*PAS + part*8) = v;
                    } else {
                        unsigned int v = *(const unsigned int*)(imgrow + node*IMGP + 32);
                        *(unsigned int*)(sm16 + OFFAS + node*PAS + 32) = v;
                    }
                }
            }
            // ---- P0d: xn-gather -> cols 34(xn_agg), 35(xn_self) ----
            if (tid < 128){
                const int nl2 = sub*128 + tid;
                const int nc  = (nl2 < NN) ? nl2 : NN-1;
                const int node_g = batch*NN + nc;
                float a0 = 0.f, xnv = 0.f;
                if (t > 0){
                    const int4*   sv = (const int4*)  (esrc + node_g*DEG);
                    const float4* wv = (const float4*)(ew   + node_g*DEG);
                    #pragma unroll
                    for (int q=0;q<4;q++){
                        int4 s4 = sv[q]; float4 w4 = wv[q];
                        a0 += w4.x*xn_ld(xn_r + s4.x) + w4.y*xn_ld(xn_r + s4.y)
                            + w4.z*xn_ld(xn_r + s4.z) + w4.w*xn_ld(xn_r + s4.w);
                    }
                    xnv = xn_ld(xn_r + node_g);
                }
                *(unsigned int*)(sm16 + OFFAS + tid*PAS + 34) = cvtpk(a0, xnv);
            }
            __syncthreads();

            // ---- P1: GraphConv GEMM (K=48) -> sigmoid -> A_s cols 64..127 ----
            {
                f16v acc = {};
                const int rA = mt*32 + (lane & 31);
                const int rB = jt*32 + (lane & 31);
                const int ke = (lane >> 5)*8;
                #pragma unroll
                for (int ks=0; ks<3; ks++){
                    s8v a = *(const s8v*)(sm16 + OFFAS + rA*PAS + ks*16 + ke);
                    s8v b = *(const s8v*)(sm16 + OFFB1 + rB*PB1 + ks*16 + ke);
                    acc = __builtin_amdgcn_mfma_f32_32x32x16_bf16(a, b, acc, 0, 0, 0);
                }
                const int j = jt*32 + (lane & 31);
                const float brl = b_rel[j];
                #pragma unroll
                for (int p=0; p<8; p++){
                    float s0 = sigf(acc[2*p]   + brl);
                    float s1 = sigf(acc[2*p+1] + brl);
                    unsigned int pk = cvtpk(s0, s1);
                    int row = ((2*p)&3) + 8*(p>>1) + 4*(lane>>5);   // rows r, r+1
                    sm16[OFFAS + (mt*32 + row  )*PAS + 64 + j] = (unsigned short)pk;
                    sm16[OFFAS + (mt*32 + row+1)*PAS + 64 + j] = (unsigned short)(pk>>16);
                }
            }
            __syncthreads();

            // ---- P2: GRU GEMMs (x: K=96 windows; h: hi-only K=64) ----
            f16v accx[3] = {{},{},{}};
            f16v acch[3] = {{},{},{}};
            {
                const int rA = mt*32 + (lane & 31);
                const int ln = lane & 31;
                const int ke = (lane >> 5)*8;
                #pragma unroll
                for (int s=0; s<6; s++){              // A cols {16,32,64,80,96,112}
                    const int acol = (s < 2) ? (16 + 16*s) : (32 + 16*s);
                    s8v a = *(const s8v*)(sm16 + OFFAS + rA*PAS + acol + ke);
                    #pragma unroll
                    for (int nt=0; nt<3; nt++){
                        int NT = jt + nt*2;
                        s8v b = *(const s8v*)(sm16 + OFFBIH + (NT*32 + ln)*PBIH + s*16 + ke);
                        accx[nt] = __builtin_amdgcn_mfma_f32_32x32x16_bf16(a, b, accx[nt], 0,0,0);
                    }
                }
                #pragma unroll
                for (int ks=0; ks<4; ks++){
                    s8v ah = *(const s8v*)(sm16 + OFFAHB + rA*PB72 + ks*16 + ke);
                    #pragma unroll
                    for (int nt=0; nt<3; nt++){
                        int NT = jt + nt*2;
                        s8v b = *(const s8v*)(sm16 + OFFBHH + (NT*32 + ln)*PB72 + ks*16 + ke);
                        acch[nt] = __builtin_amdgcn_mfma_f32_32x32x16_bf16(ah, b, acch[nt], 0,0,0);
                    }
                }
            }
            __syncthreads();                          // all A_hbf reads done

            // ---- P3: epilogue; h' -> h_f32 (master) + A_hbf (hi bf16) ----
            {
                const int j = jt*32 + (lane & 31);
                const float br  = ebih[j]     + ebhh[j];
                const float bz  = ebih[64+j]  + ebhh[64+j];
                const float bin_ = ebih[128+j];
                const float bhn  = ebhh[128+j];
                #pragma unroll
                for (int p=0; p<8; p++){
                    const int r0 = 2*p, r1 = 2*p+1;
                    int row = ((r0)&3) + 8*(p>>1) + 4*(lane>>5);
                    const int n0 = mt*32 + row, n1 = n0 + 1;
                    float hold0 = hf[n0*PHF + j];
                    float hold1 = hf[n1*PHF + j];
                    float rr0 = sigf(accx[0][r0] + acch[0][r0] + br);
                    float rr1 = sigf(accx[0][r1] + acch[0][r1] + br);
                    float zz0 = sigf(accx[1][r0] + acch[1][r0] + bz);
                    float zz1 = sigf(accx[1][r1] + acch[1][r1] + bz);
                    float nn0 = tanhf_(accx[2][r0] + bin_ + rr0*(acch[2][r0] + bhn));
                    float nn1 = tanhf_(accx[2][r1] + bin_ + rr1*(acch[2][r1] + bhn));
                    float hp0 = (1.f - zz0)*nn0 + zz0*hold0;
                    float hp1 = (1.f - zz1)*nn1 + zz1*hold1;
                    hf[n0*PHF + j] = hp0;
                    hf[n1*PHF + j] = hp1;
                    unsigned int nh = cvtpk(hp0, hp1);
                    sm16[OFFAHB + n0*PB72 + j] = (unsigned short)nh;
                    sm16[OFFAHB + n1*PB72 + j] = (unsigned short)(nh>>16);
                }
            }
            __syncthreads();

            // ---- P4: xn = h' @ Wout + bout (2 waves, f32 reads) ----
            if (tid < 128){
                const float4* hv = (const float4*)(hf + tid*PHF);
                float s = ebout[0];
                #pragma unroll
                for (int q=0; q<16; q++){
                    float4 v = hv[q];
                    s += v.x*eWout[4*q] + v.y*eWout[4*q+1]
                       + v.z*eWout[4*q+2] + v.w*eWout[4*q+3];
                }
                const int nl2 = sub*128 + tid;
                if (nl2 < NN) xn_st(xn_w + batch*NN + nl2, s);
            }
        } else {
            // ---- decoder (block-local; no grid sync) ----
            if (t == HIST){                           // overlay dec weights once
                const uint4* src = (const uint4*)decB;
                uint4* dst = (uint4*)smraw;
                for (int i = tid; i < 3456; i += 512) dst[i] = src[i];
            }
            // P0b: xin = [xn|X13..15] @ Win + bin -> A_x (pitch 72 @ OFFAS)
            {
                const int node = tid >> 2, c0 = (tid & 3)*16;
                const int nl2 = sub*128 + node;
                const int nc  = (nl2 < NN) ? nl2 : NN-1;
                const float* Xt = X + (size_t)(batch*TT + t)*NN*FF;
                float x0 = (t == HIST) ? xn_ld(xn_r + batch*NN + nc) : xnL[node];
                float x1 = Xt[nc*FF + 13];
                float x2 = Xt[nc*FF + 14];
                float x3 = Xt[nc*FF + 15];
                unsigned int* ax32 = (unsigned int*)(sm16 + OFFAS);
                #pragma unroll
                for (int p=0; p<8; p++){
                    int c = c0 + 2*p;
                    float va = dbin[c]   + x0*dWin[c]     + x1*dWin[64+c]   + x2*dWin[128+c]   + x3*dWin[192+c];
                    float vb = dbin[c+1] + x0*dWin[c+1]   + x1*dWin[64+c+1] + x2*dWin[128+c+1] + x3*dWin[192+c+1];
                    ax32[(node*PB72 + c) >> 1] = cvtpk(va, vb);
                }
            }
            __syncthreads();

            f16v accx[3] = {{},{},{}};
            f16v acch[3] = {{},{},{}};
            {
                const int rA = mt*32 + (lane & 31);
                const int ln = lane & 31;
                const int ke = (lane >> 5)*8;
                #pragma unroll
                for (int ks=0; ks<4; ks++){
                    s8v a = *(const s8v*)(sm16 + OFFAS + rA*PB72 + ks*16 + ke);
                    #pragma unroll
                    for (int nt=0; nt<3; nt++){
                        int NT = jt + nt*2;
                        s8v b = *(const s8v*)(sm16 + DOFFBIH + (NT*32 + ln)*PB72 + ks*16 + ke);
                        accx[nt] = __builtin_amdgcn_mfma_f32_32x32x16_bf16(a, b, accx[nt], 0,0,0);
                    }
                }
                #pragma unroll
                for (int ks=0; ks<4; ks++){
                    s8v ah = *(const s8v*)(sm16 + OFFAHB + rA*PB72 + ks*16 + ke);
                    #pragma unroll
                    for (int nt=0; nt<3; nt++){
                        int NT = jt + nt*2;
                        s8v b = *(const s8v*)(sm16 + DOFFBHH + (NT*32 + ln)*PB72 + ks*16 + ke);
                        acch[nt] = __builtin_amdgcn_mfma_f32_32x32x16_bf16(ah, b, acch[nt], 0,0,0);
                    }
                }
            }
            __syncthreads();

            {
                const int j = jt*32 + (lane & 31);
                const float br  = dbih[j]     + dbhh[j];
                const float bz  = dbih[64+j]  + dbhh[64+j];
                const float bin_ = dbih[128+j];
                const float bhn  = dbhh[128+j];
                #pragma unroll
                for (int p=0; p<8; p++){
                    const int r0 = 2*p, r1 = 2*p+1;
                    int row = ((r0)&3) + 8*(p>>1) + 4*(lane>>5);
                    const int n0 = mt*32 + row, n1 = n0 + 1;
                    float hold0 = hf[n0*PHF + j];
                    float hold1 = hf[n1*PHF + j];
                    float rr0 = sigf(accx[0][r0] + acch[0][r0] + br);
                    float rr1 = sigf(accx[0][r1] + acch[0][r1] + br);
                    float zz0 = sigf(accx[1][r0] + acch[1][r0] + bz);
                    float zz1 = sigf(accx[1][r1] + acch[1][r1] + bz);
                    float nn0 = tanhf_(accx[2][r0] + bin_ + rr0*(acch[2][r0] + bhn));
                    float nn1 = tanhf_(accx[2][r1] + bin_ + rr1*(acch[2][r1] + bhn));
                    float hp0 = (1.f - zz0)*nn0 + zz0*hold0;
                    float hp1 = (1.f - zz1)*nn1 + zz1*hold1;
                    hf[n0*PHF + j] = hp0;
                    hf[n1*PHF + j] = hp1;
                    unsigned int nh = cvtpk(hp0, hp1);
                    sm16[OFFAHB + n0*PB72 + j] = (unsigned short)nh;
                    sm16[OFFAHB + n1*PB72 + j] = (unsigned short)(nh>>16);
                }
            }
            __syncthreads();

            if (tid < 128){
                const float4* hv = (const float4*)(hf + tid*PHF);
                float s = dbout[0];
                #pragma unroll
                for (int q=0; q<16; q++){
                    float4 v = hv[q];
                    s += v.x*dWout[4*q] + v.y*dWout[4*q+1]
                       + v.z*dWout[4*q+2] + v.w*dWout[4*q+3];
                }
                xnL[tid] = s;
                const int nl2 = sub*128 + tid;
                if (nl2 < NN)
                    out[(size_t)(batch*FC + (t - HIST))*NN + nl2] = s;
            }
        }
        // sync: per-batch barrier between encoder steps; local sync otherwise
        if (t < HIST-1) batch_barrier(mybar, 8u*(unsigned)(t+1));
        else            __syncthreads();
    }
}

extern "C" void kernel_launch(void* const* d_in, const int* in_sizes, int n_in,
                              void* d_out, int out_size, void* d_ws, size_t ws_size,
                              hipStream_t stream)
{
    const float* X     = (const float*)d_in[0];
    const float* y     = (const float*)d_in[1];
    const int*   ei    = (const int*)  d_in[2];
    const float* ew    = (const float*)d_in[3];
    const float* W_rel = (const float*)d_in[4];
    const float* b_rel = (const float*)d_in[5];
    const float* W_root= (const float*)d_in[6];
    const float* eWih  = (const float*)d_in[7];
    const float* eWhh  = (const float*)d_in[8];
    const float* ebih  = (const float*)d_in[9];
    const float* ebhh  = (const float*)d_in[10];
    const float* eWout = (const float*)d_in[11];
    const float* ebout = (const float*)d_in[12];
    const float* dWin  = (const float*)d_in[13];
    const float* dbin  = (const float*)d_in[14];
    const float* dWih  = (const float*)d_in[15];
    const float* dWhh  = (const float*)d_in[16];
    const float* dbih  = (const float*)d_in[17];
    const float* dbhh  = (const float*)d_in[18];
    const float* dWout = (const float*)d_in[19];
    const float* dbout = (const float*)d_in[20];
    float* out = (float*)d_out;

    // ws: img 62.9MB | xn ping-pong 2x128KB | encB 71.7KB | decB 55.3KB | bar 4KB
    unsigned short* img = (unsigned short*)d_ws;
    float* x0 = (float*)(img + (size_t)24*256*128*IMGP);
    float* x1 = x0 + BN;
    unsigned short* encB = (unsigned short*)(x1 + BN);
    unsigned short* decB = encB + 35840;
    unsigned int* bar = (unsigned int*)(decB + 27648);

    const int* esrc = ei;

    const int smA = (NN*FF + NN)*sizeof(float);
    hipFuncSetAttribute((const void*)agg_pre,
                        hipFuncAttributeMaxDynamicSharedMemorySize, smA);
    hipFuncSetAttribute((const void*)fused_steps,
                        hipFuncAttributeMaxDynamicSharedMemorySize, FU_SMEM);

    hipMemsetAsync(bar, 0, 32*32*sizeof(unsigned int), stream);
    prep_weights<<<78, 256, 0, stream>>>(W_rel, W_root, eWih, eWhh, dWih, dWhh, encB, decB);
    agg_pre<<<dim3(BX,24), 1024, smA, stream>>>(X, y, esrc, ew, img);

    void* args[] = {
        (void*)&X, (void*)&esrc, (void*)&ew, (void*)&img,
        (void*)&encB, (void*)&decB,
        (void*)&b_rel, (void*)&ebih, (void*)&ebhh, (void*)&eWout, (void*)&ebout,
        (void*)&dbih, (void*)&dbhh, (void*)&dWin, (void*)&dbin, (void*)&dWout, (void*)&dbout,
        (void*)&x0, (void*)&x1, (void*)&bar, (void*)&out
    };
    hipLaunchCooperativeKernel((const void*)fused_steps, dim3(256), dim3(512),
                               args, FU_SMEM, stream);
}

// Round 17
// 487.420 us; speedup vs baseline: 3.6350x; 1.0358x over previous
//
#include <hip/hip_runtime.h>
#include <cstdint>

#define BX   32
#define NN   1000
#define FF   16
#define TT   48          // HIST + FC
#define HIST 24
#define FC   24
#define HID  64
#define DEG  16
#define BN   (BX*NN)     // 32000 nodes
#define IMGP 40          // static-image pitch (shorts/node)

typedef __attribute__((ext_vector_type(8)))  short s8v;   // bf16x8 MFMA frag
typedef __attribute__((ext_vector_type(16))) float f16v;  // 32x32 accumulator

__device__ __forceinline__ float sigf(float x)  { return 1.0f/(1.0f+__expf(-x)); }
__device__ __forceinline__ float tanhf_(float x){ return 2.0f/(1.0f+__expf(-2.0f*x)) - 1.0f; }
__device__ __forceinline__ unsigned short f2bf(float x){
    unsigned int u = __float_as_uint(x);
    return (unsigned short)((u + 0x7FFFu + ((u>>16)&1u)) >> 16);   // RNE
}
__device__ __forceinline__ float bf2f(unsigned short b){
    return __uint_as_float(((unsigned int)b)<<16);
}
// packed f32x2 -> bf16x2 (lo = a, hi = b), hardware RNE
__device__ __forceinline__ unsigned int cvtpk(float a, float b){
    unsigned int r;
    asm("v_cvt_pk_bf16_f32 %0, %1, %2" : "=v"(r) : "v"(a), "v"(b));
    return r;
}

// xn moves through agent-scope atomics (coherent at LLC, bypasses per-XCD L2).
__device__ __forceinline__ void  xn_st(float* p, float v){
    __hip_atomic_store(p, v, __ATOMIC_RELAXED, __HIP_MEMORY_SCOPE_AGENT);
}
__device__ __forceinline__ float xn_ld(const float* p){
    return __hip_atomic_load(p, __ATOMIC_RELAXED, __HIP_MEMORY_SCOPE_AGENT);
}

// flush-free PER-BATCH barrier (8 blocks), monotonic counter, relaxed atomics.
__device__ __forceinline__ void batch_barrier(unsigned int* bar, unsigned int target){
    __syncthreads();
    if (threadIdx.x == 0){
        asm volatile("s_waitcnt vmcnt(0)" ::: "memory");
        __hip_atomic_fetch_add(bar, 1u, __ATOMIC_RELAXED, __HIP_MEMORY_SCOPE_AGENT);
        while (__hip_atomic_load(bar, __ATOMIC_RELAXED, __HIP_MEMORY_SCOPE_AGENT) < target)
            __builtin_amdgcn_s_sleep(1);
    }
    __syncthreads();
}

// A_s column map (enc): 0..16 agg | 17 y | 18..33 X | 34 xn_agg | 35 xn_self
//                       | 36..63 zero | 64..127 conv
// encB: [B1 64x56 | Bih 192x96 | Bhh 192x72]   decB: [Bihd 192x72 | Bhhd 192x72]
__global__ void prep_weights(
    const float* __restrict__ W_rel, const float* __restrict__ W_root,
    const float* __restrict__ eWih, const float* __restrict__ eWhh,
    const float* __restrict__ dWih, const float* __restrict__ dWhh,
    unsigned short* __restrict__ encB, unsigned short* __restrict__ decB)
{
    const int i = blockIdx.x*256 + threadIdx.x;
    if (i < 64*56){                                // B1[n][k]
        int n = i/56, k = i%56;
        float v = 0.f;
        if (k < 17)                 v = W_rel[(k+1)*64 + n];    // agg ch 1..17
        else if (k == 17)           v = W_root[64 + n];         // y_self
        else if (k >= 18 && k < 34) v = W_root[(k-16)*64 + n];  // X_self 0..15
        else if (k == 34)           v = W_rel[n];               // xn_agg
        else if (k == 35)           v = W_root[n];              // xn_self
        encB[i] = f2bf(v);
    }
    if (i < 192*96){                               // Bih[n][c] (pitch 96)
        int n = i/96, c = i%96;
        float v = 0.f;
        if (c >= 1 && c <= 17)       v = eWih[n*82 + c];        // y,X0..15
        else if (c == 19)            v = eWih[n*82 + 0];        // xn_self
        else if (c >= 32 && c < 96)  v = eWih[n*82 + 18 + (c-32)]; // conv
        encB[3584 + i] = f2bf(v);
    }
    if (i < 192*72){                               // Bhh / dec images
        int n = i/72, k = i%72;
        encB[22016 + i] = f2bf((k < 64) ? eWhh[n*64 + k] : 0.f);
        decB[i]         = f2bf((k < 64) ? dWih[n*64 + k] : 0.f);
        decB[13824 + i] = f2bf((k < 64) ? dWhh[n*64 + k] : 0.f);
    }
}

// ---------------- pre-pass: static image [t][gblk 256][node 128][IMGP] bf16 ------
__global__ __launch_bounds__(1024, 4) void agg_pre(
    const float* __restrict__ X, const float* __restrict__ y,
    const int*   __restrict__ esrc, const float* __restrict__ ew,
    unsigned short* __restrict__ img)
{
    extern __shared__ float sm[];
    float* Xs = sm;            // [1000][16]
    float* ys = sm + NN*FF;    // [1000]

    const int b = blockIdx.x;
    const int t = blockIdx.y;
    const float* Xt = X + (size_t)(b*TT + t)*NN*FF;
    const float* yt = y + (size_t)(b*TT + t)*NN;

    for (int i = threadIdx.x; i < NN*FF/4; i += 1024)
        ((float4*)Xs)[i] = ((const float4*)Xt)[i];
    for (int i = threadIdx.x; i < NN; i += 1024)
        ys[i] = yt[i];
    __syncthreads();

    const int nl = threadIdx.x;                    // 0..1023 (>=1000 -> clamp dup)
    const int nc = (nl < NN) ? nl : NN-1;
    const int node = b*NN + nc;
    float a[18];
    #pragma unroll
    for (int i=0;i<17;i++) a[i]=0.f;
    const int4*   sv = (const int4*)  (esrc + node*DEG);
    const float4* wv = (const float4*)(ew   + node*DEG);
    #pragma unroll
    for (int q=0;q<4;q++){
        int4 s4 = sv[q]; float4 w4 = wv[q];
        const int   ss[4] = {s4.x, s4.y, s4.z, s4.w};
        const float ww[4] = {w4.x, w4.y, w4.z, w4.w};
        #pragma unroll
        for (int i=0;i<4;i++){
            const int sl = ss[i] - b*NN;
            const float wgt = ww[i];
            a[0] += wgt * ys[sl];
            const float4* sr = (const float4*)&Xs[sl*FF];
            #pragma unroll
            for (int q2=0;q2<4;q2++){
                float4 v = sr[q2];
                a[1+4*q2] += wgt*v.x; a[2+4*q2] += wgt*v.y;
                a[3+4*q2] += wgt*v.z; a[4+4*q2] += wgt*v.w;
            }
        }
    }
    a[17] = ys[nc];
    const int gblk = b*8 + (nl >> 7);
    unsigned int* w32 = (unsigned int*)(img +
        (((size_t)t*256 + gblk)*128 + (nl & 127))*IMGP);
    #pragma unroll
    for (int p=0;p<9;p++)  w32[p]   = cvtpk(a[2*p], a[2*p+1]);       // cols 0..17
    #pragma unroll
    for (int p=0;p<8;p++)  w32[9+p] = cvtpk(Xs[nc*FF+2*p], Xs[nc*FF+2*p+1]); // 18..33
}

// ---------------- fused persistent kernel ----------------
// LDS (bytes): enc weights @0..71680 | A_s @71680 (128x136 bf16) |
//              A_hbf @106496 (128x72 bf16, hi-only h) | h_f32 @124928 (128x68 f32)
#define OFFB1   0
#define OFFBIH  3584
#define OFFBHH  22016
#define DOFFBIH 0
#define DOFFBHH 13824
#define OFFAS   35840     // shorts
#define OFFAHB  53248     // shorts
#define OFFHF   124928    // bytes
#define FU_SMEM 159744
#define PAS  136
#define PB1  56
#define PBIH 96
#define PB72 72
#define PHF  68

__global__ __launch_bounds__(512, 1) void fused_steps(
    const float* __restrict__ X,
    const int* __restrict__ esrc, const float* __restrict__ ew,
    const unsigned short* __restrict__ img,
    const unsigned short* __restrict__ encB, const unsigned short* __restrict__ decB,
    const float* __restrict__ b_rel,
    const float* __restrict__ ebih, const float* __restrict__ ebhh,
    const float* __restrict__ eWout, const float* __restrict__ ebout,
    const float* __restrict__ dbih, const float* __restrict__ dbhh,
    const float* __restrict__ dWin, const float* __restrict__ dbin,
    const float* __restrict__ dWout, const float* __restrict__ dbout,
    float* __restrict__ xnA, float* __restrict__ xnB,
    unsigned int* __restrict__ bar, float* __restrict__ out)
{
    extern __shared__ char smraw[];
    __shared__ float xnL[128];
    unsigned short* sm16 = (unsigned short*)smraw;
    float* hf = (float*)(smraw + OFFHF);

    const int tid  = threadIdx.x;
    const int lane = tid & 63;
    const int w    = __builtin_amdgcn_readfirstlane(tid >> 6);
    const int mt = w >> 1, jt = w & 1;
    const int batch = blockIdx.x >> 3;
    const int sub   = blockIdx.x & 7;
    unsigned int* mybar = bar + batch*32;

    // ---- one-time init: enc weights -> LDS, zero A_s + A_hbf + h_f32 ----
    {
        const uint4* src = (const uint4*)encB;
        uint4* dst = (uint4*)smraw;
        for (int i = tid; i < 4480; i += 512) dst[i] = src[i];
        unsigned int* z32 = (unsigned int*)(smraw + 71680);
        for (int i = tid; i < 22016; i += 512) z32[i] = 0u;
    }

    // ---- persistent per-thread state ----
    f16v hreg = {};                       // h fragment mirror (same C-layout)
    // edge list in registers (gather threads only): 16 src + 16 w
    int4 esv0={0,0,0,0}, esv1={0,0,0,0}, esv2={0,0,0,0}, esv3={0,0,0,0};
    float4 ewv0={}, ewv1={}, ewv2={}, ewv3={};
    int g_node = 0;
    if (tid < 128){
        const int nl2 = sub*128 + tid;
        const int nc  = (nl2 < NN) ? nl2 : NN-1;
        g_node = batch*NN + nc;
        const int4*   sv = (const int4*)  (esrc + g_node*DEG);
        const float4* wv = (const float4*)(ew   + g_node*DEG);
        esv0=sv[0]; esv1=sv[1]; esv2=sv[2]; esv3=sv[3];
        ewv0=wv[0]; ewv1=wv[1]; ewv2=wv[2]; ewv3=wv[3];
    }
    __syncthreads();                      // init-zero visible before staging

    // ---- stage t=0 statics into A_s (div-free) ----
    {
        const unsigned short* imgrow = img + (((size_t)0*256 + blockIdx.x)*128)*IMGP;
        {
            int node = tid >> 2, part = tid & 3;
            uint4 v = *(const uint4*)(imgrow + node*IMGP + part*8);
            *(uint4*)(sm16 + OFFAS + node*PAS + part*8) = v;
        }
        if (tid < 128){
            unsigned int v = *(const unsigned int*)(imgrow + tid*IMGP + 32);
            *(unsigned int*)(sm16 + OFFAS + tid*PAS + 32) = v;
        }
    }

    for (int t = 0; t < TT; ++t){
        const bool enc = (t < HIST);
        const float* xn_r = (t & 1) ? xnB : xnA;
        float*       xn_w = (t & 1) ? xnA : xnB;

        if (enc){
            // ---- P0d: xn-gather -> cols 34(xn_agg), 35(xn_self) (edge regs) ----
            if (tid < 128){
                float a0 = 0.f, xnv = 0.f;
                if (t > 0){
                    a0 += ewv0.x*xn_ld(xn_r + esv0.x) + ewv0.y*xn_ld(xn_r + esv0.y)
                        + ewv0.z*xn_ld(xn_r + esv0.z) + ewv0.w*xn_ld(xn_r + esv0.w);
                    a0 += ewv1.x*xn_ld(xn_r + esv1.x) + ewv1.y*xn_ld(xn_r + esv1.y)
                        + ewv1.z*xn_ld(xn_r + esv1.z) + ewv1.w*xn_ld(xn_r + esv1.w);
                    a0 += ewv2.x*xn_ld(xn_r + esv2.x) + ewv2.y*xn_ld(xn_r + esv2.y)
                        + ewv2.z*xn_ld(xn_r + esv2.z) + ewv2.w*xn_ld(xn_r + esv2.w);
                    a0 += ewv3.x*xn_ld(xn_r + esv3.x) + ewv3.y*xn_ld(xn_r + esv3.y)
                        + ewv3.z*xn_ld(xn_r + esv3.z) + ewv3.w*xn_ld(xn_r + esv3.w);
                    xnv = xn_ld(xn_r + g_node);
                }
                *(unsigned int*)(sm16 + OFFAS + tid*PAS + 34) = cvtpk(a0, xnv);
            }
            __syncthreads();

            // ---- P1: GraphConv GEMM (K=48) -> sigmoid -> A_s cols 64..127 ----
            {
                f16v acc = {};
                const int rA = mt*32 + (lane & 31);
                const int rB = jt*32 + (lane & 31);
                const int ke = (lane >> 5)*8;
                #pragma unroll
                for (int ks=0; ks<3; ks++){
                    s8v a = *(const s8v*)(sm16 + OFFAS + rA*PAS + ks*16 + ke);
                    s8v b = *(const s8v*)(sm16 + OFFB1 + rB*PB1 + ks*16 + ke);
                    acc = __builtin_amdgcn_mfma_f32_32x32x16_bf16(a, b, acc, 0, 0, 0);
                }
                const int j = jt*32 + (lane & 31);
                const float brl = b_rel[j];
                #pragma unroll
                for (int p=0; p<8; p++){
                    float s0 = sigf(acc[2*p]   + brl);
                    float s1 = sigf(acc[2*p+1] + brl);
                    unsigned int pk = cvtpk(s0, s1);
                    int row = ((2*p)&3) + 8*(p>>1) + 4*(lane>>5);   // rows r, r+1
                    sm16[OFFAS + (mt*32 + row  )*PAS + 64 + j] = (unsigned short)pk;
                    sm16[OFFAS + (mt*32 + row+1)*PAS + 64 + j] = (unsigned short)(pk>>16);
                }
            }
            __syncthreads();

            // ---- P2: GRU GEMMs (x: K=96 windows; h: hi-only K=64) ----
            f16v accx[3] = {{},{},{}};
            f16v acch[3] = {{},{},{}};
            {
                const int rA = mt*32 + (lane & 31);
                const int ln = lane & 31;
                const int ke = (lane >> 5)*8;
                #pragma unroll
                for (int s=0; s<6; s++){              // A cols {16,32,64,80,96,112}
                    const int acol = (s < 2) ? (16 + 16*s) : (32 + 16*s);
                    s8v a = *(const s8v*)(sm16 + OFFAS + rA*PAS + acol + ke);
                    #pragma unroll
                    for (int nt=0; nt<3; nt++){
                        int NT = jt + nt*2;
                        s8v b = *(const s8v*)(sm16 + OFFBIH + (NT*32 + ln)*PBIH + s*16 + ke);
                        accx[nt] = __builtin_amdgcn_mfma_f32_32x32x16_bf16(a, b, accx[nt], 0,0,0);
                    }
                }
                #pragma unroll
                for (int ks=0; ks<4; ks++){
                    s8v ah = *(const s8v*)(sm16 + OFFAHB + rA*PB72 + ks*16 + ke);
                    #pragma unroll
                    for (int nt=0; nt<3; nt++){
                        int NT = jt + nt*2;
                        s8v b = *(const s8v*)(sm16 + OFFBHH + (NT*32 + ln)*PB72 + ks*16 + ke);
                        acch[nt] = __builtin_amdgcn_mfma_f32_32x32x16_bf16(ah, b, acch[nt], 0,0,0);
                    }
                }
            }
            __syncthreads();                          // all A_hbf reads done

            // ---- P3: epilogue; hold from hreg; h' -> hreg + h_f32 + A_hbf ----
            {
                const int j = jt*32 + (lane & 31);
                const float br  = ebih[j]     + ebhh[j];
                const float bz  = ebih[64+j]  + ebhh[64+j];
                const float bin_ = ebih[128+j];
                const float bhn  = ebhh[128+j];
                #pragma unroll
                for (int p=0; p<8; p++){
                    const int r0 = 2*p, r1 = 2*p+1;
                    int row = ((r0)&3) + 8*(p>>1) + 4*(lane>>5);
                    const int n0 = mt*32 + row, n1 = n0 + 1;
                    float hold0 = hreg[r0];
                    float hold1 = hreg[r1];
                    float rr0 = sigf(accx[0][r0] + acch[0][r0] + br);
                    float rr1 = sigf(accx[0][r1] + acch[0][r1] + br);
                    float zz0 = sigf(accx[1][r0] + acch[1][r0] + bz);
                    float zz1 = sigf(accx[1][r1] + acch[1][r1] + bz);
                    float nn0 = tanhf_(accx[2][r0] + bin_ + rr0*(acch[2][r0] + bhn));
                    float nn1 = tanhf_(accx[2][r1] + bin_ + rr1*(acch[2][r1] + bhn));
                    float hp0 = (1.f - zz0)*nn0 + zz0*hold0;
                    float hp1 = (1.f - zz1)*nn1 + zz1*hold1;
                    hreg[r0] = hp0;
                    hreg[r1] = hp1;
                    hf[n0*PHF + j] = hp0;
                    hf[n1*PHF + j] = hp1;
                    unsigned int nh = cvtpk(hp0, hp1);
                    sm16[OFFAHB + n0*PB72 + j] = (unsigned short)nh;
                    sm16[OFFAHB + n1*PB72 + j] = (unsigned short)(nh>>16);
                }
            }
            __syncthreads();

            // ---- prefetch next step's statics (off critical path) ----
            if (t+1 < HIST){
                const unsigned short* imgrow = img +
                    (((size_t)(t+1)*256 + blockIdx.x)*128)*IMGP;
                {
                    int node = tid >> 2, part = tid & 3;
                    uint4 v = *(const uint4*)(imgrow + node*IMGP + part*8);
                    *(uint4*)(sm16 + OFFAS + node*PAS + part*8) = v;
                }
                if (tid < 128){
                    unsigned int v = *(const unsigned int*)(imgrow + tid*IMGP + 32);
                    *(unsigned int*)(sm16 + OFFAS + tid*PAS + 32) = v;
                }
            }

            // ---- P4: xn = h' @ Wout + bout (2 waves, f32 reads) ----
            if (tid < 128){
                const float4* hv = (const float4*)(hf + tid*PHF);
                float s = ebout[0];
                #pragma unroll
                for (int q=0; q<16; q++){
                    float4 v = hv[q];
                    s += v.x*eWout[4*q] + v.y*eWout[4*q+1]
                       + v.z*eWout[4*q+2] + v.w*eWout[4*q+3];
                }
                const int nl2 = sub*128 + tid;
                if (nl2 < NN) xn_st(xn_w + batch*NN + nl2, s);
            }
        } else {
            // ---- decoder (block-local; no grid sync) ----
            if (t == HIST){                           // overlay dec weights once
                const uint4* src = (const uint4*)decB;
                uint4* dst = (uint4*)smraw;
                for (int i = tid; i < 3456; i += 512) dst[i] = src[i];
            }
            // P0b: xin = [xn|X13..15] @ Win + bin -> A_x (pitch 72 @ OFFAS)
            {
                const int node = tid >> 2, c0 = (tid & 3)*16;
                const int nl2 = sub*128 + node;
                const int nc  = (nl2 < NN) ? nl2 : NN-1;
                const float* Xt = X + (size_t)(batch*TT + t)*NN*FF;
                float x0 = (t == HIST) ? xn_ld(xn_r + batch*NN + nc) : xnL[node];
                float x1 = Xt[nc*FF + 13];
                float x2 = Xt[nc*FF + 14];
                float x3 = Xt[nc*FF + 15];
                unsigned int* ax32 = (unsigned int*)(sm16 + OFFAS);
                #pragma unroll
                for (int p=0; p<8; p++){
                    int c = c0 + 2*p;
                    float va = dbin[c]   + x0*dWin[c]     + x1*dWin[64+c]   + x2*dWin[128+c]   + x3*dWin[192+c];
                    float vb = dbin[c+1] + x0*dWin[c+1]   + x1*dWin[64+c+1] + x2*dWin[128+c+1] + x3*dWin[192+c+1];
                    ax32[(node*PB72 + c) >> 1] = cvtpk(va, vb);
                }
            }
            __syncthreads();

            f16v accx[3] = {{},{},{}};
            f16v acch[3] = {{},{},{}};
            {
                const int rA = mt*32 + (lane & 31);
                const int ln = lane & 31;
                const int ke = (lane >> 5)*8;
                #pragma unroll
                for (int ks=0; ks<4; ks++){
                    s8v a = *(const s8v*)(sm16 + OFFAS + rA*PB72 + ks*16 + ke);
                    #pragma unroll
                    for (int nt=0; nt<3; nt++){
                        int NT = jt + nt*2;
                        s8v b = *(const s8v*)(sm16 + DOFFBIH + (NT*32 + ln)*PB72 + ks*16 + ke);
                        accx[nt] = __builtin_amdgcn_mfma_f32_32x32x16_bf16(a, b, accx[nt], 0,0,0);
                    }
                }
                #pragma unroll
                for (int ks=0; ks<4; ks++){
                    s8v ah = *(const s8v*)(sm16 + OFFAHB + rA*PB72 + ks*16 + ke);
                    #pragma unroll
                    for (int nt=0; nt<3; nt++){
                        int NT = jt + nt*2;
                        s8v b = *(const s8v*)(sm16 + DOFFBHH + (NT*32 + ln)*PB72 + ks*16 + ke);
                        acch[nt] = __builtin_amdgcn_mfma_f32_32x32x16_bf16(ah, b, acch[nt], 0,0,0);
                    }
                }
            }
            __syncthreads();

            {
                const int j = jt*32 + (lane & 31);
                const float br  = dbih[j]     + dbhh[j];
                const float bz  = dbih[64+j]  + dbhh[64+j];
                const float bin_ = dbih[128+j];
                const float bhn  = dbhh[128+j];
                #pragma unroll
                for (int p=0; p<8; p++){
                    const int r0 = 2*p, r1 = 2*p+1;
                    int row = ((r0)&3) + 8*(p>>1) + 4*(lane>>5);
                    const int n0 = mt*32 + row, n1 = n0 + 1;
                    float hold0 = hreg[r0];
                    float hold1 = hreg[r1];
                    float rr0 = sigf(accx[0][r0] + acch[0][r0] + br);
                    float rr1 = sigf(accx[0][r1] + acch[0][r1] + br);
                    float zz0 = sigf(accx[1][r0] + acch[1][r0] + bz);
                    float zz1 = sigf(accx[1][r1] + acch[1][r1] + bz);
                    float nn0 = tanhf_(accx[2][r0] + bin_ + rr0*(acch[2][r0] + bhn));
                    float nn1 = tanhf_(accx[2][r1] + bin_ + rr1*(acch[2][r1] + bhn));
                    float hp0 = (1.f - zz0)*nn0 + zz0*hold0;
                    float hp1 = (1.f - zz1)*nn1 + zz1*hold1;
                    hreg[r0] = hp0;
                    hreg[r1] = hp1;
                    hf[n0*PHF + j] = hp0;
                    hf[n1*PHF + j] = hp1;
                    unsigned int nh = cvtpk(hp0, hp1);
                    sm16[OFFAHB + n0*PB72 + j] = (unsigned short)nh;
                    sm16[OFFAHB + n1*PB72 + j] = (unsigned short)(nh>>16);
                }
            }
            __syncthreads();

            if (tid < 128){
                const float4* hv = (const float4*)(hf + tid*PHF);
                float s = dbout[0];
                #pragma unroll
                for (int q=0; q<16; q++){
                    float4 v = hv[q];
                    s += v.x*dWout[4*q] + v.y*dWout[4*q+1]
                       + v.z*dWout[4*q+2] + v.w*dWout[4*q+3];
                }
                xnL[tid] = s;
                const int nl2 = sub*128 + tid;
                if (nl2 < NN)
                    out[(size_t)(batch*FC + (t - HIST))*NN + nl2] = s;
            }
        }
        // sync: per-batch barrier between encoder steps; local sync otherwise
        if (t < HIST-1) batch_barrier(mybar, 8u*(unsigned)(t+1));
        else            __syncthreads();
    }
}

extern "C" void kernel_launch(void* const* d_in, const int* in_sizes, int n_in,
                              void* d_out, int out_size, void* d_ws, size_t ws_size,
                              hipStream_t stream)
{
    const float* X     = (const float*)d_in[0];
    const float* y     = (const float*)d_in[1];
    const int*   ei    = (const int*)  d_in[2];
    const float* ew    = (const float*)d_in[3];
    const float* W_rel = (const float*)d_in[4];
    const float* b_rel = (const float*)d_in[5];
    const float* W_root= (const float*)d_in[6];
    const float* eWih  = (const float*)d_in[7];
    const float* eWhh  = (const float*)d_in[8];
    const float* ebih  = (const float*)d_in[9];
    const float* ebhh  = (const float*)d_in[10];
    const float* eWout = (const float*)d_in[11];
    const float* ebout = (const float*)d_in[12];
    const float* dWin  = (const float*)d_in[13];
    const float* dbin  = (const float*)d_in[14];
    const float* dWih  = (const float*)d_in[15];
    const float* dWhh  = (const float*)d_in[16];
    const float* dbih  = (const float*)d_in[17];
    const float* dbhh  = (const float*)d_in[18];
    const float* dWout = (const float*)d_in[19];
    const float* dbout = (const float*)d_in[20];
    float* out = (float*)d_out;

    // ws: img 62.9MB | xn ping-pong 2x128KB | encB 71.7KB | decB 55.3KB | bar 4KB
    unsigned short* img = (unsigned short*)d_ws;
    float* x0 = (float*)(img + (size_t)24*256*128*IMGP);
    float* x1 = x0 + BN;
    unsigned short* encB = (unsigned short*)(x1 + BN);
    unsigned short* decB = encB + 35840;
    unsigned int* bar = (unsigned int*)(decB + 27648);

    const int* esrc = ei;

    const int smA = (NN*FF + NN)*sizeof(float);
    hipFuncSetAttribute((const void*)agg_pre,
                        hipFuncAttributeMaxDynamicSharedMemorySize, smA);
    hipFuncSetAttribute((const void*)fused_steps,
                        hipFuncAttributeMaxDynamicSharedMemorySize, FU_SMEM);

    hipMemsetAsync(bar, 0, 32*32*sizeof(unsigned int), stream);
    prep_weights<<<78, 256, 0, stream>>>(W_rel, W_root, eWih, eWhh, dWih, dWhh, encB, decB);
    agg_pre<<<dim3(BX,24), 1024, smA, stream>>>(X, y, esrc, ew, img);

    void* args[] = {
        (void*)&X, (void*)&esrc, (void*)&ew, (void*)&img,
        (void*)&encB, (void*)&decB,
        (void*)&b_rel, (void*)&ebih, (void*)&ebhh, (void*)&eWout, (void*)&ebout,
        (void*)&dbih, (void*)&dbhh, (void*)&dWin, (void*)&dbin, (void*)&dWout, (void*)&dbout,
        (void*)&x0, (void*)&x1, (void*)&bar, (void*)&out
    };
    hipLaunchCooperativeKernel((const void*)fused_steps, dim3(256), dim3(512),
                               args, FU_SMEM, stream);
}

// Round 19
// 414.911 us; speedup vs baseline: 4.2702x; 1.1748x over previous
//
#include <hip/hip_runtime.h>
#include <cstdint>

#define BX   32
#define NN   1000
#define FF   16
#define TT   48          // HIST + FC
#define HIST 24
#define FC   24
#define HID  64
#define DEG  16
#define BN   (BX*NN)     // 32000 nodes
#define IMGP 40          // static-image pitch (shorts/node)

typedef __attribute__((ext_vector_type(8)))  short s8v;   // bf16x8 MFMA frag
typedef __attribute__((ext_vector_type(16))) float f16v;  // 32x32 accumulator

// v_rcp_f32 + one Newton iteration: <=1 ulp of IEEE divide, 3 ops vs ~10.
__device__ __forceinline__ float fastrcp(float d){
    float r = __builtin_amdgcn_rcpf(d);
    return r * (2.0f - d*r);
}
__device__ __forceinline__ float sigf(float x)  {
    return fastrcp(1.0f + __expf(-x));
}
__device__ __forceinline__ float tanhf_(float x){
    return 2.0f*fastrcp(1.0f + __expf(-2.0f*x)) - 1.0f;
}
__device__ __forceinline__ unsigned short f2bf(float x){
    unsigned int u = __float_as_uint(x);
    return (unsigned short)((u + 0x7FFFu + ((u>>16)&1u)) >> 16);   // RNE
}
__device__ __forceinline__ float bf2f(unsigned short b){
    return __uint_as_float(((unsigned int)b)<<16);
}
// packed f32x2 -> bf16x2 (lo = a, hi = b), hardware RNE
__device__ __forceinline__ unsigned int cvtpk(float a, float b){
    unsigned int r;
    asm("v_cvt_pk_bf16_f32 %0, %1, %2" : "=v"(r) : "v"(a), "v"(b));
    return r;
}

// xn moves through agent-scope atomics (coherent at LLC, bypasses per-XCD L2).
__device__ __forceinline__ void  xn_st(float* p, float v){
    __hip_atomic_store(p, v, __ATOMIC_RELAXED, __HIP_MEMORY_SCOPE_AGENT);
}
__device__ __forceinline__ float xn_ld(const float* p){
    return __hip_atomic_load(p, __ATOMIC_RELAXED, __HIP_MEMORY_SCOPE_AGENT);
}

// flush-free PER-BATCH barrier (8 blocks), monotonic counter, relaxed atomics.
__device__ __forceinline__ void batch_barrier(unsigned int* bar, unsigned int target){
    __syncthreads();
    if (threadIdx.x == 0){
        asm volatile("s_waitcnt vmcnt(0)" ::: "memory");
        __hip_atomic_fetch_add(bar, 1u, __ATOMIC_RELAXED, __HIP_MEMORY_SCOPE_AGENT);
        while (__hip_atomic_load(bar, __ATOMIC_RELAXED, __HIP_MEMORY_SCOPE_AGENT) < target)
            __builtin_amdgcn_s_sleep(1);
    }
    __syncthreads();
}

// A_s column map (enc): 0..16 agg | 17 y | 18..33 X | 34 xn_agg | 35 xn_self
//                       | 36..63 zero | 64..127 conv
// encB: [B1 64x56 | Bih 192x96 | Bhh 192x72]   decB: [Bihd 192x72 | Bhhd 192x72]
__global__ void prep_weights(
    const float* __restrict__ W_rel, const float* __restrict__ W_root,
    const float* __restrict__ eWih, const float* __restrict__ eWhh,
    const float* __restrict__ dWih, const float* __restrict__ dWhh,
    unsigned short* __restrict__ encB, unsigned short* __restrict__ decB)
{
    const int i = blockIdx.x*256 + threadIdx.x;
    if (i < 64*56){                                // B1[n][k]
        int n = i/56, k = i%56;
        float v = 0.f;
        if (k < 17)                 v = W_rel[(k+1)*64 + n];    // agg ch 1..17
        else if (k == 17)           v = W_root[64 + n];         // y_self
        else if (k >= 18 && k < 34) v = W_root[(k-16)*64 + n];  // X_self 0..15
        else if (k == 34)           v = W_rel[n];               // xn_agg
        else if (k == 35)           v = W_root[n];              // xn_self
        encB[i] = f2bf(v);
    }
    if (i < 192*96){                               // Bih[n][c] (pitch 96)
        int n = i/96, c = i%96;
        float v = 0.f;
        if (c >= 1 && c <= 17)       v = eWih[n*82 + c];        // y,X0..15
        else if (c == 19)            v = eWih[n*82 + 0];        // xn_self
        else if (c >= 32 && c < 96)  v = eWih[n*82 + 18 + (c-32)]; // conv
        encB[3584 + i] = f2bf(v);
    }
    if (i < 192*72){                               // Bhh / dec images
        int n = i/72, k = i%72;
        encB[22016 + i] = f2bf((k < 64) ? eWhh[n*64 + k] : 0.f);
        decB[i]         = f2bf((k < 64) ? dWih[n*64 + k] : 0.f);
        decB[13824 + i] = f2bf((k < 64) ? dWhh[n*64 + k] : 0.f);
    }
}

// ---------------- pre-pass: static image [t][gblk 256][node 128][IMGP] bf16 ------
__global__ __launch_bounds__(1024, 4) void agg_pre(
    const float* __restrict__ X, const float* __restrict__ y,
    const int*   __restrict__ esrc, const float* __restrict__ ew,
    unsigned short* __restrict__ img)
{
    extern __shared__ float sm[];
    float* Xs = sm;            // [1000][16]
    float* ys = sm + NN*FF;    // [1000]

    const int b = blockIdx.x;
    const int t = blockIdx.y;
    const float* Xt = X + (size_t)(b*TT + t)*NN*FF;
    const float* yt = y + (size_t)(b*TT + t)*NN;

    for (int i = threadIdx.x; i < NN*FF/4; i += 1024)
        ((float4*)Xs)[i] = ((const float4*)Xt)[i];
    for (int i = threadIdx.x; i < NN; i += 1024)
        ys[i] = yt[i];
    __syncthreads();

    const int nl = threadIdx.x;                    // 0..1023 (>=1000 -> clamp dup)
    const int nc = (nl < NN) ? nl : NN-1;
    const int node = b*NN + nc;
    float a[18];
    #pragma unroll
    for (int i=0;i<17;i++) a[i]=0.f;
    const int4*   sv = (const int4*)  (esrc + node*DEG);
    const float4* wv = (const float4*)(ew   + node*DEG);
    #pragma unroll
    for (int q=0;q<4;q++){
        int4 s4 = sv[q]; float4 w4 = wv[q];
        const int   ss[4] = {s4.x, s4.y, s4.z, s4.w};
        const float ww[4] = {w4.x, w4.y, w4.z, w4.w};
        #pragma unroll
        for (int i=0;i<4;i++){
            const int sl = ss[i] - b*NN;
            const float wgt = ww[i];
            a[0] += wgt * ys[sl];
            const float4* sr = (const float4*)&Xs[sl*FF];
            #pragma unroll
            for (int q2=0;q2<4;q2++){
                float4 v = sr[q2];
                a[1+4*q2] += wgt*v.x; a[2+4*q2] += wgt*v.y;
                a[3+4*q2] += wgt*v.z; a[4+4*q2] += wgt*v.w;
            }
        }
    }
    a[17] = ys[nc];
    const int gblk = b*8 + (nl >> 7);
    unsigned int* w32 = (unsigned int*)(img +
        (((size_t)t*256 + gblk)*128 + (nl & 127))*IMGP);
    #pragma unroll
    for (int p=0;p<9;p++)  w32[p]   = cvtpk(a[2*p], a[2*p+1]);       // cols 0..17
    #pragma unroll
    for (int p=0;p<8;p++)  w32[9+p] = cvtpk(Xs[nc*FF+2*p], Xs[nc*FF+2*p+1]); // 18..33
}

// ---------------- fused persistent kernel ----------------
// LDS (bytes): enc weights @0..71680 | A_s @71680 (128x136 bf16) |
//              A_hbf @106496 (128x72 bf16, hi-only h) | h_f32 @124928 (128x68 f32)
#define OFFB1   0
#define OFFBIH  3584
#define OFFBHH  22016
#define DOFFBIH 0
#define DOFFBHH 13824
#define OFFAS   35840     // shorts
#define OFFAHB  53248     // shorts
#define OFFHF   124928    // bytes
#define FU_SMEM 159744
#define PAS  136
#define PB1  56
#define PBIH 96
#define PB72 72
#define PHF  68

__global__ __launch_bounds__(512, 1) void fused_steps(
    const float* __restrict__ X,
    const int* __restrict__ esrc, const float* __restrict__ ew,
    const unsigned short* __restrict__ img,
    const unsigned short* __restrict__ encB, const unsigned short* __restrict__ decB,
    const float* __restrict__ b_rel,
    const float* __restrict__ ebih, const float* __restrict__ ebhh,
    const float* __restrict__ eWout, const float* __restrict__ ebout,
    const float* __restrict__ dbih, const float* __restrict__ dbhh,
    const float* __restrict__ dWin, const float* __restrict__ dbin,
    const float* __restrict__ dWout, const float* __restrict__ dbout,
    float* __restrict__ xnA, float* __restrict__ xnB,
    unsigned int* __restrict__ bar, float* __restrict__ out)
{
    extern __shared__ char smraw[];
    __shared__ float xnL[128];
    unsigned short* sm16 = (unsigned short*)smraw;
    float* hf = (float*)(smraw + OFFHF);

    const int tid  = threadIdx.x;
    const int lane = tid & 63;
    const int w    = __builtin_amdgcn_readfirstlane(tid >> 6);
    const int mt = w >> 1, jt = w & 1;
    const int batch = blockIdx.x >> 3;
    const int sub   = blockIdx.x & 7;
    unsigned int* mybar = bar + batch*32;

    // ---- one-time init: enc weights -> LDS, zero A_s + A_hbf + h_f32 ----
    {
        const uint4* src = (const uint4*)encB;
        uint4* dst = (uint4*)smraw;
        for (int i = tid; i < 4480; i += 512) dst[i] = src[i];
        unsigned int* z32 = (unsigned int*)(smraw + 71680);
        for (int i = tid; i < 22016; i += 512) z32[i] = 0u;
    }

    // ---- persistent per-thread state ----
    f16v hreg = {};                       // h fragment mirror (same C-layout)
    // edge list in registers (gather threads only): 16 src + 16 w
    int4 esv0={0,0,0,0}, esv1={0,0,0,0}, esv2={0,0,0,0}, esv3={0,0,0,0};
    float4 ewv0={}, ewv1={}, ewv2={}, ewv3={};
    int g_node = 0;
    if (tid < 128){
        const int nl2 = sub*128 + tid;
        const int nc  = (nl2 < NN) ? nl2 : NN-1;
        g_node = batch*NN + nc;
        const int4*   sv = (const int4*)  (esrc + g_node*DEG);
        const float4* wv = (const float4*)(ew   + g_node*DEG);
        esv0=sv[0]; esv1=sv[1]; esv2=sv[2]; esv3=sv[3];
        ewv0=wv[0]; ewv1=wv[1]; ewv2=wv[2]; ewv3=wv[3];
    }
    __syncthreads();                      // init-zero visible before staging

    // ---- stage t=0 statics into A_s (div-free) ----
    {
        const unsigned short* imgrow = img + (((size_t)0*256 + blockIdx.x)*128)*IMGP;
        {
            int node = tid >> 2, part = tid & 3;
            uint4 v = *(const uint4*)(imgrow + node*IMGP + part*8);
            *(uint4*)(sm16 + OFFAS + node*PAS + part*8) = v;
        }
        if (tid < 128){
            unsigned int v = *(const unsigned int*)(imgrow + tid*IMGP + 32);
            *(unsigned int*)(sm16 + OFFAS + tid*PAS + 32) = v;
        }
    }

    for (int t = 0; t < TT; ++t){
        const bool enc = (t < HIST);
        const float* xn_r = (t & 1) ? xnB : xnA;
        float*       xn_w = (t & 1) ? xnA : xnB;

        if (enc){
            // ---- P0d: xn-gather -> cols 34(xn_agg), 35(xn_self) (edge regs) ----
            if (tid < 128){
                float a0 = 0.f, xnv = 0.f;
                if (t > 0){
                    a0 += ewv0.x*xn_ld(xn_r + esv0.x) + ewv0.y*xn_ld(xn_r + esv0.y)
                        + ewv0.z*xn_ld(xn_r + esv0.z) + ewv0.w*xn_ld(xn_r + esv0.w);
                    a0 += ewv1.x*xn_ld(xn_r + esv1.x) + ewv1.y*xn_ld(xn_r + esv1.y)
                        + ewv1.z*xn_ld(xn_r + esv1.z) + ewv1.w*xn_ld(xn_r + esv1.w);
                    a0 += ewv2.x*xn_ld(xn_r + esv2.x) + ewv2.y*xn_ld(xn_r + esv2.y)
                        + ewv2.z*xn_ld(xn_r + esv2.z) + ewv2.w*xn_ld(xn_r + esv2.w);
                    a0 += ewv3.x*xn_ld(xn_r + esv3.x) + ewv3.y*xn_ld(xn_r + esv3.y)
                        + ewv3.z*xn_ld(xn_r + esv3.z) + ewv3.w*xn_ld(xn_r + esv3.w);
                    xnv = xn_ld(xn_r + g_node);
                }
                *(unsigned int*)(sm16 + OFFAS + tid*PAS + 34) = cvtpk(a0, xnv);
            }
            __syncthreads();

            // ---- P1: GraphConv GEMM (K=48) -> sigmoid -> A_s cols 64..127 ----
            {
                f16v acc = {};
                const int rA = mt*32 + (lane & 31);
                const int rB = jt*32 + (lane & 31);
                const int ke = (lane >> 5)*8;
                #pragma unroll
                for (int ks=0; ks<3; ks++){
                    s8v a = *(const s8v*)(sm16 + OFFAS + rA*PAS + ks*16 + ke);
                    s8v b = *(const s8v*)(sm16 + OFFB1 + rB*PB1 + ks*16 + ke);
                    acc = __builtin_amdgcn_mfma_f32_32x32x16_bf16(a, b, acc, 0, 0, 0);
                }
                const int j = jt*32 + (lane & 31);
                const float brl = b_rel[j];
                #pragma unroll
                for (int p=0; p<8; p++){
                    float s0 = sigf(acc[2*p]   + brl);
                    float s1 = sigf(acc[2*p+1] + brl);
                    unsigned int pk = cvtpk(s0, s1);
                    int row = ((2*p)&3) + 8*(p>>1) + 4*(lane>>5);   // rows r, r+1
                    sm16[OFFAS + (mt*32 + row  )*PAS + 64 + j] = (unsigned short)pk;
                    sm16[OFFAS + (mt*32 + row+1)*PAS + 64 + j] = (unsigned short)(pk>>16);
                }
            }
            __syncthreads();

            // ---- P2: GRU GEMMs (x: K=96 windows; h: hi-only K=64) ----
            f16v accx[3] = {{},{},{}};
            f16v acch[3] = {{},{},{}};
            {
                const int rA = mt*32 + (lane & 31);
                const int ln = lane & 31;
                const int ke = (lane >> 5)*8;
                #pragma unroll
                for (int s=0; s<6; s++){              // A cols {16,32,64,80,96,112}
                    const int acol = (s < 2) ? (16 + 16*s) : (32 + 16*s);
                    s8v a = *(const s8v*)(sm16 + OFFAS + rA*PAS + acol + ke);
                    #pragma unroll
                    for (int nt=0; nt<3; nt++){
                        int NT = jt + nt*2;
                        s8v b = *(const s8v*)(sm16 + OFFBIH + (NT*32 + ln)*PBIH + s*16 + ke);
                        accx[nt] = __builtin_amdgcn_mfma_f32_32x32x16_bf16(a, b, accx[nt], 0,0,0);
                    }
                }
                #pragma unroll
                for (int ks=0; ks<4; ks++){
                    s8v ah = *(const s8v*)(sm16 + OFFAHB + rA*PB72 + ks*16 + ke);
                    #pragma unroll
                    for (int nt=0; nt<3; nt++){
                        int NT = jt + nt*2;
                        s8v b = *(const s8v*)(sm16 + OFFBHH + (NT*32 + ln)*PB72 + ks*16 + ke);
                        acch[nt] = __builtin_amdgcn_mfma_f32_32x32x16_bf16(ah, b, acch[nt], 0,0,0);
                    }
                }
            }
            __syncthreads();                          // all A_hbf reads done

            // ---- P3: epilogue; hold from hreg; h' -> hreg + h_f32 + A_hbf ----
            {
                const int j = jt*32 + (lane & 31);
                const float br  = ebih[j]     + ebhh[j];
                const float bz  = ebih[64+j]  + ebhh[64+j];
                const float bin_ = ebih[128+j];
                const float bhn  = ebhh[128+j];
                #pragma unroll
                for (int p=0; p<8; p++){
                    const int r0 = 2*p, r1 = 2*p+1;
                    int row = ((r0)&3) + 8*(p>>1) + 4*(lane>>5);
                    const int n0 = mt*32 + row, n1 = n0 + 1;
                    float hold0 = hreg[r0];
                    float hold1 = hreg[r1];
                    float rr0 = sigf(accx[0][r0] + acch[0][r0] + br);
                    float rr1 = sigf(accx[0][r1] + acch[0][r1] + br);
                    float zz0 = sigf(accx[1][r0] + acch[1][r0] + bz);
                    float zz1 = sigf(accx[1][r1] + acch[1][r1] + bz);
                    float nn0 = tanhf_(accx[2][r0] + bin_ + rr0*(acch[2][r0] + bhn));
                    float nn1 = tanhf_(accx[2][r1] + bin_ + rr1*(acch[2][r1] + bhn));
                    float hp0 = (1.f - zz0)*nn0 + zz0*hold0;
                    float hp1 = (1.f - zz1)*nn1 + zz1*hold1;
                    hreg[r0] = hp0;
                    hreg[r1] = hp1;
                    hf[n0*PHF + j] = hp0;
                    hf[n1*PHF + j] = hp1;
                    unsigned int nh = cvtpk(hp0, hp1);
                    sm16[OFFAHB + n0*PB72 + j] = (unsigned short)nh;
                    sm16[OFFAHB + n1*PB72 + j] = (unsigned short)(nh>>16);
                }
            }
            __syncthreads();

            // ---- prefetch next step's statics (off critical path) ----
            if (t+1 < HIST){
                const unsigned short* imgrow = img +
                    (((size_t)(t+1)*256 + blockIdx.x)*128)*IMGP;
                {
                    int node = tid >> 2, part = tid & 3;
                    uint4 v = *(const uint4*)(imgrow + node*IMGP + part*8);
                    *(uint4*)(sm16 + OFFAS + node*PAS + part*8) = v;
                }
                if (tid < 128){
                    unsigned int v = *(const unsigned int*)(imgrow + tid*IMGP + 32);
                    *(unsigned int*)(sm16 + OFFAS + tid*PAS + 32) = v;
                }
            }

            // ---- P4: xn = h' @ Wout + bout (2 waves, f32 reads) ----
            if (tid < 128){
                const float4* hv = (const float4*)(hf + tid*PHF);
                float s = ebout[0];
                #pragma unroll
                for (int q=0; q<16; q++){
                    float4 v = hv[q];
                    s += v.x*eWout[4*q] + v.y*eWout[4*q+1]
                       + v.z*eWout[4*q+2] + v.w*eWout[4*q+3];
                }
                const int nl2 = sub*128 + tid;
                if (nl2 < NN) xn_st(xn_w + batch*NN + nl2, s);
            }
        } else {
            // ---- decoder (block-local; no grid sync) ----
            if (t == HIST){                           // overlay dec weights once
                const uint4* src = (const uint4*)decB;
                uint4* dst = (uint4*)smraw;
                for (int i = tid; i < 3456; i += 512) dst[i] = src[i];
            }
            // P0b: xin = [xn|X13..15] @ Win + bin -> A_x (pitch 72 @ OFFAS)
            {
                const int node = tid >> 2, c0 = (tid & 3)*16;
                const int nl2 = sub*128 + node;
                const int nc  = (nl2 < NN) ? nl2 : NN-1;
                const float* Xt = X + (size_t)(batch*TT + t)*NN*FF;
                float x0 = (t == HIST) ? xn_ld(xn_r + batch*NN + nc) : xnL[node];
                float x1 = Xt[nc*FF + 13];
                float x2 = Xt[nc*FF + 14];
                float x3 = Xt[nc*FF + 15];
                unsigned int* ax32 = (unsigned int*)(sm16 + OFFAS);
                #pragma unroll
                for (int p=0; p<8; p++){
                    int c = c0 + 2*p;
                    float va = dbin[c]   + x0*dWin[c]     + x1*dWin[64+c]   + x2*dWin[128+c]   + x3*dWin[192+c];
                    float vb = dbin[c+1] + x0*dWin[c+1]   + x1*dWin[64+c+1] + x2*dWin[128+c+1] + x3*dWin[192+c+1];
                    ax32[(node*PB72 + c) >> 1] = cvtpk(va, vb);
                }
            }
            __syncthreads();

            f16v accx[3] = {{},{},{}};
            f16v acch[3] = {{},{},{}};
            {
                const int rA = mt*32 + (lane & 31);
                const int ln = lane & 31;
                const int ke = (lane >> 5)*8;
                #pragma unroll
                for (int ks=0; ks<4; ks++){
                    s8v a = *(const s8v*)(sm16 + OFFAS + rA*PB72 + ks*16 + ke);
                    #pragma unroll
                    for (int nt=0; nt<3; nt++){
                        int NT = jt + nt*2;
                        s8v b = *(const s8v*)(sm16 + DOFFBIH + (NT*32 + ln)*PB72 + ks*16 + ke);
                        accx[nt] = __builtin_amdgcn_mfma_f32_32x32x16_bf16(a, b, accx[nt], 0,0,0);
                    }
                }
                #pragma unroll
                for (int ks=0; ks<4; ks++){
                    s8v ah = *(const s8v*)(sm16 + OFFAHB + rA*PB72 + ks*16 + ke);
                    #pragma unroll
                    for (int nt=0; nt<3; nt++){
                        int NT = jt + nt*2;
                        s8v b = *(const s8v*)(sm16 + DOFFBHH + (NT*32 + ln)*PB72 + ks*16 + ke);
                        acch[nt] = __builtin_amdgcn_mfma_f32_32x32x16_bf16(ah, b, acch[nt], 0,0,0);
                    }
                }
            }
            __syncthreads();

            {
                const int j = jt*32 + (lane & 31);
                const float br  = dbih[j]     + dbhh[j];
                const float bz  = dbih[64+j]  + dbhh[64+j];
                const float bin_ = dbih[128+j];
                const float bhn  = dbhh[128+j];
                #pragma unroll
                for (int p=0; p<8; p++){
                    const int r0 = 2*p, r1 = 2*p+1;
                    int row = ((r0)&3) + 8*(p>>1) + 4*(lane>>5);
                    const int n0 = mt*32 + row, n1 = n0 + 1;
                    float hold0 = hreg[r0];
                    float hold1 = hreg[r1];
                    float rr0 = sigf(accx[0][r0] + acch[0][r0] + br);
                    float rr1 = sigf(accx[0][r1] + acch[0][r1] + br);
                    float zz0 = sigf(accx[1][r0] + acch[1][r0] + bz);
                    float zz1 = sigf(accx[1][r1] + acch[1][r1] + bz);
                    float nn0 = tanhf_(accx[2][r0] + bin_ + rr0*(acch[2][r0] + bhn));
                    float nn1 = tanhf_(accx[2][r1] + bin_ + rr1*(acch[2][r1] + bhn));
                    float hp0 = (1.f - zz0)*nn0 + zz0*hold0;
                    float hp1 = (1.f - zz1)*nn1 + zz1*hold1;
                    hreg[r0] = hp0;
                    hreg[r1] = hp1;
                    hf[n0*PHF + j] = hp0;
                    hf[n1*PHF + j] = hp1;
                    unsigned int nh = cvtpk(hp0, hp1);
                    sm16[OFFAHB + n0*PB72 + j] = (unsigned short)nh;
                    sm16[OFFAHB + n1*PB72 + j] = (unsigned short)(nh>>16);
                }
            }
            __syncthreads();

            if (tid < 128){
                const float4* hv = (const float4*)(hf + tid*PHF);
                float s = dbout[0];
                #pragma unroll
                for (int q=0; q<16; q++){
                    float4 v = hv[q];
                    s += v.x*dWout[4*q] + v.y*dWout[4*q+1]
                       + v.z*dWout[4*q+2] + v.w*dWout[4*q+3];
                }
                xnL[tid] = s;
                const int nl2 = sub*128 + tid;
                if (nl2 < NN)
                    out[(size_t)(batch*FC + (t - HIST))*NN + nl2] = s;
            }
        }
        // sync: per-batch barrier between encoder steps; local sync otherwise
        if (t < HIST-1) batch_barrier(mybar, 8u*(unsigned)(t+1));
        else            __syncthreads();
    }
}

extern "C" void kernel_launch(void* const* d_in, const int* in_sizes, int n_in,
                              void* d_out, int out_size, void* d_ws, size_t ws_size,
                              hipStream_t stream)
{
    const float* X     = (const float*)d_in[0];
    const float* y     = (const float*)d_in[1];
    const int*   ei    = (const int*)  d_in[2];
    const float* ew    = (const float*)d_in[3];
    const float* W_rel = (const float*)d_in[4];
    const float* b_rel = (const float*)d_in[5];
    const float* W_root= (const float*)d_in[6];
    const float* eWih  = (const float*)d_in[7];
    const float* eWhh  = (const float*)d_in[8];
    const float* ebih  = (const float*)d_in[9];
    const float* ebhh  = (const float*)d_in[10];
    const float* eWout = (const float*)d_in[11];
    const float* ebout = (const float*)d_in[12];
    const float* dWin  = (const float*)d_in[13];
    const float* dbin  = (const float*)d_in[14];
    const float* dWih  = (const float*)d_in[15];
    const float* dWhh  = (const float*)d_in[16];
    const float* dbih  = (const float*)d_in[17];
    const float* dbhh  = (const float*)d_in[18];
    const float* dWout = (const float*)d_in[19];
    const float* dbout = (const float*)d_in[20];
    float* out = (float*)d_out;

    // ws: img 62.9MB | xn ping-pong 2x128KB | encB 71.7KB | decB 55.3KB | bar 4KB
    unsigned short* img = (unsigned short*)d_ws;
    float* x0 = (float*)(img + (size_t)24*256*128*IMGP);
    float* x1 = x0 + BN;
    unsigned short* encB = (unsigned short*)(x1 + BN);
    unsigned short* decB = encB + 35840;
    unsigned int* bar = (unsigned int*)(decB + 27648);

    const int* esrc = ei;

    const int smA = (NN*FF + NN)*sizeof(float);
    hipFuncSetAttribute((const void*)agg_pre,
                        hipFuncAttributeMaxDynamicSharedMemorySize, smA);
    hipFuncSetAttribute((const void*)fused_steps,
                        hipFuncAttributeMaxDynamicSharedMemorySize, FU_SMEM);

    hipMemsetAsync(bar, 0, 32*32*sizeof(unsigned int), stream);
    prep_weights<<<78, 256, 0, stream>>>(W_rel, W_root, eWih, eWhh, dWih, dWhh, encB, decB);
    agg_pre<<<dim3(BX,24), 1024, smA, stream>>>(X, y, esrc, ew, img);

    void* args[] = {
        (void*)&X, (void*)&esrc, (void*)&ew, (void*)&img,
        (void*)&encB, (void*)&decB,
        (void*)&b_rel, (void*)&ebih, (void*)&ebhh, (void*)&eWout, (void*)&ebout,
        (void*)&dbih, (void*)&dbhh, (void*)&dWin, (void*)&dbin, (void*)&dWout, (void*)&dbout,
        (void*)&x0, (void*)&x1, (void*)&bar, (void*)&out
    };
    hipLaunchCooperativeKernel((const void*)fused_steps, dim3(256), dim3(512),
                               args, FU_SMEM, stream);
}

// Round 20
// 412.005 us; speedup vs baseline: 4.3003x; 1.0071x over previous
//
#include <hip/hip_runtime.h>
#include <cstdint>

#define BX   32
#define NN   1000
#define FF   16
#define TT   48          // HIST + FC
#define HIST 24
#define FC   24
#define HID  64
#define DEG  16
#define BN   (BX*NN)     // 32000 nodes
#define IMGP 40          // static-image pitch (shorts/node)

typedef __attribute__((ext_vector_type(8)))  short s8v;   // bf16x8 MFMA frag
typedef __attribute__((ext_vector_type(16))) float f16v;  // 32x32 accumulator

// v_rcp_f32 + one Newton iteration: <=1 ulp of IEEE divide, 3 ops vs ~10.
__device__ __forceinline__ float fastrcp(float d){
    float r = __builtin_amdgcn_rcpf(d);
    return r * (2.0f - d*r);
}
__device__ __forceinline__ float sigf(float x)  {
    return fastrcp(1.0f + __expf(-x));
}
__device__ __forceinline__ float tanhf_(float x){
    return 2.0f*fastrcp(1.0f + __expf(-2.0f*x)) - 1.0f;
}
__device__ __forceinline__ unsigned short f2bf(float x){
    unsigned int u = __float_as_uint(x);
    return (unsigned short)((u + 0x7FFFu + ((u>>16)&1u)) >> 16);   // RNE
}
__device__ __forceinline__ float bf2f(unsigned short b){
    return __uint_as_float(((unsigned int)b)<<16);
}
// packed f32x2 -> bf16x2 (lo = a, hi = b), hardware RNE
__device__ __forceinline__ unsigned int cvtpk(float a, float b){
    unsigned int r;
    asm("v_cvt_pk_bf16_f32 %0, %1, %2" : "=v"(r) : "v"(a), "v"(b));
    return r;
}

// xn moves through agent-scope atomics (coherent at LLC, bypasses per-XCD L2).
__device__ __forceinline__ void  xn_st(float* p, float v){
    __hip_atomic_store(p, v, __ATOMIC_RELAXED, __HIP_MEMORY_SCOPE_AGENT);
}
__device__ __forceinline__ float xn_ld(const float* p){
    return __hip_atomic_load(p, __ATOMIC_RELAXED, __HIP_MEMORY_SCOPE_AGENT);
}

// flush-free PER-BATCH barrier (8 blocks), monotonic counter, relaxed atomics.
__device__ __forceinline__ void batch_barrier(unsigned int* bar, unsigned int target){
    __syncthreads();
    if (threadIdx.x == 0){
        asm volatile("s_waitcnt vmcnt(0)" ::: "memory");
        __hip_atomic_fetch_add(bar, 1u, __ATOMIC_RELAXED, __HIP_MEMORY_SCOPE_AGENT);
        while (__hip_atomic_load(bar, __ATOMIC_RELAXED, __HIP_MEMORY_SCOPE_AGENT) < target)
            __builtin_amdgcn_s_sleep(1);
    }
    __syncthreads();
}

// A_s column map (enc): 0..16 agg | 17 y | 18..33 X | 34 xn_agg | 35 xn_self
//                       | 36..63 zero | 64..127 conv
// encB: [B1 64x56 | Bih 192x96 | Bhh 192x72]   decB: [Bihd 192x72 | Bhhd 192x72]
__global__ void prep_weights(
    const float* __restrict__ W_rel, const float* __restrict__ W_root,
    const float* __restrict__ eWih, const float* __restrict__ eWhh,
    const float* __restrict__ dWih, const float* __restrict__ dWhh,
    unsigned short* __restrict__ encB, unsigned short* __restrict__ decB)
{
    const int i = blockIdx.x*256 + threadIdx.x;
    if (i < 64*56){                                // B1[n][k]
        int n = i/56, k = i%56;
        float v = 0.f;
        if (k < 17)                 v = W_rel[(k+1)*64 + n];    // agg ch 1..17
        else if (k == 17)           v = W_root[64 + n];         // y_self
        else if (k >= 18 && k < 34) v = W_root[(k-16)*64 + n];  // X_self 0..15
        else if (k == 34)           v = W_rel[n];               // xn_agg
        else if (k == 35)           v = W_root[n];              // xn_self
        encB[i] = f2bf(v);
    }
    if (i < 192*96){                               // Bih[n][c] (pitch 96)
        int n = i/96, c = i%96;
        float v = 0.f;
        if (c >= 1 && c <= 17)       v = eWih[n*82 + c];        // y,X0..15
        else if (c == 19)            v = eWih[n*82 + 0];        // xn_self
        else if (c >= 32 && c < 96)  v = eWih[n*82 + 18 + (c-32)]; // conv
        encB[3584 + i] = f2bf(v);
    }
    if (i < 192*72){                               // Bhh / dec images
        int n = i/72, k = i%72;
        encB[22016 + i] = f2bf((k < 64) ? eWhh[n*64 + k] : 0.f);
        decB[i]         = f2bf((k < 64) ? dWih[n*64 + k] : 0.f);
        decB[13824 + i] = f2bf((k < 64) ? dWhh[n*64 + k] : 0.f);
    }
}

// ---------------- pre-pass: static image [t][gblk 256][node 128][IMGP] bf16 ------
__global__ __launch_bounds__(1024, 4) void agg_pre(
    const float* __restrict__ X, const float* __restrict__ y,
    const int*   __restrict__ esrc, const float* __restrict__ ew,
    unsigned short* __restrict__ img)
{
    extern __shared__ float sm[];
    float* Xs = sm;            // [1000][16]
    float* ys = sm + NN*FF;    // [1000]

    const int b = blockIdx.x;
    const int t = blockIdx.y;
    const float* Xt = X + (size_t)(b*TT + t)*NN*FF;
    const float* yt = y + (size_t)(b*TT + t)*NN;

    for (int i = threadIdx.x; i < NN*FF/4; i += 1024)
        ((float4*)Xs)[i] = ((const float4*)Xt)[i];
    for (int i = threadIdx.x; i < NN; i += 1024)
        ys[i] = yt[i];
    __syncthreads();

    const int nl = threadIdx.x;                    // 0..1023 (>=1000 -> clamp dup)
    const int nc = (nl < NN) ? nl : NN-1;
    const int node = b*NN + nc;
    float a[18];
    #pragma unroll
    for (int i=0;i<17;i++) a[i]=0.f;
    const int4*   sv = (const int4*)  (esrc + node*DEG);
    const float4* wv = (const float4*)(ew   + node*DEG);
    #pragma unroll
    for (int q=0;q<4;q++){
        int4 s4 = sv[q]; float4 w4 = wv[q];
        const int   ss[4] = {s4.x, s4.y, s4.z, s4.w};
        const float ww[4] = {w4.x, w4.y, w4.z, w4.w};
        #pragma unroll
        for (int i=0;i<4;i++){
            const int sl = ss[i] - b*NN;
            const float wgt = ww[i];
            a[0] += wgt * ys[sl];
            const float4* sr = (const float4*)&Xs[sl*FF];
            #pragma unroll
            for (int q2=0;q2<4;q2++){
                float4 v = sr[q2];
                a[1+4*q2] += wgt*v.x; a[2+4*q2] += wgt*v.y;
                a[3+4*q2] += wgt*v.z; a[4+4*q2] += wgt*v.w;
            }
        }
    }
    a[17] = ys[nc];
    const int gblk = b*8 + (nl >> 7);
    unsigned int* w32 = (unsigned int*)(img +
        (((size_t)t*256 + gblk)*128 + (nl & 127))*IMGP);
    #pragma unroll
    for (int p=0;p<9;p++)  w32[p]   = cvtpk(a[2*p], a[2*p+1]);       // cols 0..17
    #pragma unroll
    for (int p=0;p<8;p++)  w32[9+p] = cvtpk(Xs[nc*FF+2*p], Xs[nc*FF+2*p+1]); // 18..33
}

// ---------------- fused persistent kernel ----------------
// LDS (bytes): enc weights @0..71680 | A_s @71680 (128x136 bf16) |
//              A_hbf @106496 (128x72 bf16, hi-only h) | h_f32 @124928 (128x68 f32)
#define OFFB1   0
#define OFFBIH  3584
#define OFFBHH  22016
#define DOFFBIH 0
#define DOFFBHH 13824
#define OFFAS   35840     // shorts
#define OFFAHB  53248     // shorts
#define OFFHF   124928    // bytes
#define FU_SMEM 159744
#define PAS  136
#define PB1  56
#define PBIH 96
#define PB72 72
#define PHF  68

__global__ __launch_bounds__(512, 1) void fused_steps(
    const float* __restrict__ X,
    const int* __restrict__ esrc, const float* __restrict__ ew,
    const unsigned short* __restrict__ img,
    const unsigned short* __restrict__ encB, const unsigned short* __restrict__ decB,
    const float* __restrict__ b_rel,
    const float* __restrict__ ebih, const float* __restrict__ ebhh,
    const float* __restrict__ eWout, const float* __restrict__ ebout,
    const float* __restrict__ dbih, const float* __restrict__ dbhh,
    const float* __restrict__ dWin, const float* __restrict__ dbin,
    const float* __restrict__ dWout, const float* __restrict__ dbout,
    float* __restrict__ xnA, float* __restrict__ xnB,
    unsigned int* __restrict__ bar, float* __restrict__ out)
{
    extern __shared__ char smraw[];
    __shared__ float xnL[128];
    unsigned short* sm16 = (unsigned short*)smraw;
    float* hf = (float*)(smraw + OFFHF);

    const int tid  = threadIdx.x;
    const int lane = tid & 63;
    const int w    = __builtin_amdgcn_readfirstlane(tid >> 6);
    const int mt = w >> 1, jt = w & 1;
    const int batch = blockIdx.x >> 3;
    const int sub   = blockIdx.x & 7;
    unsigned int* mybar = bar + batch*32;

    // ---- one-time init: enc weights -> LDS, zero A_s + A_hbf + h_f32 ----
    {
        const uint4* src = (const uint4*)encB;
        uint4* dst = (uint4*)smraw;
        for (int i = tid; i < 4480; i += 512) dst[i] = src[i];
        unsigned int* z32 = (unsigned int*)(smraw + 71680);
        for (int i = tid; i < 22016; i += 512) z32[i] = 0u;
    }

    // ---- persistent per-thread state ----
    f16v hreg = {};                       // h fragment mirror (same C-layout)
    // edge list in registers (gather threads only): 16 src + 16 w
    int4 esv0={0,0,0,0}, esv1={0,0,0,0}, esv2={0,0,0,0}, esv3={0,0,0,0};
    float4 ewv0={}, ewv1={}, ewv2={}, ewv3={};
    int g_node = 0;
    if (tid < 128){
        const int nl2 = sub*128 + tid;
        const int nc  = (nl2 < NN) ? nl2 : NN-1;
        g_node = batch*NN + nc;
        const int4*   sv = (const int4*)  (esrc + g_node*DEG);
        const float4* wv = (const float4*)(ew   + g_node*DEG);
        esv0=sv[0]; esv1=sv[1]; esv2=sv[2]; esv3=sv[3];
        ewv0=wv[0]; ewv1=wv[1]; ewv2=wv[2]; ewv3=wv[3];
    }
    __syncthreads();                      // init-zero visible before staging

    // ---- stage t=0 statics into A_s (div-free) ----
    {
        const unsigned short* imgrow = img + (((size_t)0*256 + blockIdx.x)*128)*IMGP;
        {
            int node = tid >> 2, part = tid & 3;
            uint4 v = *(const uint4*)(imgrow + node*IMGP + part*8);
            *(uint4*)(sm16 + OFFAS + node*PAS + part*8) = v;
        }
        if (tid < 128){
            unsigned int v = *(const unsigned int*)(imgrow + tid*IMGP + 32);
            *(unsigned int*)(sm16 + OFFAS + tid*PAS + 32) = v;
        }
    }

    for (int t = 0; t < TT; ++t){
        const bool enc = (t < HIST);
        const float* xn_r = (t & 1) ? xnB : xnA;
        float*       xn_w = (t & 1) ? xnA : xnB;

        if (enc){
            const int rA = mt*32 + (lane & 31);
            const int rB = jt*32 + (lane & 31);
            const int ke = (lane >> 5)*8;

            // ---- issue gather loads early (LLC latency hidden under P1a) ----
            float xl0=0,xl1=0,xl2=0,xl3=0,xl4=0,xl5=0,xl6=0,xl7=0;
            float xl8=0,xl9=0,xl10=0,xl11=0,xl12=0,xl13=0,xl14=0,xl15=0;
            float xnv = 0.f;
            if (tid < 128 && t > 0){
                xl0 = xn_ld(xn_r + esv0.x); xl1 = xn_ld(xn_r + esv0.y);
                xl2 = xn_ld(xn_r + esv0.z); xl3 = xn_ld(xn_r + esv0.w);
                xl4 = xn_ld(xn_r + esv1.x); xl5 = xn_ld(xn_r + esv1.y);
                xl6 = xn_ld(xn_r + esv1.z); xl7 = xn_ld(xn_r + esv1.w);
                xl8 = xn_ld(xn_r + esv2.x); xl9 = xn_ld(xn_r + esv2.y);
                xl10= xn_ld(xn_r + esv2.z); xl11= xn_ld(xn_r + esv2.w);
                xl12= xn_ld(xn_r + esv3.x); xl13= xn_ld(xn_r + esv3.y);
                xl14= xn_ld(xn_r + esv3.z); xl15= xn_ld(xn_r + esv3.w);
                xnv = xn_ld(xn_r + g_node);
            }

            // ---- P1a: GraphConv GEMM ks=0,1 (cols 0..31, gather-independent) ----
            f16v acc = {};
            #pragma unroll
            for (int ks=0; ks<2; ks++){
                s8v a = *(const s8v*)(sm16 + OFFAS + rA*PAS + ks*16 + ke);
                s8v b = *(const s8v*)(sm16 + OFFB1 + rB*PB1 + ks*16 + ke);
                acc = __builtin_amdgcn_mfma_f32_32x32x16_bf16(a, b, acc, 0, 0, 0);
            }

            // ---- finish gather: a0 = sum(w*xn[src]) -> col 34/35 ----
            if (tid < 128){
                float a0 = 0.f;
                if (t > 0){
                    a0  = ewv0.x*xl0 + ewv0.y*xl1 + ewv0.z*xl2 + ewv0.w*xl3;
                    a0 += ewv1.x*xl4 + ewv1.y*xl5 + ewv1.z*xl6 + ewv1.w*xl7;
                    a0 += ewv2.x*xl8 + ewv2.y*xl9 + ewv2.z*xl10 + ewv2.w*xl11;
                    a0 += ewv3.x*xl12 + ewv3.y*xl13 + ewv3.z*xl14 + ewv3.w*xl15;
                }
                *(unsigned int*)(sm16 + OFFAS + tid*PAS + 34) = cvtpk(a0, xnv);
            }
            __syncthreads();

            // ---- P1b: ks=2 (cols 32..47 incl. xn) -> sigmoid -> conv cols ----
            {
                s8v a = *(const s8v*)(sm16 + OFFAS + rA*PAS + 32 + ke);
                s8v b = *(const s8v*)(sm16 + OFFB1 + rB*PB1 + 32 + ke);
                acc = __builtin_amdgcn_mfma_f32_32x32x16_bf16(a, b, acc, 0, 0, 0);
                const int j = jt*32 + (lane & 31);
                const float brl = b_rel[j];
                #pragma unroll
                for (int p=0; p<8; p++){
                    float s0 = sigf(acc[2*p]   + brl);
                    float s1 = sigf(acc[2*p+1] + brl);
                    unsigned int pk = cvtpk(s0, s1);
                    int row = ((2*p)&3) + 8*(p>>1) + 4*(lane>>5);   // rows r, r+1
                    sm16[OFFAS + (mt*32 + row  )*PAS + 64 + j] = (unsigned short)pk;
                    sm16[OFFAS + (mt*32 + row+1)*PAS + 64 + j] = (unsigned short)(pk>>16);
                }
            }
            __syncthreads();

            // ---- P2: GRU GEMMs (x: K=96 windows; h: hi-only K=64) ----
            f16v accx[3] = {{},{},{}};
            f16v acch[3] = {{},{},{}};
            {
                const int ln = lane & 31;
                #pragma unroll
                for (int s=0; s<6; s++){              // A cols {16,32,64,80,96,112}
                    const int acol = (s < 2) ? (16 + 16*s) : (32 + 16*s);
                    s8v a = *(const s8v*)(sm16 + OFFAS + rA*PAS + acol + ke);
                    #pragma unroll
                    for (int nt=0; nt<3; nt++){
                        int NT = jt + nt*2;
                        s8v b = *(const s8v*)(sm16 + OFFBIH + (NT*32 + ln)*PBIH + s*16 + ke);
                        accx[nt] = __builtin_amdgcn_mfma_f32_32x32x16_bf16(a, b, accx[nt], 0,0,0);
                    }
                }
                #pragma unroll
                for (int ks=0; ks<4; ks++){
                    s8v ah = *(const s8v*)(sm16 + OFFAHB + rA*PB72 + ks*16 + ke);
                    #pragma unroll
                    for (int nt=0; nt<3; nt++){
                        int NT = jt + nt*2;
                        s8v b = *(const s8v*)(sm16 + OFFBHH + (NT*32 + ln)*PB72 + ks*16 + ke);
                        acch[nt] = __builtin_amdgcn_mfma_f32_32x32x16_bf16(ah, b, acch[nt], 0,0,0);
                    }
                }
            }
            __syncthreads();                          // all A_hbf reads done

            // ---- prefetch next step's statics (issued BEFORE P3: latency hides
            //      under epilogue; A_s statics are dead after P2) ----
            if (t+1 < HIST){
                const unsigned short* imgrow = img +
                    (((size_t)(t+1)*256 + blockIdx.x)*128)*IMGP;
                {
                    int node = tid >> 2, part = tid & 3;
                    uint4 v = *(const uint4*)(imgrow + node*IMGP + part*8);
                    *(uint4*)(sm16 + OFFAS + node*PAS + part*8) = v;
                }
                if (tid < 128){
                    unsigned int v = *(const unsigned int*)(imgrow + tid*IMGP + 32);
                    *(unsigned int*)(sm16 + OFFAS + tid*PAS + 32) = v;
                }
            }

            // ---- P3: epilogue; hold from hreg; h' -> hreg + h_f32 + A_hbf ----
            {
                const int j = jt*32 + (lane & 31);
                const float br  = ebih[j]     + ebhh[j];
                const float bz  = ebih[64+j]  + ebhh[64+j];
                const float bin_ = ebih[128+j];
                const float bhn  = ebhh[128+j];
                #pragma unroll
                for (int p=0; p<8; p++){
                    const int r0 = 2*p, r1 = 2*p+1;
                    int row = ((r0)&3) + 8*(p>>1) + 4*(lane>>5);
                    const int n0 = mt*32 + row, n1 = n0 + 1;
                    float hold0 = hreg[r0];
                    float hold1 = hreg[r1];
                    float rr0 = sigf(accx[0][r0] + acch[0][r0] + br);
                    float rr1 = sigf(accx[0][r1] + acch[0][r1] + br);
                    float zz0 = sigf(accx[1][r0] + acch[1][r0] + bz);
                    float zz1 = sigf(accx[1][r1] + acch[1][r1] + bz);
                    float nn0 = tanhf_(accx[2][r0] + bin_ + rr0*(acch[2][r0] + bhn));
                    float nn1 = tanhf_(accx[2][r1] + bin_ + rr1*(acch[2][r1] + bhn));
                    float hp0 = (1.f - zz0)*nn0 + zz0*hold0;
                    float hp1 = (1.f - zz1)*nn1 + zz1*hold1;
                    hreg[r0] = hp0;
                    hreg[r1] = hp1;
                    hf[n0*PHF + j] = hp0;
                    hf[n1*PHF + j] = hp1;
                    unsigned int nh = cvtpk(hp0, hp1);
                    sm16[OFFAHB + n0*PB72 + j] = (unsigned short)nh;
                    sm16[OFFAHB + n1*PB72 + j] = (unsigned short)(nh>>16);
                }
            }
            __syncthreads();

            // ---- P4: xn = h' @ Wout + bout (2 waves, f32 reads) ----
            if (tid < 128){
                const float4* hv = (const float4*)(hf + tid*PHF);
                float s = ebout[0];
                #pragma unroll
                for (int q=0; q<16; q++){
                    float4 v = hv[q];
                    s += v.x*eWout[4*q] + v.y*eWout[4*q+1]
                       + v.z*eWout[4*q+2] + v.w*eWout[4*q+3];
                }
                const int nl2 = sub*128 + tid;
                if (nl2 < NN) xn_st(xn_w + batch*NN + nl2, s);
            }
        } else {
            // ---- decoder (block-local; no grid sync) ----
            if (t == HIST){                           // overlay dec weights once
                const uint4* src = (const uint4*)decB;
                uint4* dst = (uint4*)smraw;
                for (int i = tid; i < 3456; i += 512) dst[i] = src[i];
            }
            // P0b: xin = [xn|X13..15] @ Win + bin -> A_x (pitch 72 @ OFFAS)
            {
                const int node = tid >> 2, c0 = (tid & 3)*16;
                const int nl2 = sub*128 + node;
                const int nc  = (nl2 < NN) ? nl2 : NN-1;
                const float* Xt = X + (size_t)(batch*TT + t)*NN*FF;
                float x0 = (t == HIST) ? xn_ld(xn_r + batch*NN + nc) : xnL[node];
                float x1 = Xt[nc*FF + 13];
                float x2 = Xt[nc*FF + 14];
                float x3 = Xt[nc*FF + 15];
                unsigned int* ax32 = (unsigned int*)(sm16 + OFFAS);
                #pragma unroll
                for (int p=0; p<8; p++){
                    int c = c0 + 2*p;
                    float va = dbin[c]   + x0*dWin[c]     + x1*dWin[64+c]   + x2*dWin[128+c]   + x3*dWin[192+c];
                    float vb = dbin[c+1] + x0*dWin[c+1]   + x1*dWin[64+c+1] + x2*dWin[128+c+1] + x3*dWin[192+c+1];
                    ax32[(node*PB72 + c) >> 1] = cvtpk(va, vb);
                }
            }
            __syncthreads();

            f16v accx[3] = {{},{},{}};
            f16v acch[3] = {{},{},{}};
            {
                const int rA = mt*32 + (lane & 31);
                const int ln = lane & 31;
                const int ke = (lane >> 5)*8;
                #pragma unroll
                for (int ks=0; ks<4; ks++){
                    s8v a = *(const s8v*)(sm16 + OFFAS + rA*PB72 + ks*16 + ke);
                    #pragma unroll
                    for (int nt=0; nt<3; nt++){
                        int NT = jt + nt*2;
                        s8v b = *(const s8v*)(sm16 + DOFFBIH + (NT*32 + ln)*PB72 + ks*16 + ke);
                        accx[nt] = __builtin_amdgcn_mfma_f32_32x32x16_bf16(a, b, accx[nt], 0,0,0);
                    }
                }
                #pragma unroll
                for (int ks=0; ks<4; ks++){
                    s8v ah = *(const s8v*)(sm16 + OFFAHB + rA*PB72 + ks*16 + ke);
                    #pragma unroll
                    for (int nt=0; nt<3; nt++){
                        int NT = jt + nt*2;
                        s8v b = *(const s8v*)(sm16 + DOFFBHH + (NT*32 + ln)*PB72 + ks*16 + ke);
                        acch[nt] = __builtin_amdgcn_mfma_f32_32x32x16_bf16(ah, b, acch[nt], 0,0,0);
                    }
                }
            }
            __syncthreads();

            {
                const int j = jt*32 + (lane & 31);
                const float br  = dbih[j]     + dbhh[j];
                const float bz  = dbih[64+j]  + dbhh[64+j];
                const float bin_ = dbih[128+j];
                const float bhn  = dbhh[128+j];
                #pragma unroll
                for (int p=0; p<8; p++){
                    const int r0 = 2*p, r1 = 2*p+1;
                    int row = ((r0)&3) + 8*(p>>1) + 4*(lane>>5);
                    const int n0 = mt*32 + row, n1 = n0 + 1;
                    float hold0 = hreg[r0];
                    float hold1 = hreg[r1];
                    float rr0 = sigf(accx[0][r0] + acch[0][r0] + br);
                    float rr1 = sigf(accx[0][r1] + acch[0][r1] + br);
                    float zz0 = sigf(accx[1][r0] + acch[1][r0] + bz);
                    float zz1 = sigf(accx[1][r1] + acch[1][r1] + bz);
                    float nn0 = tanhf_(accx[2][r0] + bin_ + rr0*(acch[2][r0] + bhn));
                    float nn1 = tanhf_(accx[2][r1] + bin_ + rr1*(acch[2][r1] + bhn));
                    float hp0 = (1.f - zz0)*nn0 + zz0*hold0;
                    float hp1 = (1.f - zz1)*nn1 + zz1*hold1;
                    hreg[r0] = hp0;
                    hreg[r1] = hp1;
                    hf[n0*PHF + j] = hp0;
                    hf[n1*PHF + j] = hp1;
                    unsigned int nh = cvtpk(hp0, hp1);
                    sm16[OFFAHB + n0*PB72 + j] = (unsigned short)nh;
                    sm16[OFFAHB + n1*PB72 + j] = (unsigned short)(nh>>16);
                }
            }
            __syncthreads();

            if (tid < 128){
                const float4* hv = (const float4*)(hf + tid*PHF);
                float s = dbout[0];
                #pragma unroll
                for (int q=0; q<16; q++){
                    float4 v = hv[q];
                    s += v.x*dWout[4*q] + v.y*dWout[4*q+1]
                       + v.z*dWout[4*q+2] + v.w*dWout[4*q+3];
                }
                xnL[tid] = s;
                const int nl2 = sub*128 + tid;
                if (nl2 < NN)
                    out[(size_t)(batch*FC + (t - HIST))*NN + nl2] = s;
            }
        }
        // sync: per-batch barrier between encoder steps; local sync otherwise
        if (t < HIST-1) batch_barrier(mybar, 8u*(unsigned)(t+1));
        else            __syncthreads();
    }
}

extern "C" void kernel_launch(void* const* d_in, const int* in_sizes, int n_in,
                              void* d_out, int out_size, void* d_ws, size_t ws_size,
                              hipStream_t stream)
{
    const float* X     = (const float*)d_in[0];
    const float* y     = (const float*)d_in[1];
    const int*   ei    = (const int*)  d_in[2];
    const float* ew    = (const float*)d_in[3];
    const float* W_rel = (const float*)d_in[4];
    const float* b_rel = (const float*)d_in[5];
    const float* W_root= (const float*)d_in[6];
    const float* eWih  = (const float*)d_in[7];
    const float* eWhh  = (const float*)d_in[8];
    const float* ebih  = (const float*)d_in[9];
    const float* ebhh  = (const float*)d_in[10];
    const float* eWout = (const float*)d_in[11];
    const float* ebout = (const float*)d_in[12];
    const float* dWin  = (const float*)d_in[13];
    const float* dbin  = (const float*)d_in[14];
    const float* dWih  = (const float*)d_in[15];
    const float* dWhh  = (const float*)d_in[16];
    const float* dbih  = (const float*)d_in[17];
    const float* dbhh  = (const float*)d_in[18];
    const float* dWout = (const float*)d_in[19];
    const float* dbout = (const float*)d_in[20];
    float* out = (float*)d_out;

    // ws: img 62.9MB | xn ping-pong 2x128KB | encB 71.7KB | decB 55.3KB | bar 4KB
    unsigned short* img = (unsigned short*)d_ws;
    float* x0 = (float*)(img + (size_t)24*256*128*IMGP);
    float* x1 = x0 + BN;
    unsigned short* encB = (unsigned short*)(x1 + BN);
    unsigned short* decB = encB + 35840;
    unsigned int* bar = (unsigned int*)(decB + 27648);

    const int* esrc = ei;

    const int smA = (NN*FF + NN)*sizeof(float);
    hipFuncSetAttribute((const void*)agg_pre,
                        hipFuncAttributeMaxDynamicSharedMemorySize, smA);
    hipFuncSetAttribute((const void*)fused_steps,
                        hipFuncAttributeMaxDynamicSharedMemorySize, FU_SMEM);

    hipMemsetAsync(bar, 0, 32*32*sizeof(unsigned int), stream);
    prep_weights<<<78, 256, 0, stream>>>(W_rel, W_root, eWih, eWhh, dWih, dWhh, encB, decB);
    agg_pre<<<dim3(BX,24), 1024, smA, stream>>>(X, y, esrc, ew, img);

    void* args[] = {
        (void*)&X, (void*)&esrc, (void*)&ew, (void*)&img,
        (void*)&encB, (void*)&decB,
        (void*)&b_rel, (void*)&ebih, (void*)&ebhh, (void*)&eWout, (void*)&ebout,
        (void*)&dbih, (void*)&dbhh, (void*)&dWin, (void*)&dbin, (void*)&dWout, (void*)&dbout,
        (void*)&x0, (void*)&x1, (void*)&bar, (void*)&out
    };
    hipLaunchCooperativeKernel((const void*)fused_steps, dim3(256), dim3(512),
                               args, FU_SMEM, stream);
}